// Round 3
// baseline (4448.335 us; speedup 1.0000x reference)
//
#include <hip/hip_runtime.h>
#include <math.h>
#include <stdint.h>

// ---------------- Threefry-2x32 (exact JAX PRNG) ----------------
__host__ __device__ static inline uint32_t rotl32(uint32_t x, int d){ return (x<<d)|(x>>(32-d)); }

__host__ __device__ static inline void tf2x32(uint32_t k0, uint32_t k1, uint32_t c0, uint32_t c1,
                                              uint32_t* o0, uint32_t* o1){
  uint32_t ks0=k0, ks1=k1, ks2=k0^k1^0x1BD11BDAu;
  uint32_t x0=c0+ks0, x1=c1+ks1;
  const int ra[4]={13,15,26,6}, rb[4]={17,29,16,24};
  #pragma unroll
  for(int i=0;i<4;i++){x0+=x1;x1=rotl32(x1,ra[i]);x1^=x0;}
  x0+=ks1; x1+=ks2+1u;
  #pragma unroll
  for(int i=0;i<4;i++){x0+=x1;x1=rotl32(x1,rb[i]);x1^=x0;}
  x0+=ks2; x1+=ks0+2u;
  #pragma unroll
  for(int i=0;i<4;i++){x0+=x1;x1=rotl32(x1,ra[i]);x1^=x0;}
  x0+=ks0; x1+=ks1+3u;
  #pragma unroll
  for(int i=0;i<4;i++){x0+=x1;x1=rotl32(x1,rb[i]);x1^=x0;}
  x0+=ks1; x1+=ks2+4u;
  #pragma unroll
  for(int i=0;i<4;i++){x0+=x1;x1=rotl32(x1,ra[i]);x1^=x0;}
  x0+=ks2; x1+=ks0+5u;
  *o0=x0; *o1=x1;
}

// JAX partitionable randint:
//   k1,k2 = foldlike split(key);  bits(key)[i] = o0^o1 of threefry(key,(0,i))
//   idx = ((hi%span)*mult + lo%span) % span,  mult=(65536%span)^2%span
__global__ __launch_bounds__(256) void gen_idx_k(uint32_t k1a,uint32_t k1b,
                                                 uint32_t k2a,uint32_t k2b,
                                                 int size,uint32_t span,uint32_t mult,
                                                 int* __restrict__ idx){
  int i = blockIdx.x*256 + threadIdx.x;
  if (i >= size) return;
  uint32_t h0,h1,l0,l1;
  tf2x32(k1a,k1b,0u,(uint32_t)i,&h0,&h1);
  tf2x32(k2a,k2b,0u,(uint32_t)i,&l0,&l1);
  uint32_t hb = h0^h1, lb = l0^l1;
  idx[i] = (int)((((hb%span)*mult) + (lb%span)) % span);
}

// ---------------- token embedding (circular conv 12->512, k=3) + sinusoidal PE ----------------
__global__ __launch_bounds__(256) void embed_k(const float* __restrict__ xe,
                                               const float* __restrict__ tw,
                                               float* __restrict__ X){
  int i = blockIdx.x*256 + threadIdx.x;     // over 8*1021*512
  int c = i & 511;
  int bl = i >> 9;
  int l = bl % 1021;
  int b = bl / 1021;
  float acc = 0.f;
  #pragma unroll
  for (int t=0;t<3;t++){
    int ls = l - 1 + t;
    ls = (ls < 0) ? 1020 : (ls >= 1021 ? 0 : ls);
    const float* xp = xe + (size_t)(b*1021 + ls)*12;
    const float* wp = tw + (size_t)c*36 + t;
    #pragma unroll
    for (int ci=0; ci<12; ci++) acc += xp[ci] * wp[ci*3];
  }
  int ip = c >> 1;
  float div = expf((float)(2*ip) * (float)(-9.210340371976184/512.0));
  float ang = (float)l * div;
  acc += (c & 1) ? cosf(ang) : sinf(ang);
  X[i] = acc;
}

// ---------------- generic fp32 GEMM: C = A(MxK) @ W^T(NxK) + bias, epilogues ----------------
// mode 0: bias   mode 1: bias+GELU(exact)   mode 2: bias, then *(bn_w/sqrt(1+eps))+bn_b, then ELU
__global__ __launch_bounds__(256) void gemm_k(const float* __restrict__ A,
                                              const float* __restrict__ W,
                                              const float* __restrict__ bias,
                                              float* __restrict__ C,
                                              int M, int N, int K, int mode,
                                              const float* __restrict__ s2,
                                              const float* __restrict__ b2){
  __shared__ float As[8][132];
  __shared__ float Ws[8][132];
  const int t  = threadIdx.x;
  const int tx = t & 15, ty = t >> 4;
  const int m0 = blockIdx.x * 128, n0 = blockIdx.y * 128;
  const int lrow = t >> 1;
  const int lcol = (t & 1) << 2;
  float acc[8][8] = {};
  for (int k0 = 0; k0 < K; k0 += 8){
    float4 av = make_float4(0.f,0.f,0.f,0.f);
    float4 wv = make_float4(0.f,0.f,0.f,0.f);
    int gm = m0 + lrow, gn = n0 + lrow;
    if (gm < M) av = *reinterpret_cast<const float4*>(A + (size_t)gm*K + k0 + lcol);
    if (gn < N) wv = *reinterpret_cast<const float4*>(W + (size_t)gn*K + k0 + lcol);
    __syncthreads();
    As[lcol+0][lrow]=av.x; As[lcol+1][lrow]=av.y; As[lcol+2][lrow]=av.z; As[lcol+3][lrow]=av.w;
    Ws[lcol+0][lrow]=wv.x; Ws[lcol+1][lrow]=wv.y; Ws[lcol+2][lrow]=wv.z; Ws[lcol+3][lrow]=wv.w;
    __syncthreads();
    #pragma unroll
    for (int kk=0; kk<8; ++kk){
      float4 a0 = *reinterpret_cast<const float4*>(&As[kk][ty*4]);
      float4 a1 = *reinterpret_cast<const float4*>(&As[kk][ty*4+64]);
      float4 b0 = *reinterpret_cast<const float4*>(&Ws[kk][tx*4]);
      float4 b1 = *reinterpret_cast<const float4*>(&Ws[kk][tx*4+64]);
      float am[8] = {a0.x,a0.y,a0.z,a0.w,a1.x,a1.y,a1.z,a1.w};
      float bn[8] = {b0.x,b0.y,b0.z,b0.w,b1.x,b1.y,b1.z,b1.w};
      #pragma unroll
      for (int i=0;i<8;i++)
        #pragma unroll
        for (int j=0;j<8;j++) acc[i][j] += am[i]*bn[j];
    }
  }
  #pragma unroll
  for (int i=0;i<8;i++){
    int gm = m0 + ((i<4) ? (ty*4 + i) : (64 + ty*4 + (i-4)));
    if (gm >= M) continue;
    #pragma unroll
    for (int j=0;j<8;j++){
      int gn = n0 + ((j<4) ? (tx*4 + j) : (64 + tx*4 + (j-4)));
      if (gn >= N) continue;
      float v = acc[i][j] + bias[gn];
      if (mode == 1){
        v = 0.5f*v*(1.0f + erff(v*0.707106781186547524f));
      } else if (mode == 2){
        v = v * (s2[gn]*0.9999950000374997f) + b2[gn];
        v = (v > 0.f) ? v : expm1f(v);
      }
      C[(size_t)gm*N + gn] = v;
    }
  }
}

// ---------------- sampled scores m = max_s(q.k_idx) - sum_s(q.k_idx)/L ----------------
__global__ __launch_bounds__(64) void sample_m_k(const float* __restrict__ Q,
                                                 const float* __restrict__ Kb,
                                                 const int* __restrict__ idx,
                                                 float* __restrict__ Mout, int L, int n){
  int bhl = blockIdx.x;
  int l = bhl % L; int bh = bhl / L;
  int h = bh & 7; int b = bh >> 3;
  int s = threadIdx.x;
  __shared__ float qs[64];
  qs[s] = Q[(size_t)(b*L + l)*512 + h*64 + s];
  __syncthreads();
  float dot = 0.f;
  if (s < n){
    int kr = idx[l*n + s];
    const float* kp = Kb + (size_t)(b*L + kr)*512 + h*64;
    #pragma unroll
    for (int d=0; d<64; d++) dot += qs[d]*kp[d];
  }
  float vmax = (s<n) ? dot : -INFINITY;
  float vsum = (s<n) ? dot : 0.f;
  #pragma unroll
  for (int o=32;o>0;o>>=1){
    vmax = fmaxf(vmax, __shfl_down(vmax,o));
    vsum += __shfl_down(vsum,o);
  }
  if (s==0) Mout[(size_t)bh*L + l] = vmax - vsum/(float)L;
}

// ---------------- top-k (iterative argmax, tie -> lower index; matches lax.top_k set) ---------
__global__ __launch_bounds__(256) void topk_k(const float* __restrict__ Mv,
                                              int* __restrict__ topk, int L, int n){
  int bh = blockIdx.x;
  __shared__ float vals[1024];
  __shared__ float rv[256];
  __shared__ int   ri[256];
  int t = threadIdx.x;
  for (int l=t; l<1024; l+=256) vals[l] = (l<L) ? Mv[(size_t)bh*L + l] : -INFINITY;
  __syncthreads();
  for (int it=0; it<n; ++it){
    float bv = -INFINITY; int bi = 0x7fffffff;
    for (int l=t; l<1024; l+=256){
      float v = vals[l];
      if (v > bv || (v == bv && l < bi)){ bv = v; bi = l; }
    }
    rv[t]=bv; ri[t]=bi; __syncthreads();
    for (int o=128;o>0;o>>=1){
      if (t<o){
        float v2=rv[t+o]; int i2=ri[t+o];
        if (v2 > rv[t] || (v2 == rv[t] && i2 < ri[t])){ rv[t]=v2; ri[t]=i2; }
      }
      __syncthreads();
    }
    if (t==0){ topk[bh*n+it] = ri[0]; vals[ri[0]] = -INFINITY; }
    __syncthreads();
  }
}

// ---------------- scores -> softmax -> PV for one selected query ----------------
__global__ __launch_bounds__(256) void attn_upd_k(const float* __restrict__ Q,
                                                  const float* __restrict__ Kb,
                                                  const float* __restrict__ V,
                                                  const int* __restrict__ topk,
                                                  float* __restrict__ UPD, int L, int n){
  int u = blockIdx.x % n; int bh = blockIdx.x / n;
  int h = bh & 7; int b = bh >> 3;
  __shared__ float qs[64];
  __shared__ float sc[1024];
  __shared__ float red[256];
  __shared__ float pv[4][64];
  int t = threadIdx.x;
  int lq = topk[bh*n + u];
  if (t < 64) qs[t] = Q[(size_t)(b*L + lq)*512 + h*64 + t];
  __syncthreads();
  for (int l = t; l < L; l += 256){
    const float* kp = Kb + (size_t)(b*L + l)*512 + h*64;
    float dot = 0.f;
    #pragma unroll
    for (int d=0; d<64; d++) dot += qs[d]*kp[d];
    sc[l] = dot * 0.125f;
  }
  __syncthreads();
  float lm = -INFINITY;
  for (int l=t; l<L; l+=256) lm = fmaxf(lm, sc[l]);
  red[t]=lm; __syncthreads();
  for (int o=128;o>0;o>>=1){ if(t<o) red[t]=fmaxf(red[t],red[t+o]); __syncthreads(); }
  float mx = red[0]; __syncthreads();
  float ls = 0.f;
  for (int l=t; l<L; l+=256){ float p = expf(sc[l]-mx); sc[l]=p; ls += p; }
  red[t]=ls; __syncthreads();
  for (int o=128;o>0;o>>=1){ if(t<o) red[t]+=red[t+o]; __syncthreads(); }
  float inv = 1.0f/red[0];
  int d = t & 63; int chunk = t >> 6;
  float acc = 0.f;
  for (int l=chunk; l<L; l+=4) acc += sc[l] * V[(size_t)(b*L + l)*512 + h*64 + d];
  pv[chunk][d] = acc; __syncthreads();
  if (t < 64){
    float s = (pv[0][t]+pv[1][t]) + (pv[2][t]+pv[3][t]);
    UPD[(size_t)(bh*n + u)*64 + t] = s * inv;
  }
}

// ---------------- v mean (two-phase) ----------------
__global__ __launch_bounds__(512) void vmean_part_k(const float* __restrict__ V,
                                                    float* __restrict__ part, int L){
  int b = blockIdx.x; int j = blockIdx.y; int c = threadIdx.x;
  float s = 0.f;
  for (int l = j; l < L; l += 16) s += V[(size_t)(b*L + l)*512 + c];
  part[(size_t)(b*16 + j)*512 + c] = s;
}
__global__ __launch_bounds__(256) void vmean_comb_k(const float* __restrict__ part,
                                                    float* __restrict__ vmean, int L){
  int i = blockIdx.x*256 + threadIdx.x;   // over 8*512
  int b = i >> 9; int c = i & 511;
  float s = 0.f;
  #pragma unroll
  for (int j=0;j<16;j++) s += part[(size_t)(b*16 + j)*512 + c];
  vmean[i] = s / (float)L;
}

__global__ __launch_bounds__(256) void ctx_fill_k(float* __restrict__ CTX,
                                                  const float* __restrict__ vmean, int L){
  int i = blockIdx.x*256 + threadIdx.x;   // over 8*L*512
  int c = i & 511; int bl = i >> 9; int b = bl / L;
  CTX[i] = vmean[b*512 + c];
}

__global__ __launch_bounds__(256) void ctx_scatter_k(float* __restrict__ CTX,
                                                     const float* __restrict__ UPD,
                                                     const int* __restrict__ topk, int L, int n){
  int i = blockIdx.x*256 + threadIdx.x;   // over 64*n*64
  int d = i & 63; int u = (i >> 6) % n; int bh = i / (64*n);
  int h = bh & 7; int b = bh >> 3;
  int lq = topk[bh*n + u];
  CTX[(size_t)(b*L + lq)*512 + h*64 + d] = UPD[(size_t)(bh*n + u)*64 + d];
}

// ---------------- residual add + LayerNorm (in-place on X) ----------------
__global__ __launch_bounds__(256) void add_ln_k(float* __restrict__ X,
                                                const float* __restrict__ Y,
                                                const float* __restrict__ w,
                                                const float* __restrict__ b){
  int r = blockIdx.x;
  size_t base = (size_t)r*512;
  int t = threadIdx.x;
  float v0 = X[base+t]     + Y[base+t];
  float v1 = X[base+t+256] + Y[base+t+256];
  __shared__ float red[256];
  red[t] = v0 + v1; __syncthreads();
  for (int o=128;o>0;o>>=1){ if(t<o) red[t]+=red[t+o]; __syncthreads(); }
  float mu = red[0]*(1.f/512.f); __syncthreads();
  float d0 = v0-mu, d1 = v1-mu;
  red[t] = d0*d0 + d1*d1; __syncthreads();
  for (int o=128;o>0;o>>=1){ if(t<o) red[t]+=red[t+o]; __syncthreads(); }
  float rs = 1.0f/sqrtf(red[0]*(1.f/512.f) + 1e-5f);
  X[base+t]     = d0*rs*w[t]     + b[t];
  X[base+t+256] = d1*rs*w[t+256] + b[t+256];
}

// ---------------- final LayerNorm + GELU (X -> Yout) ----------------
__global__ __launch_bounds__(256) void ln_gelu_k(const float* __restrict__ X,
                                                 float* __restrict__ Yout,
                                                 const float* __restrict__ w,
                                                 const float* __restrict__ b){
  int r = blockIdx.x;
  size_t base = (size_t)r*512;
  int t = threadIdx.x;
  float v0 = X[base+t];
  float v1 = X[base+t+256];
  __shared__ float red[256];
  red[t] = v0 + v1; __syncthreads();
  for (int o=128;o>0;o>>=1){ if(t<o) red[t]+=red[t+o]; __syncthreads(); }
  float mu = red[0]*(1.f/512.f); __syncthreads();
  float d0 = v0-mu, d1 = v1-mu;
  red[t] = d0*d0 + d1*d1; __syncthreads();
  for (int o=128;o>0;o>>=1){ if(t<o) red[t]+=red[t+o]; __syncthreads(); }
  float rs = 1.0f/sqrtf(red[0]*(1.f/512.f) + 1e-5f);
  float g0 = d0*rs*w[t]     + b[t];
  float g1 = d1*rs*w[t+256] + b[t+256];
  Yout[base+t]     = 0.5f*g0*(1.0f + erff(g0*0.707106781186547524f));
  Yout[base+t+256] = 0.5f*g1*(1.0f + erff(g1*0.707106781186547524f));
}

// ---------------- conv-layer helpers ----------------
__global__ __launch_bounds__(256) void convw_k(const float* __restrict__ cw,
                                               float* __restrict__ W){
  int i = blockIdx.x*256 + threadIdx.x;   // 512*1536
  int col = i % 1536; int co = i / 1536;
  int t = col / 512; int ci = col % 512;
  W[i] = cw[(size_t)co*1536 + ci*3 + t];
}
__global__ __launch_bounds__(256) void im2col_k(const float* __restrict__ X,
                                                float* __restrict__ O, int L){
  int i = blockIdx.x*256 + threadIdx.x;   // 8*L*1536
  int col = i % 1536; int bl = i / 1536;
  int l = bl % L; int b = bl / L;
  int t = col / 512; int ci = col % 512;
  int ls = l - 1 + t;
  ls = (ls < 0) ? (L-1) : (ls >= L ? 0 : ls);
  O[(size_t)bl*1536 + col] = X[(size_t)(b*L + ls)*512 + ci];
}
__global__ __launch_bounds__(256) void pool_k(const float* __restrict__ Hc,
                                              float* __restrict__ X, int L, int Lo){
  int i = blockIdx.x*256 + threadIdx.x;   // 8*Lo*512
  int c = i & 511; int r = i >> 9; int lo = r % Lo; int b = r / Lo;
  float m = -INFINITY;
  #pragma unroll
  for (int dt=-1; dt<=1; dt++){
    int li = 2*lo + dt;
    if (li >= 0 && li < L) m = fmaxf(m, Hc[(size_t)(b*L + li)*512 + c]);
  }
  X[(size_t)(b*Lo + lo)*512 + c] = m;
}

// ---------------- final projection (8,131072) @ (10,131072)^T ----------------
__global__ __launch_bounds__(256) void proj_k(const float* __restrict__ Xg,
                                              const float* __restrict__ pw,
                                              const float* __restrict__ pb,
                                              float* __restrict__ out){
  int j = blockIdx.x % 10; int b = blockIdx.x / 10;
  const float* x = Xg + (size_t)b*131072;
  const float* w = pw + (size_t)j*131072;
  float acc = 0.f;
  for (int k = threadIdx.x; k < 131072; k += 256) acc += x[k]*w[k];
  __shared__ float red[256];
  red[threadIdx.x] = acc; __syncthreads();
  for (int o=128;o>0;o>>=1){ if(threadIdx.x<o) red[threadIdx.x]+=red[threadIdx.x+o]; __syncthreads(); }
  if (threadIdx.x==0) out[blockIdx.x] = red[0] + pb[j];
}

// ---------------- workspace layout (floats) ----------------
static const size_t OFF_X     = 0;
static const size_t OFF_Y     = 4194304;
static const size_t OFF_Q     = 8388608;
static const size_t OFF_K     = 12582912;
static const size_t OFF_V     = 16777216;
static const size_t OFF_CTX   = 20971520;
static const size_t OFF_FF    = 25165824;   // 16777216 floats
static const size_t OFF_M     = 41943040;   // 65536
static const size_t OFF_UPD   = 42008576;   // 143360
static const size_t OFF_VMEAN = 42151936;   // 4096
static const size_t OFF_VPART = 42156032;   // 65536
static const size_t OFF_WCONV = 42221568;   // 786432
static const size_t OFF_IDX   = 43008000;   // 36864 (int)
static const size_t OFF_TOPK  = 43044864;   // 4096  (int)

extern "C" void kernel_launch(void* const* d_in, const int* in_sizes, int n_in,
                              void* d_out, int out_size, void* d_ws, size_t ws_size,
                              hipStream_t stream){
  (void)in_sizes; (void)n_in; (void)out_size; (void)ws_size;
  const float* x_enc = (const float*)d_in[0];
  const float* tok_w = (const float*)d_in[1];
  const float* wq    = (const float*)d_in[2];
  const float* bq    = (const float*)d_in[3];
  const float* wk    = (const float*)d_in[4];
  const float* bk    = (const float*)d_in[5];
  const float* wvp   = (const float*)d_in[6];
  const float* bvp   = (const float*)d_in[7];
  const float* wo    = (const float*)d_in[8];
  const float* bo    = (const float*)d_in[9];
  const float* ln1w  = (const float*)d_in[10];
  const float* ln1b  = (const float*)d_in[11];
  const float* ln2w  = (const float*)d_in[12];
  const float* ln2b  = (const float*)d_in[13];
  const float* f1w   = (const float*)d_in[14];
  const float* f1b   = (const float*)d_in[15];
  const float* f2w   = (const float*)d_in[16];
  const float* f2b   = (const float*)d_in[17];
  const float* cvw   = (const float*)d_in[18];
  const float* cvb   = (const float*)d_in[19];
  const float* bnw   = (const float*)d_in[20];
  const float* bnb   = (const float*)d_in[21];
  const float* nw    = (const float*)d_in[22];
  const float* nb    = (const float*)d_in[23];
  const float* pw    = (const float*)d_in[24];
  const float* pb    = (const float*)d_in[25];

  float* ws   = (float*)d_ws;
  float* X    = ws + OFF_X;
  float* Y    = ws + OFF_Y;
  float* Q    = ws + OFF_Q;
  float* Kb   = ws + OFF_K;
  float* V    = ws + OFF_V;
  float* CTX  = ws + OFF_CTX;
  float* FF   = ws + OFF_FF;
  float* Mb   = ws + OFF_M;
  float* UPD  = ws + OFF_UPD;
  float* VME  = ws + OFF_VMEAN;
  float* VPA  = ws + OFF_VPART;
  float* WCV  = ws + OFF_WCONV;
  int*   IDX  = (int*)(ws + OFF_IDX);
  int*   TOPK = (int*)(ws + OFF_TOPK);

  // JAX partitionable (foldlike) key derivation, host-side:
  // rngs = split(key(42), 3):  rngs[l] = threefry((0,42), (0, l))   (both output words)
  // randint subkeys:           k1 = threefry(rng, (0,0)), k2 = threefry(rng, (0,1))
  uint32_t rka[3], rkb[3];
  for (int l = 0; l < 3; ++l) tf2x32(0u, 42u, 0u, (uint32_t)l, &rka[l], &rkb[l]);

  auto gemm = [&](const float* A, const float* W, const float* bias, float* C,
                  int M, int N, int K, int mode, const float* s2, const float* b2c){
    dim3 g((unsigned)((M+127)/128), (unsigned)(N/128));
    hipLaunchKernelGGL(gemm_k, g, dim3(256), 0, stream, A, W, bias, C, M, N, K, mode, s2, b2c);
  };

  // token embedding + PE
  hipLaunchKernelGGL(embed_k, dim3(16336), dim3(256), 0, stream, x_enc, tok_w, X);

  int L = 1021;
  for (int l = 0; l < 3; ++l){
    int n = 5 * (int)ceil(log((double)L)); if (n > L) n = L;
    int Mr = 8 * L;

    // random sample indices (exact JAX partitionable randint)
    uint32_t k1a,k1b,k2a,k2b;
    tf2x32(rka[l], rkb[l], 0u, 0u, &k1a, &k1b);
    tf2x32(rka[l], rkb[l], 0u, 1u, &k2a, &k2b);
    int size = L * n;
    uint32_t span = (uint32_t)L;
    uint32_t rr = 65536u % span;
    uint32_t mult = (rr * rr) % span;
    hipLaunchKernelGGL(gen_idx_k, dim3((unsigned)((size+255)/256)), dim3(256), 0, stream,
                       k1a, k1b, k2a, k2b, size, span, mult, IDX);

    // QKV
    gemm(X, wq + (size_t)l*262144, bq + (size_t)l*512, Q,  Mr, 512, 512, 0, nullptr, nullptr);
    gemm(X, wk + (size_t)l*262144, bk + (size_t)l*512, Kb, Mr, 512, 512, 0, nullptr, nullptr);
    gemm(X, wvp+ (size_t)l*262144, bvp+ (size_t)l*512, V,  Mr, 512, 512, 0, nullptr, nullptr);

    // sampled m, top-k, attention on reduced queries
    hipLaunchKernelGGL(sample_m_k, dim3((unsigned)(64*L)), dim3(64), 0, stream, Q, Kb, IDX, Mb, L, n);
    hipLaunchKernelGGL(topk_k, dim3(64), dim3(256), 0, stream, Mb, TOPK, L, n);
    hipLaunchKernelGGL(attn_upd_k, dim3((unsigned)(64*n)), dim3(256), 0, stream, Q, Kb, V, TOPK, UPD, L, n);

    // ctx = broadcast mean(v) with top-k rows replaced
    hipLaunchKernelGGL(vmean_part_k, dim3(8,16), dim3(512), 0, stream, V, VPA, L);
    hipLaunchKernelGGL(vmean_comb_k, dim3(16), dim3(256), 0, stream, VPA, VME, L);
    hipLaunchKernelGGL(ctx_fill_k, dim3((unsigned)(Mr*2)), dim3(256), 0, stream, CTX, VME, L);
    hipLaunchKernelGGL(ctx_scatter_k, dim3((unsigned)(16*n)), dim3(256), 0, stream, CTX, UPD, TOPK, L, n);

    // out-proj + LN1
    gemm(CTX, wo + (size_t)l*262144, bo + (size_t)l*512, Y, Mr, 512, 512, 0, nullptr, nullptr);
    hipLaunchKernelGGL(add_ln_k, dim3((unsigned)Mr), dim3(256), 0, stream, X, Y, ln1w + (size_t)l*512, ln1b + (size_t)l*512);

    // FFN + LN2
    gemm(X,  f1w + (size_t)l*1048576, f1b + (size_t)l*2048, FF, Mr, 2048, 512, 1, nullptr, nullptr);
    gemm(FF, f2w + (size_t)l*1048576, f2b + (size_t)l*512,  Y,  Mr, 512, 2048, 0, nullptr, nullptr);
    hipLaunchKernelGGL(add_ln_k, dim3((unsigned)Mr), dim3(256), 0, stream, X, Y, ln2w + (size_t)l*512, ln2b + (size_t)l*512);

    // distilling conv (layers 0,1)
    if (l < 2){
      hipLaunchKernelGGL(convw_k, dim3(3072), dim3(256), 0, stream, cvw + (size_t)l*786432, WCV);
      hipLaunchKernelGGL(im2col_k, dim3((unsigned)(Mr*6)), dim3(256), 0, stream, X, FF, L);
      gemm(FF, WCV, cvb + (size_t)l*512, CTX, Mr, 512, 1536, 2, bnw + (size_t)l*512, bnb + (size_t)l*512);
      int Lo = (L - 1)/2 + 1;
      hipLaunchKernelGGL(pool_k, dim3((unsigned)(8*Lo*2)), dim3(256), 0, stream, CTX, X, L, Lo);
      L = Lo;
    }
  }

  // final LN + GELU + projection
  hipLaunchKernelGGL(ln_gelu_k, dim3((unsigned)(8*L)), dim3(256), 0, stream, X, Y, nw, nb);
  hipLaunchKernelGGL(proj_k, dim3(80), dim3(256), 0, stream, Y, pw, pb, (float*)d_out);
}

// Round 4
// 1998.048 us; speedup vs baseline: 2.2263x; 2.2263x over previous
//
#include <hip/hip_runtime.h>
#include <math.h>
#include <stdint.h>

typedef __attribute__((ext_vector_type(8))) short bf16x8;
typedef __attribute__((ext_vector_type(4))) float f32x4;

// ---------------- helpers ----------------
__device__ __forceinline__ unsigned short f2bf(float f){
  unsigned int u = __float_as_uint(f);
  unsigned int r = (u + 0x7fffu + ((u>>16)&1u)) >> 16;
  return (unsigned short)r;
}
__device__ __forceinline__ float bf2f(unsigned short h){
  return __uint_as_float(((unsigned int)h)<<16);
}
__device__ __forceinline__ void gload16(const void* g, void* l){
  __builtin_amdgcn_global_load_lds(
      (const __attribute__((address_space(1))) unsigned int*)g,
      (__attribute__((address_space(3))) unsigned int*)l, 16, 0, 0);
}

// ---------------- Threefry-2x32 (exact JAX PRNG, partitionable) ----------------
__host__ __device__ static inline uint32_t rotl32(uint32_t x, int d){ return (x<<d)|(x>>(32-d)); }
__host__ __device__ static inline void tf2x32(uint32_t k0, uint32_t k1, uint32_t c0, uint32_t c1,
                                              uint32_t* o0, uint32_t* o1){
  uint32_t ks0=k0, ks1=k1, ks2=k0^k1^0x1BD11BDAu;
  uint32_t x0=c0+ks0, x1=c1+ks1;
  const int ra[4]={13,15,26,6}, rb[4]={17,29,16,24};
  #pragma unroll
  for(int i=0;i<4;i++){x0+=x1;x1=rotl32(x1,ra[i]);x1^=x0;}
  x0+=ks1; x1+=ks2+1u;
  #pragma unroll
  for(int i=0;i<4;i++){x0+=x1;x1=rotl32(x1,rb[i]);x1^=x0;}
  x0+=ks2; x1+=ks0+2u;
  #pragma unroll
  for(int i=0;i<4;i++){x0+=x1;x1=rotl32(x1,ra[i]);x1^=x0;}
  x0+=ks0; x1+=ks1+3u;
  #pragma unroll
  for(int i=0;i<4;i++){x0+=x1;x1=rotl32(x1,rb[i]);x1^=x0;}
  x0+=ks1; x1+=ks2+4u;
  #pragma unroll
  for(int i=0;i<4;i++){x0+=x1;x1=rotl32(x1,ra[i]);x1^=x0;}
  x0+=ks2; x1+=ks0+5u;
  *o0=x0; *o1=x1;
}

__global__ __launch_bounds__(256) void gen_idx_k(uint32_t k1a,uint32_t k1b,
                                                 uint32_t k2a,uint32_t k2b,
                                                 int size,uint32_t span,uint32_t mult,
                                                 int* __restrict__ idx){
  int i = blockIdx.x*256 + threadIdx.x;
  if (i >= size) return;
  uint32_t h0,h1,l0,l1;
  tf2x32(k1a,k1b,0u,(uint32_t)i,&h0,&h1);
  tf2x32(k2a,k2b,0u,(uint32_t)i,&l0,&l1);
  uint32_t hb = h0^h1, lb = l0^l1;
  idx[i] = (int)((((hb%span)*mult) + (lb%span)) % span);
}

// ---------------- token embedding + PE (writes fp32 X and bf16 Xh) ----------------
__global__ __launch_bounds__(256) void embed_k(const float* __restrict__ xe,
                                               const float* __restrict__ tw,
                                               float* __restrict__ X,
                                               short* __restrict__ Xh){
  int i = blockIdx.x*256 + threadIdx.x;     // over 8*1021*512
  int c = i & 511;
  int bl = i >> 9;
  int l = bl % 1021;
  int b = bl / 1021;
  float acc = 0.f;
  #pragma unroll
  for (int t=0;t<3;t++){
    int ls = l - 1 + t;
    ls = (ls < 0) ? 1020 : (ls >= 1021 ? 0 : ls);
    const float* xp = xe + (size_t)(b*1021 + ls)*12;
    const float* wp = tw + (size_t)c*36 + t;
    #pragma unroll
    for (int ci=0; ci<12; ci++) acc += xp[ci] * wp[ci*3];
  }
  int ip = c >> 1;
  float div = expf((float)(2*ip) * (float)(-9.210340371976184/512.0));
  float ang = (float)l * div;
  acc += (c & 1) ? cosf(ang) : sinf(ang);
  X[i] = acc;
  Xh[i] = f2bf(acc);
}

// ---------------- weight converts ----------------
__global__ __launch_bounds__(256) void wcvt_k(const float* __restrict__ src,
                                              short* __restrict__ dst, int n){
  int i = blockIdx.x*256 + threadIdx.x;
  if (i < n) dst[i] = f2bf(src[i]);
}
__global__ __launch_bounds__(256) void convw_k(const float* __restrict__ cw,
                                               short* __restrict__ W){
  int i = blockIdx.x*256 + threadIdx.x;   // 512*1536
  int col = i % 1536; int co = i / 1536;
  int t = col / 512; int ci = col % 512;
  W[i] = f2bf(cw[(size_t)co*1536 + ci*3 + t]);
}

// ---------------- bf16 MFMA GEMM: C = A(MxK) @ W^T(NxK), batched, epilogues ----------
// mode 0: +bias  1: +bias,GELU  2: +bias,BN,ELU  3: raw  4: *rowscale
__global__ __launch_bounds__(256) void gemm_bf16_k(
    const short* __restrict__ A, long Ab,
    const short* __restrict__ W, long Wb,
    const float* __restrict__ bias,
    float* __restrict__ Cf, short* __restrict__ Ch, long Cb,
    int M, int Nreal, int Nstride, int K, int mode,
    const float* __restrict__ s2, const float* __restrict__ b2,
    const float* __restrict__ rs, long rsb)
{
  __shared__ short As[4096];   // 128 x 32
  __shared__ short Bs[4096];
  const int t = threadIdx.x;
  const int lane = t & 63;
  const int w = t >> 6;
  const int wr = w >> 1, wc = w & 1;
  const int z = blockIdx.z;
  const int m0 = blockIdx.x * 128, n0 = blockIdx.y * 128;
  const short* Az = A + (size_t)z * Ab;
  const short* Wz = W + (size_t)z * Wb;

  f32x4 acc[4][4];
  #pragma unroll
  for (int i=0;i<4;i++)
    #pragma unroll
    for (int j=0;j<4;j++) acc[i][j] = (f32x4){0.f,0.f,0.f,0.f};

  const int r0  = t >> 2;          // staging row for slot t
  const int k80 = (t & 3) << 3;    // staging k-offset (elements)
  char* AsB = (char*)As;
  char* BsB = (char*)Bs;

  for (int k0 = 0; k0 < K; k0 += 32){
    gload16(Az + (size_t)(m0 + r0)      * K + k0 + k80, AsB + (size_t)w*1024);
    gload16(Az + (size_t)(m0 + r0 + 64) * K + k0 + k80, AsB + 4096 + (size_t)w*1024);
    gload16(Wz + (size_t)(n0 + r0)      * K + k0 + k80, BsB + (size_t)w*1024);
    gload16(Wz + (size_t)(n0 + r0 + 64) * K + k0 + k80, BsB + 4096 + (size_t)w*1024);
    __syncthreads();
    bf16x8 a[4], b[4];
    #pragma unroll
    for (int mi=0; mi<4; mi++){
      int aoff = (wr*64 + mi*16 + (lane&15))*32 + ((lane>>4)<<3);
      a[mi] = *(const bf16x8*)(&As[aoff]);
    }
    #pragma unroll
    for (int ni=0; ni<4; ni++){
      int boff = (wc*64 + ni*16 + (lane&15))*32 + ((lane>>4)<<3);
      b[ni] = *(const bf16x8*)(&Bs[boff]);
    }
    #pragma unroll
    for (int mi=0; mi<4; mi++)
      #pragma unroll
      for (int ni=0; ni<4; ni++)
        acc[mi][ni] = __builtin_amdgcn_mfma_f32_16x16x32_bf16(a[mi], b[ni], acc[mi][ni], 0, 0, 0);
    __syncthreads();
  }

  #pragma unroll
  for (int mi=0; mi<4; mi++){
    #pragma unroll
    for (int r=0; r<4; r++){
      int gm = m0 + wr*64 + mi*16 + ((lane>>4)<<2) + r;
      if (gm >= M) continue;
      float rsc = (mode==4) ? rs[(size_t)z*rsb + gm] : 0.f;
      #pragma unroll
      for (int ni=0; ni<4; ni++){
        int gn = n0 + wc*64 + ni*16 + (lane&15);
        if (gn >= Nreal) continue;
        float v = acc[mi][ni][r];
        if (mode <= 2) v += bias[gn];
        if (mode == 1){
          v = 0.5f*v*(1.0f + erff(v*0.707106781186547524f));
        } else if (mode == 2){
          v = v * (s2[gn]*0.9999950000374997f) + b2[gn];
          v = (v > 0.f) ? v : expm1f(v);
        } else if (mode == 4){
          v *= rsc;
        }
        size_t off = (size_t)z*Cb + (size_t)gm*Nstride + gn;
        if (Cf) Cf[off] = v;
        if (Ch) Ch[off] = f2bf(v);
      }
    }
  }
}

// ---------------- sampled scores m = max_s(q.k_idx) - sum_s(q.k_idx)/L ----------------
__global__ __launch_bounds__(256) void sample_m_k(const float* __restrict__ Q,
                                                  const float* __restrict__ Kb,
                                                  const int* __restrict__ idx,
                                                  float* __restrict__ Mout, int L, int n){
  int w = threadIdx.x >> 6, lane = threadIdx.x & 63;
  int gl = blockIdx.x*4 + w;
  if (gl >= 64*L) return;
  int l = gl % L; int bh = gl / L;
  int h = bh & 7; int b = bh >> 3;
  float q = Q[(size_t)(b*L + l)*512 + h*64 + lane];
  float vmax = -INFINITY, vsum = 0.f;
  for (int s = 0; s < n; ++s){
    int kr = idx[l*n + s];
    float kv = Kb[(size_t)(b*L + kr)*512 + h*64 + lane];
    float p = q * kv;
    #pragma unroll
    for (int o = 32; o > 0; o >>= 1) p += __shfl_xor(p, o);
    vmax = fmaxf(vmax, p); vsum += p;
  }
  if (lane == 0) Mout[(size_t)bh*1024 + l] = vmax - vsum/(float)L;
}

// ---------------- top-k (single wave per bh, tie -> lower index) ----------------
__global__ __launch_bounds__(64) void topk_k(const float* __restrict__ Mv,
                                             int* __restrict__ topk, int L, int n){
  int bh = blockIdx.x; int lane = threadIdx.x;
  float v[16];
  #pragma unroll
  for (int i=0;i<16;i++){ int l = i*64 + lane; v[i] = (l<L) ? Mv[(size_t)bh*1024 + l] : -INFINITY; }
  for (int it=0; it<n; ++it){
    float bv = -INFINITY; int bi = 0x7fffffff;
    #pragma unroll
    for (int i=0;i<16;i++){ int l = i*64+lane; if (v[i] > bv){ bv = v[i]; bi = l; } }
    #pragma unroll
    for (int o=32;o>0;o>>=1){
      float ov = __shfl_xor(bv, o); int oi = __shfl_xor(bi, o);
      if (ov > bv || (ov == bv && oi < bi)){ bv = ov; bi = oi; }
    }
    if (lane == 0) topk[bh*n + it] = bi;
    int wl = bi & 63, wi = bi >> 6;
    if (lane == wl){
      #pragma unroll
      for (int i=0;i<16;i++) if (i == wi) v[i] = -INFINITY;
    }
  }
}

// ---------------- Qred gather (scaled by 1/8, bf16) ----------------
__global__ __launch_bounds__(64) void qred_k(const float* __restrict__ Q,
                                             const int* __restrict__ topk,
                                             short* __restrict__ Qrh, int L, int n){
  int u = blockIdx.x % n; int bh = blockIdx.x / n;
  int h = bh & 7, b = bh >> 3; int d = threadIdx.x;
  int lq = topk[bh*n + u];
  Qrh[(size_t)bh*8192 + u*64 + d] = f2bf(0.125f * Q[(size_t)(b*L + lq)*512 + h*64 + d]);
}

// ---------------- K head-gather to bf16 [bh][1024][64] ----------------
__global__ __launch_bounds__(256) void kh_k(const float* __restrict__ Kb,
                                            short* __restrict__ Kh, int L){
  int i = blockIdx.x*256 + threadIdx.x;  // 64*1024*64
  int d = i & 63; int l = (i>>6) & 1023; int bh = i >> 16;
  int h = bh & 7, b = bh >> 3;
  Kh[i] = (l < L) ? f2bf(Kb[(size_t)(b*L + l)*512 + h*64 + d]) : (short)0;
}

// ---------------- V transpose to bf16 [bh][128pad d][1024 l] ----------------
__global__ __launch_bounds__(256) void vt_k(const float* __restrict__ V,
                                            short* __restrict__ Vt, int L){
  __shared__ float ts[64][65];
  int z = blockIdx.x >> 4;
  int l0 = (blockIdx.x & 15) * 64;
  int h = z & 7, b = z >> 3;
  int t = threadIdx.x;
  for (int i = t; i < 4096; i += 256){
    int lloc = i >> 6, d = i & 63;
    int l = l0 + lloc;
    ts[d][lloc] = (l < L) ? V[(size_t)(b*L + l)*512 + h*64 + d] : 0.f;
  }
  __syncthreads();
  for (int i = t; i < 4096; i += 256){
    int d = i >> 6, lloc = i & 63;
    Vt[(size_t)z*131072 + (size_t)d*1024 + l0 + lloc] = f2bf(ts[d][lloc]);
  }
}

// ---------------- softmax on S rows -> bf16 P, 1/sum ----------------
__global__ __launch_bounds__(256) void softmax_k(const float* __restrict__ S,
                                                 short* __restrict__ Ph,
                                                 float* __restrict__ RS, int L, int n){
  int u = blockIdx.x % n; int z = blockIdx.x / n;
  const float* srow = S + (size_t)z*n*1024 + (size_t)u*1024;
  short* prow = Ph + (size_t)z*131072 + (size_t)u*1024;
  int t = threadIdx.x;
  __shared__ float red[256];
  float lm = -INFINITY;
  for (int l=t; l<L; l+=256) lm = fmaxf(lm, srow[l]);
  red[t]=lm; __syncthreads();
  for (int o=128;o>0;o>>=1){ if(t<o) red[t]=fmaxf(red[t],red[t+o]); __syncthreads(); }
  float mx = red[0]; __syncthreads();
  float ls = 0.f;
  for (int l=t; l<1024; l+=256){
    float p = (l < L) ? expf(srow[l]-mx) : 0.f;
    prow[l] = f2bf(p);
    ls += p;
  }
  red[t]=ls; __syncthreads();
  for (int o=128;o>0;o>>=1){ if(t<o) red[t]+=red[t+o]; __syncthreads(); }
  if (t==0) RS[(size_t)z*n + u] = 1.0f/red[0];
}

// ---------------- v mean ----------------
__global__ __launch_bounds__(512) void vmean_part_k(const float* __restrict__ V,
                                                    float* __restrict__ part, int L){
  int b = blockIdx.x; int j = blockIdx.y; int c = threadIdx.x;
  float s = 0.f;
  for (int l = j; l < L; l += 16) s += V[(size_t)(b*L + l)*512 + c];
  part[(size_t)(b*16 + j)*512 + c] = s;
}
__global__ __launch_bounds__(256) void vmean_comb_k(const float* __restrict__ part,
                                                    float* __restrict__ vmean, int L){
  int i = blockIdx.x*256 + threadIdx.x;
  int b = i >> 9; int c = i & 511;
  float s = 0.f;
  #pragma unroll
  for (int j=0;j<16;j++) s += part[(size_t)(b*16 + j)*512 + c];
  vmean[i] = s / (float)L;
}
__global__ __launch_bounds__(256) void ctx_fill_k(short* __restrict__ CTXh,
                                                  const float* __restrict__ vmean, int L){
  int i = blockIdx.x*256 + threadIdx.x;
  int c = i & 511; int bl = i >> 9; int b = bl / L;
  CTXh[i] = f2bf(vmean[b*512 + c]);
}
__global__ __launch_bounds__(256) void ctx_scatter_k(short* __restrict__ CTXh,
                                                     const float* __restrict__ UPD,
                                                     const int* __restrict__ topk, int L, int n){
  int i = blockIdx.x*256 + threadIdx.x;   // 64*n*64
  int d = i & 63; int u = (i >> 6) % n; int bh = i / (64*n);
  int h = bh & 7; int b = bh >> 3;
  int lq = topk[bh*n + u];
  CTXh[(size_t)(b*L + lq)*512 + h*64 + d] = f2bf(UPD[((size_t)bh*n + u)*64 + d]);
}

// ---------------- residual add + LayerNorm (X fp32 + Xh bf16) ----------------
__global__ __launch_bounds__(256) void add_ln_k(float* __restrict__ X,
                                                short* __restrict__ Xh,
                                                const float* __restrict__ Y,
                                                const float* __restrict__ w,
                                                const float* __restrict__ b){
  int r = blockIdx.x;
  size_t base = (size_t)r*512;
  int t = threadIdx.x;
  float v0 = X[base+t]     + Y[base+t];
  float v1 = X[base+t+256] + Y[base+t+256];
  __shared__ float red[256];
  red[t] = v0 + v1; __syncthreads();
  for (int o=128;o>0;o>>=1){ if(t<o) red[t]+=red[t+o]; __syncthreads(); }
  float mu = red[0]*(1.f/512.f); __syncthreads();
  float d0 = v0-mu, d1 = v1-mu;
  red[t] = d0*d0 + d1*d1; __syncthreads();
  for (int o=128;o>0;o>>=1){ if(t<o) red[t]+=red[t+o]; __syncthreads(); }
  float rs = 1.0f/sqrtf(red[0]*(1.f/512.f) + 1e-5f);
  float x0 = d0*rs*w[t]     + b[t];
  float x1 = d1*rs*w[t+256] + b[t+256];
  X[base+t]     = x0;  Xh[base+t]     = f2bf(x0);
  X[base+t+256] = x1;  Xh[base+t+256] = f2bf(x1);
}

// ---------------- final LayerNorm + GELU ----------------
__global__ __launch_bounds__(256) void ln_gelu_k(const float* __restrict__ X,
                                                 float* __restrict__ Yout,
                                                 const float* __restrict__ w,
                                                 const float* __restrict__ b){
  int r = blockIdx.x;
  size_t base = (size_t)r*512;
  int t = threadIdx.x;
  float v0 = X[base+t];
  float v1 = X[base+t+256];
  __shared__ float red[256];
  red[t] = v0 + v1; __syncthreads();
  for (int o=128;o>0;o>>=1){ if(t<o) red[t]+=red[t+o]; __syncthreads(); }
  float mu = red[0]*(1.f/512.f); __syncthreads();
  float d0 = v0-mu, d1 = v1-mu;
  red[t] = d0*d0 + d1*d1; __syncthreads();
  for (int o=128;o>0;o>>=1){ if(t<o) red[t]+=red[t+o]; __syncthreads(); }
  float rs = 1.0f/sqrtf(red[0]*(1.f/512.f) + 1e-5f);
  float g0 = d0*rs*w[t]     + b[t];
  float g1 = d1*rs*w[t+256] + b[t+256];
  Yout[base+t]     = 0.5f*g0*(1.0f + erff(g0*0.707106781186547524f));
  Yout[base+t+256] = 0.5f*g1*(1.0f + erff(g1*0.707106781186547524f));
}

// ---------------- conv helpers ----------------
__global__ __launch_bounds__(256) void im2col_k(const float* __restrict__ X,
                                                short* __restrict__ O, int L){
  int i = blockIdx.x*256 + threadIdx.x;   // 8*L*1536
  int col = i % 1536; int bl = i / 1536;
  int l = bl % L; int b = bl / L;
  int t = col / 512; int ci = col % 512;
  int ls = l - 1 + t;
  ls = (ls < 0) ? (L-1) : (ls >= L ? 0 : ls);
  O[(size_t)bl*1536 + col] = f2bf(X[(size_t)(b*L + ls)*512 + ci]);
}
__global__ __launch_bounds__(256) void pool_k(const short* __restrict__ Hc,
                                              float* __restrict__ X,
                                              short* __restrict__ Xh, int L, int Lo){
  int i = blockIdx.x*256 + threadIdx.x;   // 8*Lo*512
  int c = i & 511; int r = i >> 9; int lo = r % Lo; int b = r / Lo;
  float m = -INFINITY;
  #pragma unroll
  for (int dt=-1; dt<=1; dt++){
    int li = 2*lo + dt;
    if (li >= 0 && li < L) m = fmaxf(m, bf2f((unsigned short)Hc[(size_t)(b*L + li)*512 + c]));
  }
  size_t o = (size_t)(b*Lo + lo)*512 + c;
  X[o] = m; Xh[o] = f2bf(m);
}

// ---------------- final projection ----------------
__global__ __launch_bounds__(256) void proj_k(const float* __restrict__ Xg,
                                              const float* __restrict__ pw,
                                              const float* __restrict__ pb,
                                              float* __restrict__ out){
  int j = blockIdx.x % 10; int b = blockIdx.x / 10;
  const float* x = Xg + (size_t)b*131072;
  const float* w = pw + (size_t)j*131072;
  float acc = 0.f;
  for (int k = threadIdx.x; k < 131072; k += 256) acc += x[k]*w[k];
  __shared__ float red[256];
  red[threadIdx.x] = acc; __syncthreads();
  for (int o=128;o>0;o>>=1){ if(threadIdx.x<o) red[threadIdx.x]+=red[threadIdx.x+o]; __syncthreads(); }
  if (threadIdx.x==0) out[blockIdx.x] = red[0] + pb[j];
}

extern "C" void kernel_launch(void* const* d_in, const int* in_sizes, int n_in,
                              void* d_out, int out_size, void* d_ws, size_t ws_size,
                              hipStream_t stream){
  (void)in_sizes; (void)n_in; (void)out_size; (void)ws_size;
  const float* x_enc = (const float*)d_in[0];
  const float* tok_w = (const float*)d_in[1];
  const float* wq    = (const float*)d_in[2];
  const float* bq    = (const float*)d_in[3];
  const float* wk    = (const float*)d_in[4];
  const float* bk    = (const float*)d_in[5];
  const float* wvp   = (const float*)d_in[6];
  const float* bvp   = (const float*)d_in[7];
  const float* wo    = (const float*)d_in[8];
  const float* bo    = (const float*)d_in[9];
  const float* ln1w  = (const float*)d_in[10];
  const float* ln1b  = (const float*)d_in[11];
  const float* ln2w  = (const float*)d_in[12];
  const float* ln2b  = (const float*)d_in[13];
  const float* f1w   = (const float*)d_in[14];
  const float* f1b   = (const float*)d_in[15];
  const float* f2w   = (const float*)d_in[16];
  const float* f2b   = (const float*)d_in[17];
  const float* cvw   = (const float*)d_in[18];
  const float* cvb   = (const float*)d_in[19];
  const float* bnw   = (const float*)d_in[20];
  const float* bnb   = (const float*)d_in[21];
  const float* nw    = (const float*)d_in[22];
  const float* nb    = (const float*)d_in[23];
  const float* pw    = (const float*)d_in[24];
  const float* pb    = (const float*)d_in[25];

  char* wsb = (char*)d_ws;
  float* X    = (float*)(wsb + 0);            // 8192x512 f32
  float* Y    = (float*)(wsb + 16777216);     // 8192x512 f32
  float* Q    = (float*)(wsb + 33554432);
  float* Kbuf = (float*)(wsb + 50331648);
  float* V    = (float*)(wsb + 67108864);
  short* Xh   = (short*)(wsb + 83886080);     // 8192x512 bf16
  short* CTXh = (short*)(wsb + 92274688);     // 8192x512 bf16
  short* WQH  = (short*)(wsb + 100663296);
  short* WKH  = WQH + 262144;
  short* WVH  = WKH + 262144;
  short* WOH  = WVH + 262144;
  short* F1H  = WOH + 262144;                 // 2048x512
  short* F2H  = F1H + 1048576;                // 512x2048
  short* WCVH = F2H + 1048576;                // 512x1536
  char*  RB   = wsb + 108527616;              // shared region (58.7MB)
  short* FFh  = (short*)(RB);                 // 8192x2048 bf16 (FFN phase)
  short* IM2  = (short*)(RB + 33554432);      // 8192x1536 bf16 (conv phase)
  short* Kh   = (short*)(RB + 0);             // [64][1024][64] bf16 (attn phase)
  short* Vt   = (short*)(RB + 8388608);       // [64][128][1024] bf16
  short* Ph   = (short*)(RB + 25165824);      // [64][128][1024] bf16
  short* Qrh  = (short*)(RB + 41943040);      // [64][128][64] bf16
  float* S    = (float*)(RB + 42991616);      // [64][35][1024] f32
  float* RS   = (float*)(RB + 52166656);      // [64][35] f32
  float* UPD  = (float*)(RB + 52175616);      // [64][35][64] f32
  float* Mb   = (float*)(RB + 52749056);      // [64][1024] f32
  float* VME  = (float*)(RB + 53011200);
  float* VPA  = (float*)(RB + 53027584);
  int*   IDX  = (int*)  (RB + 53289728);
  int*   TOPK = (int*)  (RB + 53433088);

  // JAX partitionable key derivation (host)
  uint32_t rka[3], rkb[3];
  for (int l = 0; l < 3; ++l) tf2x32(0u, 42u, 0u, (uint32_t)l, &rka[l], &rkb[l]);

  auto gemm = [&](const short* A, long Ab, const short* W, long Wb, const float* bias,
                  float* Cf, short* Ch, long Cb, int M, int Nreal, int Nstride, int K,
                  int mode, const float* s2, const float* b2, const float* rs, long rsb,
                  int mt, int nt, int zt){
    hipLaunchKernelGGL(gemm_bf16_k, dim3(mt, nt, zt), dim3(256), 0, stream,
                       A, Ab, W, Wb, bias, Cf, Ch, Cb, M, Nreal, Nstride, K, mode,
                       s2, b2, rs, rsb);
  };

  hipLaunchKernelGGL(embed_k, dim3(16336), dim3(256), 0, stream, x_enc, tok_w, X, Xh);

  int L = 1021;
  for (int l = 0; l < 3; ++l){
    int n = 5 * (int)ceil(log((double)L)); if (n > L) n = L;
    int Mr = 8 * L;
    int mt = (Mr + 127)/128;

    // weight converts (bf16)
    hipLaunchKernelGGL(wcvt_k, dim3(1024), dim3(256), 0, stream, wq + (size_t)l*262144, WQH, 262144);
    hipLaunchKernelGGL(wcvt_k, dim3(1024), dim3(256), 0, stream, wk + (size_t)l*262144, WKH, 262144);
    hipLaunchKernelGGL(wcvt_k, dim3(1024), dim3(256), 0, stream, wvp+ (size_t)l*262144, WVH, 262144);
    hipLaunchKernelGGL(wcvt_k, dim3(1024), dim3(256), 0, stream, wo + (size_t)l*262144, WOH, 262144);
    hipLaunchKernelGGL(wcvt_k, dim3(4096), dim3(256), 0, stream, f1w+ (size_t)l*1048576, F1H, 1048576);
    hipLaunchKernelGGL(wcvt_k, dim3(4096), dim3(256), 0, stream, f2w+ (size_t)l*1048576, F2H, 1048576);

    // random sample indices
    uint32_t k1a,k1b,k2a,k2b;
    tf2x32(rka[l], rkb[l], 0u, 0u, &k1a, &k1b);
    tf2x32(rka[l], rkb[l], 0u, 1u, &k2a, &k2b);
    int size = L * n;
    uint32_t span = (uint32_t)L;
    uint32_t rr = 65536u % span;
    uint32_t mult = (rr * rr) % span;
    hipLaunchKernelGGL(gen_idx_k, dim3((unsigned)((size+255)/256)), dim3(256), 0, stream,
                       k1a, k1b, k2a, k2b, size, span, mult, IDX);

    // QKV (bf16 MFMA, fp32 out)
    gemm(Xh, 0, WQH, 0, bq + (size_t)l*512, Q,    nullptr, 0, Mr, 512, 512, 512, 0, 0, 0, 0, 0, mt, 4, 1);
    gemm(Xh, 0, WKH, 0, bk + (size_t)l*512, Kbuf, nullptr, 0, Mr, 512, 512, 512, 0, 0, 0, 0, 0, mt, 4, 1);
    gemm(Xh, 0, WVH, 0, bvp+ (size_t)l*512, V,    nullptr, 0, Mr, 512, 512, 512, 0, 0, 0, 0, 0, mt, 4, 1);

    // sample m, top-k
    hipLaunchKernelGGL(sample_m_k, dim3((unsigned)((64*L+3)/4)), dim3(256), 0, stream, Q, Kbuf, IDX, Mb, L, n);
    hipLaunchKernelGGL(topk_k, dim3(64), dim3(64), 0, stream, Mb, TOPK, L, n);

    // attention: gather -> scores GEMM -> softmax -> PV GEMM
    hipLaunchKernelGGL(qred_k, dim3((unsigned)(64*n)), dim3(64), 0, stream, Q, TOPK, Qrh, L, n);
    hipLaunchKernelGGL(kh_k, dim3(16384), dim3(256), 0, stream, Kbuf, Kh, L);
    hipLaunchKernelGGL(vt_k, dim3(1024), dim3(256), 0, stream, V, Vt, L);
    gemm(Qrh, 8192, Kh, 65536, nullptr, S, nullptr, (long)n*1024, n, L, 1024, 64, 3, 0, 0, 0, 0, 1, 8, 64);
    hipLaunchKernelGGL(softmax_k, dim3((unsigned)(64*n)), dim3(256), 0, stream, S, Ph, RS, L, n);
    gemm(Ph, 131072, Vt, 131072, nullptr, UPD, nullptr, (long)n*64, n, 64, 64, 1024, 4, 0, 0, RS, n, 1, 1, 64);

    // ctx = broadcast mean(v) with top-k rows replaced (bf16)
    hipLaunchKernelGGL(vmean_part_k, dim3(8,16), dim3(512), 0, stream, V, VPA, L);
    hipLaunchKernelGGL(vmean_comb_k, dim3(16), dim3(256), 0, stream, VPA, VME, L);
    hipLaunchKernelGGL(ctx_fill_k, dim3((unsigned)(Mr*2)), dim3(256), 0, stream, CTXh, VME, L);
    hipLaunchKernelGGL(ctx_scatter_k, dim3((unsigned)(16*n)), dim3(256), 0, stream, CTXh, UPD, TOPK, L, n);

    // out-proj + LN1
    gemm(CTXh, 0, WOH, 0, bo + (size_t)l*512, Y, nullptr, 0, Mr, 512, 512, 512, 0, 0, 0, 0, 0, mt, 4, 1);
    hipLaunchKernelGGL(add_ln_k, dim3((unsigned)Mr), dim3(256), 0, stream, X, Xh, Y, ln1w + (size_t)l*512, ln1b + (size_t)l*512);

    // FFN + LN2
    gemm(Xh, 0, F1H, 0, f1b + (size_t)l*2048, nullptr, FFh, 0, Mr, 2048, 2048, 512, 1, 0, 0, 0, 0, mt, 16, 1);
    gemm(FFh, 0, F2H, 0, f2b + (size_t)l*512, Y, nullptr, 0, Mr, 512, 512, 2048, 0, 0, 0, 0, 0, mt, 4, 1);
    hipLaunchKernelGGL(add_ln_k, dim3((unsigned)Mr), dim3(256), 0, stream, X, Xh, Y, ln2w + (size_t)l*512, ln2b + (size_t)l*512);

    // distilling conv (layers 0,1)
    if (l < 2){
      hipLaunchKernelGGL(convw_k, dim3(3072), dim3(256), 0, stream, cvw + (size_t)l*786432, WCVH);
      hipLaunchKernelGGL(im2col_k, dim3((unsigned)(Mr*6)), dim3(256), 0, stream, X, IM2, L);
      gemm(IM2, 0, WCVH, 0, cvb + (size_t)l*512, nullptr, CTXh, 0, Mr, 512, 512, 1536, 2,
           bnw + (size_t)l*512, bnb + (size_t)l*512, 0, 0, mt, 4, 1);
      int Lo = (L - 1)/2 + 1;
      hipLaunchKernelGGL(pool_k, dim3((unsigned)(8*Lo*2)), dim3(256), 0, stream, CTXh, X, Xh, L, Lo);
      L = Lo;
    }
  }

  hipLaunchKernelGGL(ln_gelu_k, dim3((unsigned)(8*L)), dim3(256), 0, stream, X, Y, nw, nb);
  hipLaunchKernelGGL(proj_k, dim3(80), dim3(256), 0, stream, Y, pw, pb, (float*)d_out);
}

// Round 5
// 1889.952 us; speedup vs baseline: 2.3537x; 1.0572x over previous
//
#include <hip/hip_runtime.h>
#include <math.h>
#include <stdint.h>

typedef __attribute__((ext_vector_type(8))) short bf16x8;
typedef __attribute__((ext_vector_type(4))) float f32x4;

// ---------------- helpers ----------------
__device__ __forceinline__ unsigned short f2bf(float f){
  unsigned int u = __float_as_uint(f);
  unsigned int r = (u + 0x7fffu + ((u>>16)&1u)) >> 16;
  return (unsigned short)r;
}
__device__ __forceinline__ float bf2f(unsigned short h){
  return __uint_as_float(((unsigned int)h)<<16);
}
__device__ __forceinline__ void gload16(const void* g, void* l){
  __builtin_amdgcn_global_load_lds(
      (const __attribute__((address_space(1))) unsigned int*)g,
      (__attribute__((address_space(3))) unsigned int*)l, 16, 0, 0);
}

// ---------------- Threefry-2x32 (exact JAX PRNG, partitionable) ----------------
__host__ __device__ static inline uint32_t rotl32(uint32_t x, int d){ return (x<<d)|(x>>(32-d)); }
__host__ __device__ static inline void tf2x32(uint32_t k0, uint32_t k1, uint32_t c0, uint32_t c1,
                                              uint32_t* o0, uint32_t* o1){
  uint32_t ks0=k0, ks1=k1, ks2=k0^k1^0x1BD11BDAu;
  uint32_t x0=c0+ks0, x1=c1+ks1;
  const int ra[4]={13,15,26,6}, rb[4]={17,29,16,24};
  #pragma unroll
  for(int i=0;i<4;i++){x0+=x1;x1=rotl32(x1,ra[i]);x1^=x0;}
  x0+=ks1; x1+=ks2+1u;
  #pragma unroll
  for(int i=0;i<4;i++){x0+=x1;x1=rotl32(x1,rb[i]);x1^=x0;}
  x0+=ks2; x1+=ks0+2u;
  #pragma unroll
  for(int i=0;i<4;i++){x0+=x1;x1=rotl32(x1,ra[i]);x1^=x0;}
  x0+=ks0; x1+=ks1+3u;
  #pragma unroll
  for(int i=0;i<4;i++){x0+=x1;x1=rotl32(x1,rb[i]);x1^=x0;}
  x0+=ks1; x1+=ks2+4u;
  #pragma unroll
  for(int i=0;i<4;i++){x0+=x1;x1=rotl32(x1,ra[i]);x1^=x0;}
  x0+=ks2; x1+=ks0+5u;
  *o0=x0; *o1=x1;
}

__global__ __launch_bounds__(256) void gen_idx_k(uint32_t k1a,uint32_t k1b,
                                                 uint32_t k2a,uint32_t k2b,
                                                 int size,uint32_t span,uint32_t mult,
                                                 int* __restrict__ idx){
  int i = blockIdx.x*256 + threadIdx.x;
  if (i >= size) return;
  uint32_t h0,h1,l0,l1;
  tf2x32(k1a,k1b,0u,(uint32_t)i,&h0,&h1);
  tf2x32(k2a,k2b,0u,(uint32_t)i,&l0,&l1);
  uint32_t hb = h0^h1, lb = l0^l1;
  idx[i] = (int)((((hb%span)*mult) + (lb%span)) % span);
}

// ---------------- token embedding + PE (writes fp32 X and bf16 Xh) ----------------
__global__ __launch_bounds__(256) void embed_k(const float* __restrict__ xe,
                                               const float* __restrict__ tw,
                                               float* __restrict__ X,
                                               short* __restrict__ Xh){
  int i = blockIdx.x*256 + threadIdx.x;     // over 8*1021*512
  int c = i & 511;
  int bl = i >> 9;
  int l = bl % 1021;
  int b = bl / 1021;
  float acc = 0.f;
  #pragma unroll
  for (int t=0;t<3;t++){
    int ls = l - 1 + t;
    ls = (ls < 0) ? 1020 : (ls >= 1021 ? 0 : ls);
    const float* xp = xe + (size_t)(b*1021 + ls)*12;
    const float* wp = tw + (size_t)c*36 + t;
    #pragma unroll
    for (int ci=0; ci<12; ci++) acc += xp[ci] * wp[ci*3];
  }
  int ip = c >> 1;
  float div = expf((float)(2*ip) * (float)(-9.210340371976184/512.0));
  float ang = (float)l * div;
  acc += (c & 1) ? cosf(ang) : sinf(ang);
  X[i] = acc;
  Xh[i] = f2bf(acc);
}

// ---------------- weight converts ----------------
__global__ __launch_bounds__(256) void wcvt_k(const float* __restrict__ src,
                                              short* __restrict__ dst, int n){
  int i = blockIdx.x*256 + threadIdx.x;
  if (i < n) dst[i] = f2bf(src[i]);
}
__global__ __launch_bounds__(256) void convw_k(const float* __restrict__ cw,
                                               short* __restrict__ W){
  int i = blockIdx.x*256 + threadIdx.x;   // 512*1536
  int col = i % 1536; int co = i / 1536;
  int t = col / 512; int ci = col % 512;
  W[i] = f2bf(cw[(size_t)co*1536 + ci*3 + t]);
}

// ---------------- bf16 MFMA GEMM: C = A(MxK) @ W^T(NxK), batched, epilogues ----------
// mode 0: +bias  1: +bias,GELU  2: +bias,BN,ELU  3: raw  4: *rowscale
__global__ __launch_bounds__(256) void gemm_bf16_k(
    const short* __restrict__ A, long Ab,
    const short* __restrict__ W, long Wb,
    const float* __restrict__ bias,
    float* __restrict__ Cf, short* __restrict__ Ch, long Cb,
    int M, int Nreal, int Nstride, int K, int mode,
    const float* __restrict__ s2, const float* __restrict__ b2,
    const float* __restrict__ rs, long rsb)
{
  __shared__ short As[4096];   // 128 x 32
  __shared__ short Bs[4096];
  const int t = threadIdx.x;
  const int lane = t & 63;
  const int w = t >> 6;
  const int wr = w >> 1, wc = w & 1;
  const int z = blockIdx.z;
  const int m0 = blockIdx.x * 128, n0 = blockIdx.y * 128;
  const short* Az = A + (size_t)z * Ab;
  const short* Wz = W + (size_t)z * Wb;

  f32x4 acc[4][4];
  #pragma unroll
  for (int i=0;i<4;i++)
    #pragma unroll
    for (int j=0;j<4;j++) acc[i][j] = (f32x4){0.f,0.f,0.f,0.f};

  const int r0  = t >> 2;          // staging row for slot t
  const int k80 = (t & 3) << 3;    // staging k-offset (elements)
  char* AsB = (char*)As;
  char* BsB = (char*)Bs;

  for (int k0 = 0; k0 < K; k0 += 32){
    gload16(Az + (size_t)(m0 + r0)      * K + k0 + k80, AsB + (size_t)w*1024);
    gload16(Az + (size_t)(m0 + r0 + 64) * K + k0 + k80, AsB + 4096 + (size_t)w*1024);
    gload16(Wz + (size_t)(n0 + r0)      * K + k0 + k80, BsB + (size_t)w*1024);
    gload16(Wz + (size_t)(n0 + r0 + 64) * K + k0 + k80, BsB + 4096 + (size_t)w*1024);
    __syncthreads();
    bf16x8 a[4], b[4];
    #pragma unroll
    for (int mi=0; mi<4; mi++){
      int aoff = (wr*64 + mi*16 + (lane&15))*32 + ((lane>>4)<<3);
      a[mi] = *(const bf16x8*)(&As[aoff]);
    }
    #pragma unroll
    for (int ni=0; ni<4; ni++){
      int boff = (wc*64 + ni*16 + (lane&15))*32 + ((lane>>4)<<3);
      b[ni] = *(const bf16x8*)(&Bs[boff]);
    }
    #pragma unroll
    for (int mi=0; mi<4; mi++)
      #pragma unroll
      for (int ni=0; ni<4; ni++)
        acc[mi][ni] = __builtin_amdgcn_mfma_f32_16x16x32_bf16(a[mi], b[ni], acc[mi][ni], 0, 0, 0);
    __syncthreads();
  }

  #pragma unroll
  for (int mi=0; mi<4; mi++){
    #pragma unroll
    for (int r=0; r<4; r++){
      int gm = m0 + wr*64 + mi*16 + ((lane>>4)<<2) + r;
      if (gm >= M) continue;
      float rsc = (mode==4) ? rs[(size_t)z*rsb + gm] : 0.f;
      #pragma unroll
      for (int ni=0; ni<4; ni++){
        int gn = n0 + wc*64 + ni*16 + (lane&15);
        if (gn >= Nreal) continue;
        float v = acc[mi][ni][r];
        if (mode <= 2) v += bias[gn];
        if (mode == 1){
          v = 0.5f*v*(1.0f + erff(v*0.707106781186547524f));
        } else if (mode == 2){
          v = v * (s2[gn]*0.9999950000374997f) + b2[gn];
          v = (v > 0.f) ? v : expm1f(v);
        } else if (mode == 4){
          v *= rsc;
        }
        size_t off = (size_t)z*Cb + (size_t)gm*Nstride + gn;
        if (Cf) Cf[off] = v;
        if (Ch) Ch[off] = f2bf(v);
      }
    }
  }
}

// ---------------- sampled dots: one thread per (bh,l,s), fp32 float4 dot ----------------
__global__ __launch_bounds__(256) void qk_dot_k(const float* __restrict__ Q,
                                                const float* __restrict__ Kb,
                                                const int* __restrict__ idx,
                                                float* __restrict__ QK, int L, int n){
  long gi = (long)blockIdx.x*256 + threadIdx.x;   // over 64*L*n, layout (bh, l, s)
  long total = (long)64*L*n;
  if (gi >= total) return;
  int s = (int)(gi % n); long t2 = gi / n;
  int l = (int)(t2 % L); int bh = (int)(t2 / L);
  int h = bh & 7, b = bh >> 3;
  const float4* qp = (const float4*)(Q + (size_t)(b*L + l)*512 + h*64);
  int kr = idx[l*n + s];
  const float4* kp = (const float4*)(Kb + (size_t)(b*L + kr)*512 + h*64);
  float dot = 0.f;
  #pragma unroll
  for (int i=0;i<16;i++){
    float4 a = qp[i], c = kp[i];
    dot += a.x*c.x + a.y*c.y + a.z*c.z + a.w*c.w;
  }
  QK[gi] = dot;
}

// ---------------- m = max_s - sum_s/L over contiguous rows of n ----------------
__global__ __launch_bounds__(256) void reduce_m_k(const float* __restrict__ QK,
                                                  float* __restrict__ Mout, int L, int n){
  int gi = blockIdx.x*256 + threadIdx.x;   // over 64*L
  if (gi >= 64*L) return;
  int l = gi % L; int bh = gi / L;
  const float* row = QK + (size_t)gi*n;
  float mx = -INFINITY, sm = 0.f;
  for (int s=0;s<n;s++){ float v = row[s]; mx = fmaxf(mx, v); sm += v; }
  Mout[(size_t)bh*1024 + l] = mx - sm/(float)L;
}

// ---------------- top-k (single wave per bh, tie -> lower index) ----------------
__global__ __launch_bounds__(64) void topk_k(const float* __restrict__ Mv,
                                             int* __restrict__ topk, int L, int n){
  int bh = blockIdx.x; int lane = threadIdx.x;
  float v[16];
  #pragma unroll
  for (int i=0;i<16;i++){ int l = i*64 + lane; v[i] = (l<L) ? Mv[(size_t)bh*1024 + l] : -INFINITY; }
  for (int it=0; it<n; ++it){
    float bv = -INFINITY; int bi = 0x7fffffff;
    #pragma unroll
    for (int i=0;i<16;i++){ int l = i*64+lane; if (v[i] > bv){ bv = v[i]; bi = l; } }
    #pragma unroll
    for (int o=32;o>0;o>>=1){
      float ov = __shfl_xor(bv, o); int oi = __shfl_xor(bi, o);
      if (ov > bv || (ov == bv && oi < bi)){ bv = ov; bi = oi; }
    }
    if (lane == 0) topk[bh*n + it] = bi;
    int wl = bi & 63, wi = bi >> 6;
    if (lane == wl){
      #pragma unroll
      for (int i=0;i<16;i++) if (i == wi) v[i] = -INFINITY;
    }
  }
}

// ---------------- Qred gather (scaled by 1/8, bf16) ----------------
__global__ __launch_bounds__(64) void qred_k(const float* __restrict__ Q,
                                             const int* __restrict__ topk,
                                             short* __restrict__ Qrh, int L, int n){
  int u = blockIdx.x % n; int bh = blockIdx.x / n;
  int h = bh & 7, b = bh >> 3; int d = threadIdx.x;
  int lq = topk[bh*n + u];
  Qrh[(size_t)bh*8192 + u*64 + d] = f2bf(0.125f * Q[(size_t)(b*L + lq)*512 + h*64 + d]);
}

// ---------------- K head-gather to bf16 [bh][1024][64] ----------------
__global__ __launch_bounds__(256) void kh_k(const float* __restrict__ Kb,
                                            short* __restrict__ Kh, int L){
  int i = blockIdx.x*256 + threadIdx.x;  // 64*1024*64
  int d = i & 63; int l = (i>>6) & 1023; int bh = i >> 16;
  int h = bh & 7, b = bh >> 3;
  Kh[i] = (l < L) ? f2bf(Kb[(size_t)(b*L + l)*512 + h*64 + d]) : (short)0;
}

// ---------------- V transpose to bf16 [bh][128pad d][1024 l] ----------------
__global__ __launch_bounds__(256) void vt_k(const float* __restrict__ V,
                                            short* __restrict__ Vt, int L){
  __shared__ float ts[64][65];
  int z = blockIdx.x >> 4;
  int l0 = (blockIdx.x & 15) * 64;
  int h = z & 7, b = z >> 3;
  int t = threadIdx.x;
  for (int i = t; i < 4096; i += 256){
    int lloc = i >> 6, d = i & 63;
    int l = l0 + lloc;
    ts[d][lloc] = (l < L) ? V[(size_t)(b*L + l)*512 + h*64 + d] : 0.f;
  }
  __syncthreads();
  for (int i = t; i < 4096; i += 256){
    int d = i >> 6, lloc = i & 63;
    Vt[(size_t)z*131072 + (size_t)d*1024 + l0 + lloc] = f2bf(ts[d][lloc]);
  }
}

// ---------------- softmax on S rows -> bf16 P, 1/sum ----------------
__global__ __launch_bounds__(256) void softmax_k(const float* __restrict__ S,
                                                 short* __restrict__ Ph,
                                                 float* __restrict__ RS, int L, int n){
  int u = blockIdx.x % n; int z = blockIdx.x / n;
  const float* srow = S + (size_t)z*n*1024 + (size_t)u*1024;
  short* prow = Ph + (size_t)z*131072 + (size_t)u*1024;
  int t = threadIdx.x;
  __shared__ float red[256];
  float lm = -INFINITY;
  for (int l=t; l<L; l+=256) lm = fmaxf(lm, srow[l]);
  red[t]=lm; __syncthreads();
  for (int o=128;o>0;o>>=1){ if(t<o) red[t]=fmaxf(red[t],red[t+o]); __syncthreads(); }
  float mx = red[0]; __syncthreads();
  float ls = 0.f;
  for (int l=t; l<1024; l+=256){
    float p = (l < L) ? expf(srow[l]-mx) : 0.f;
    prow[l] = f2bf(p);
    ls += p;
  }
  red[t]=ls; __syncthreads();
  for (int o=128;o>0;o>>=1){ if(t<o) red[t]+=red[t+o]; __syncthreads(); }
  if (t==0) RS[(size_t)z*n + u] = 1.0f/red[0];
}

// ---------------- v mean ----------------
__global__ __launch_bounds__(512) void vmean_part_k(const float* __restrict__ V,
                                                    float* __restrict__ part, int L){
  int b = blockIdx.x; int j = blockIdx.y; int c = threadIdx.x;
  float s = 0.f;
  for (int l = j; l < L; l += 16) s += V[(size_t)(b*L + l)*512 + c];
  part[(size_t)(b*16 + j)*512 + c] = s;
}
__global__ __launch_bounds__(256) void vmean_comb_k(const float* __restrict__ part,
                                                    float* __restrict__ vmean, int L){
  int i = blockIdx.x*256 + threadIdx.x;
  int b = i >> 9; int c = i & 511;
  float s = 0.f;
  #pragma unroll
  for (int j=0;j<16;j++) s += part[(size_t)(b*16 + j)*512 + c];
  vmean[i] = s / (float)L;
}
__global__ __launch_bounds__(256) void ctx_fill_k(short* __restrict__ CTXh,
                                                  const float* __restrict__ vmean, int L){
  int i = blockIdx.x*256 + threadIdx.x;
  int c = i & 511; int bl = i >> 9; int b = bl / L;
  CTXh[i] = f2bf(vmean[b*512 + c]);
}
__global__ __launch_bounds__(256) void ctx_scatter_k(short* __restrict__ CTXh,
                                                     const float* __restrict__ UPD,
                                                     const int* __restrict__ topk, int L, int n){
  int i = blockIdx.x*256 + threadIdx.x;   // 64*n*64
  int d = i & 63; int u = (i >> 6) % n; int bh = i / (64*n);
  int h = bh & 7; int b = bh >> 3;
  int lq = topk[bh*n + u];
  CTXh[(size_t)(b*L + lq)*512 + h*64 + d] = f2bf(UPD[((size_t)bh*n + u)*64 + d]);
}

// ---------------- residual add + LayerNorm (X fp32 + Xh bf16) ----------------
__global__ __launch_bounds__(256) void add_ln_k(float* __restrict__ X,
                                                short* __restrict__ Xh,
                                                const float* __restrict__ Y,
                                                const float* __restrict__ w,
                                                const float* __restrict__ b){
  int r = blockIdx.x;
  size_t base = (size_t)r*512;
  int t = threadIdx.x;
  float v0 = X[base+t]     + Y[base+t];
  float v1 = X[base+t+256] + Y[base+t+256];
  __shared__ float red[256];
  red[t] = v0 + v1; __syncthreads();
  for (int o=128;o>0;o>>=1){ if(t<o) red[t]+=red[t+o]; __syncthreads(); }
  float mu = red[0]*(1.f/512.f); __syncthreads();
  float d0 = v0-mu, d1 = v1-mu;
  red[t] = d0*d0 + d1*d1; __syncthreads();
  for (int o=128;o>0;o>>=1){ if(t<o) red[t]+=red[t+o]; __syncthreads(); }
  float rs = 1.0f/sqrtf(red[0]*(1.f/512.f) + 1e-5f);
  float x0 = d0*rs*w[t]     + b[t];
  float x1 = d1*rs*w[t+256] + b[t+256];
  X[base+t]     = x0;  Xh[base+t]     = f2bf(x0);
  X[base+t+256] = x1;  Xh[base+t+256] = f2bf(x1);
}

// ---------------- final LayerNorm + GELU ----------------
__global__ __launch_bounds__(256) void ln_gelu_k(const float* __restrict__ X,
                                                 float* __restrict__ Yout,
                                                 const float* __restrict__ w,
                                                 const float* __restrict__ b){
  int r = blockIdx.x;
  size_t base = (size_t)r*512;
  int t = threadIdx.x;
  float v0 = X[base+t];
  float v1 = X[base+t+256];
  __shared__ float red[256];
  red[t] = v0 + v1; __syncthreads();
  for (int o=128;o>0;o>>=1){ if(t<o) red[t]+=red[t+o]; __syncthreads(); }
  float mu = red[0]*(1.f/512.f); __syncthreads();
  float d0 = v0-mu, d1 = v1-mu;
  red[t] = d0*d0 + d1*d1; __syncthreads();
  for (int o=128;o>0;o>>=1){ if(t<o) red[t]+=red[t+o]; __syncthreads(); }
  float rs = 1.0f/sqrtf(red[0]*(1.f/512.f) + 1e-5f);
  float g0 = d0*rs*w[t]     + b[t];
  float g1 = d1*rs*w[t+256] + b[t+256];
  Yout[base+t]     = 0.5f*g0*(1.0f + erff(g0*0.707106781186547524f));
  Yout[base+t+256] = 0.5f*g1*(1.0f + erff(g1*0.707106781186547524f));
}

// ---------------- conv helpers ----------------
__global__ __launch_bounds__(256) void im2col_k(const float* __restrict__ X,
                                                short* __restrict__ O, int L){
  int i = blockIdx.x*256 + threadIdx.x;   // 8*L*1536
  int col = i % 1536; int bl = i / 1536;
  int l = bl % L; int b = bl / L;
  int t = col / 512; int ci = col % 512;
  int ls = l - 1 + t;
  ls = (ls < 0) ? (L-1) : (ls >= L ? 0 : ls);
  O[(size_t)bl*1536 + col] = f2bf(X[(size_t)(b*L + ls)*512 + ci]);
}
__global__ __launch_bounds__(256) void pool_k(const short* __restrict__ Hc,
                                              float* __restrict__ X,
                                              short* __restrict__ Xh, int L, int Lo){
  int i = blockIdx.x*256 + threadIdx.x;   // 8*Lo*512
  int c = i & 511; int r = i >> 9; int lo = r % Lo; int b = r / Lo;
  float m = -INFINITY;
  #pragma unroll
  for (int dt=-1; dt<=1; dt++){
    int li = 2*lo + dt;
    if (li >= 0 && li < L) m = fmaxf(m, bf2f((unsigned short)Hc[(size_t)(b*L + li)*512 + c]));
  }
  size_t o = (size_t)(b*Lo + lo)*512 + c;
  X[o] = m; Xh[o] = f2bf(m);
}

// ---------------- final projection ----------------
__global__ __launch_bounds__(256) void proj_k(const float* __restrict__ Xg,
                                              const float* __restrict__ pw,
                                              const float* __restrict__ pb,
                                              float* __restrict__ out){
  int j = blockIdx.x % 10; int b = blockIdx.x / 10;
  const float* x = Xg + (size_t)b*131072;
  const float* w = pw + (size_t)j*131072;
  float acc = 0.f;
  for (int k = threadIdx.x; k < 131072; k += 256) acc += x[k]*w[k];
  __shared__ float red[256];
  red[threadIdx.x] = acc; __syncthreads();
  for (int o=128;o>0;o>>=1){ if(threadIdx.x<o) red[threadIdx.x]+=red[threadIdx.x+o]; __syncthreads(); }
  if (threadIdx.x==0) out[blockIdx.x] = red[0] + pb[j];
}

extern "C" void kernel_launch(void* const* d_in, const int* in_sizes, int n_in,
                              void* d_out, int out_size, void* d_ws, size_t ws_size,
                              hipStream_t stream){
  (void)in_sizes; (void)n_in; (void)out_size; (void)ws_size;
  const float* x_enc = (const float*)d_in[0];
  const float* tok_w = (const float*)d_in[1];
  const float* wq    = (const float*)d_in[2];
  const float* bq    = (const float*)d_in[3];
  const float* wk    = (const float*)d_in[4];
  const float* bk    = (const float*)d_in[5];
  const float* wvp   = (const float*)d_in[6];
  const float* bvp   = (const float*)d_in[7];
  const float* wo    = (const float*)d_in[8];
  const float* bo    = (const float*)d_in[9];
  const float* ln1w  = (const float*)d_in[10];
  const float* ln1b  = (const float*)d_in[11];
  const float* ln2w  = (const float*)d_in[12];
  const float* ln2b  = (const float*)d_in[13];
  const float* f1w   = (const float*)d_in[14];
  const float* f1b   = (const float*)d_in[15];
  const float* f2w   = (const float*)d_in[16];
  const float* f2b   = (const float*)d_in[17];
  const float* cvw   = (const float*)d_in[18];
  const float* cvb   = (const float*)d_in[19];
  const float* bnw   = (const float*)d_in[20];
  const float* bnb   = (const float*)d_in[21];
  const float* nw    = (const float*)d_in[22];
  const float* nb    = (const float*)d_in[23];
  const float* pw    = (const float*)d_in[24];
  const float* pb    = (const float*)d_in[25];

  char* wsb = (char*)d_ws;
  float* X    = (float*)(wsb + 0);            // 8192x512 f32
  float* Y    = (float*)(wsb + 16777216);     // 8192x512 f32
  float* Q    = (float*)(wsb + 33554432);
  float* Kbuf = (float*)(wsb + 50331648);
  float* V    = (float*)(wsb + 67108864);
  short* Xh   = (short*)(wsb + 83886080);     // 8192x512 bf16
  short* CTXh = (short*)(wsb + 92274688);     // 8192x512 bf16
  short* WQH  = (short*)(wsb + 100663296);
  short* WKH  = WQH + 262144;
  short* WVH  = WKH + 262144;
  short* WOH  = WVH + 262144;
  short* F1H  = WOH + 262144;                 // 2048x512
  short* F2H  = F1H + 1048576;                // 512x2048
  short* WCVH = F2H + 1048576;                // 512x1536
  char*  RB   = wsb + 108527616;              // shared region (58.7MB)
  short* FFh  = (short*)(RB);                 // 8192x2048 bf16 (FFN phase)
  short* IM2  = (short*)(RB + 33554432);      // 8192x1536 bf16 (conv phase)
  short* Kh   = (short*)(RB + 0);             // [64][1024][64] bf16 (attn phase)
  short* Vt   = (short*)(RB + 8388608);       // [64][128][1024] bf16
  short* Ph   = (short*)(RB + 25165824);      // [64][128][1024] bf16
  short* Qrh  = (short*)(RB + 41943040);      // [64][128][64] bf16
  float* S    = (float*)(RB + 42991616);      // [64][35][1024] f32 (also QK dots)
  float* RS   = (float*)(RB + 52166656);      // [64][35] f32
  float* UPD  = (float*)(RB + 52175616);      // [64][35][64] f32
  float* Mb   = (float*)(RB + 52749056);      // [64][1024] f32
  float* VME  = (float*)(RB + 53011200);
  float* VPA  = (float*)(RB + 53027584);
  int*   IDX  = (int*)  (RB + 53289728);
  int*   TOPK = (int*)  (RB + 53433088);

  // JAX partitionable key derivation (host)
  uint32_t rka[3], rkb[3];
  for (int l = 0; l < 3; ++l) tf2x32(0u, 42u, 0u, (uint32_t)l, &rka[l], &rkb[l]);

  auto gemm = [&](const short* A, long Ab, const short* W, long Wb, const float* bias,
                  float* Cf, short* Ch, long Cb, int M, int Nreal, int Nstride, int K,
                  int mode, const float* s2, const float* b2, const float* rs, long rsb,
                  int mt, int nt, int zt){
    hipLaunchKernelGGL(gemm_bf16_k, dim3(mt, nt, zt), dim3(256), 0, stream,
                       A, Ab, W, Wb, bias, Cf, Ch, Cb, M, Nreal, Nstride, K, mode,
                       s2, b2, rs, rsb);
  };

  hipLaunchKernelGGL(embed_k, dim3(16336), dim3(256), 0, stream, x_enc, tok_w, X, Xh);

  int L = 1021;
  for (int l = 0; l < 3; ++l){
    int n = 5 * (int)ceil(log((double)L)); if (n > L) n = L;
    int Mr = 8 * L;
    int mt = (Mr + 127)/128;

    // weight converts (bf16)
    hipLaunchKernelGGL(wcvt_k, dim3(1024), dim3(256), 0, stream, wq + (size_t)l*262144, WQH, 262144);
    hipLaunchKernelGGL(wcvt_k, dim3(1024), dim3(256), 0, stream, wk + (size_t)l*262144, WKH, 262144);
    hipLaunchKernelGGL(wcvt_k, dim3(1024), dim3(256), 0, stream, wvp+ (size_t)l*262144, WVH, 262144);
    hipLaunchKernelGGL(wcvt_k, dim3(1024), dim3(256), 0, stream, wo + (size_t)l*262144, WOH, 262144);
    hipLaunchKernelGGL(wcvt_k, dim3(4096), dim3(256), 0, stream, f1w+ (size_t)l*1048576, F1H, 1048576);
    hipLaunchKernelGGL(wcvt_k, dim3(4096), dim3(256), 0, stream, f2w+ (size_t)l*1048576, F2H, 1048576);

    // random sample indices
    uint32_t k1a,k1b,k2a,k2b;
    tf2x32(rka[l], rkb[l], 0u, 0u, &k1a, &k1b);
    tf2x32(rka[l], rkb[l], 0u, 1u, &k2a, &k2b);
    int size = L * n;
    uint32_t span = (uint32_t)L;
    uint32_t rr = 65536u % span;
    uint32_t mult = (rr * rr) % span;
    hipLaunchKernelGGL(gen_idx_k, dim3((unsigned)((size+255)/256)), dim3(256), 0, stream,
                       k1a, k1b, k2a, k2b, size, span, mult, IDX);

    // QKV (bf16 MFMA, fp32 out)
    gemm(Xh, 0, WQH, 0, bq + (size_t)l*512, Q,    nullptr, 0, Mr, 512, 512, 512, 0, 0, 0, 0, 0, mt, 4, 1);
    gemm(Xh, 0, WKH, 0, bk + (size_t)l*512, Kbuf, nullptr, 0, Mr, 512, 512, 512, 0, 0, 0, 0, 0, mt, 4, 1);
    gemm(Xh, 0, WVH, 0, bvp+ (size_t)l*512, V,    nullptr, 0, Mr, 512, 512, 512, 0, 0, 0, 0, 0, mt, 4, 1);

    // sampled dots (thread-per-(l,s)) then m-reduce, top-k
    long tot = (long)64*L*n;
    hipLaunchKernelGGL(qk_dot_k, dim3((unsigned)((tot+255)/256)), dim3(256), 0, stream,
                       Q, Kbuf, IDX, S, L, n);
    hipLaunchKernelGGL(reduce_m_k, dim3((unsigned)((64*L+255)/256)), dim3(256), 0, stream,
                       S, Mb, L, n);
    hipLaunchKernelGGL(topk_k, dim3(64), dim3(64), 0, stream, Mb, TOPK, L, n);

    // attention: gather -> scores GEMM -> softmax -> PV GEMM
    hipLaunchKernelGGL(qred_k, dim3((unsigned)(64*n)), dim3(64), 0, stream, Q, TOPK, Qrh, L, n);
    hipLaunchKernelGGL(kh_k, dim3(16384), dim3(256), 0, stream, Kbuf, Kh, L);
    hipLaunchKernelGGL(vt_k, dim3(1024), dim3(256), 0, stream, V, Vt, L);
    gemm(Qrh, 8192, Kh, 65536, nullptr, S, nullptr, (long)n*1024, n, L, 1024, 64, 3, 0, 0, 0, 0, 1, 8, 64);
    hipLaunchKernelGGL(softmax_k, dim3((unsigned)(64*n)), dim3(256), 0, stream, S, Ph, RS, L, n);
    gemm(Ph, 131072, Vt, 131072, nullptr, UPD, nullptr, (long)n*64, n, 64, 64, 1024, 4, 0, 0, RS, n, 1, 1, 64);

    // ctx = broadcast mean(v) with top-k rows replaced (bf16)
    hipLaunchKernelGGL(vmean_part_k, dim3(8,16), dim3(512), 0, stream, V, VPA, L);
    hipLaunchKernelGGL(vmean_comb_k, dim3(16), dim3(256), 0, stream, VPA, VME, L);
    hipLaunchKernelGGL(ctx_fill_k, dim3((unsigned)(Mr*2)), dim3(256), 0, stream, CTXh, VME, L);
    hipLaunchKernelGGL(ctx_scatter_k, dim3((unsigned)(16*n)), dim3(256), 0, stream, CTXh, UPD, TOPK, L, n);

    // out-proj + LN1
    gemm(CTXh, 0, WOH, 0, bo + (size_t)l*512, Y, nullptr, 0, Mr, 512, 512, 512, 0, 0, 0, 0, 0, mt, 4, 1);
    hipLaunchKernelGGL(add_ln_k, dim3((unsigned)Mr), dim3(256), 0, stream, X, Xh, Y, ln1w + (size_t)l*512, ln1b + (size_t)l*512);

    // FFN + LN2
    gemm(Xh, 0, F1H, 0, f1b + (size_t)l*2048, nullptr, FFh, 0, Mr, 2048, 2048, 512, 1, 0, 0, 0, 0, mt, 16, 1);
    gemm(FFh, 0, F2H, 0, f2b + (size_t)l*512, Y, nullptr, 0, Mr, 512, 512, 2048, 0, 0, 0, 0, 0, mt, 4, 1);
    hipLaunchKernelGGL(add_ln_k, dim3((unsigned)Mr), dim3(256), 0, stream, X, Xh, Y, ln2w + (size_t)l*512, ln2b + (size_t)l*512);

    // distilling conv (layers 0,1)
    if (l < 2){
      hipLaunchKernelGGL(convw_k, dim3(3072), dim3(256), 0, stream, cvw + (size_t)l*786432, WCVH);
      hipLaunchKernelGGL(im2col_k, dim3((unsigned)(Mr*6)), dim3(256), 0, stream, X, IM2, L);
      gemm(IM2, 0, WCVH, 0, cvb + (size_t)l*512, nullptr, CTXh, 0, Mr, 512, 512, 1536, 2,
           bnw + (size_t)l*512, bnb + (size_t)l*512, 0, 0, mt, 4, 1);
      int Lo = (L - 1)/2 + 1;
      hipLaunchKernelGGL(pool_k, dim3((unsigned)(8*Lo*2)), dim3(256), 0, stream, CTXh, X, Xh, L, Lo);
      L = Lo;
    }
  }

  hipLaunchKernelGGL(ln_gelu_k, dim3((unsigned)(8*L)), dim3(256), 0, stream, X, Y, nw, nb);
  hipLaunchKernelGGL(proj_k, dim3(80), dim3(256), 0, stream, Y, pw, pb, (float*)d_out);
}

// Round 6
// 1714.123 us; speedup vs baseline: 2.5951x; 1.1026x over previous
//
#include <hip/hip_runtime.h>
#include <math.h>
#include <stdint.h>

typedef __attribute__((ext_vector_type(8))) short bf16x8;
typedef __attribute__((ext_vector_type(4))) float f32x4;

// ---------------- helpers ----------------
__device__ __forceinline__ unsigned short f2bf(float f){
  unsigned int u = __float_as_uint(f);
  unsigned int r = (u + 0x7fffu + ((u>>16)&1u)) >> 16;
  return (unsigned short)r;
}
__device__ __forceinline__ float bf2f(unsigned short h){
  return __uint_as_float(((unsigned int)h)<<16);
}
__device__ __forceinline__ void gload16(const void* g, void* l){
  __builtin_amdgcn_global_load_lds(
      (const __attribute__((address_space(1))) unsigned int*)g,
      (__attribute__((address_space(3))) unsigned int*)l, 16, 0, 0);
}

// ---------------- Threefry-2x32 (exact JAX PRNG, partitionable) ----------------
__host__ __device__ static inline uint32_t rotl32(uint32_t x, int d){ return (x<<d)|(x>>(32-d)); }
__host__ __device__ static inline void tf2x32(uint32_t k0, uint32_t k1, uint32_t c0, uint32_t c1,
                                              uint32_t* o0, uint32_t* o1){
  uint32_t ks0=k0, ks1=k1, ks2=k0^k1^0x1BD11BDAu;
  uint32_t x0=c0+ks0, x1=c1+ks1;
  const int ra[4]={13,15,26,6}, rb[4]={17,29,16,24};
  #pragma unroll
  for(int i=0;i<4;i++){x0+=x1;x1=rotl32(x1,ra[i]);x1^=x0;}
  x0+=ks1; x1+=ks2+1u;
  #pragma unroll
  for(int i=0;i<4;i++){x0+=x1;x1=rotl32(x1,rb[i]);x1^=x0;}
  x0+=ks2; x1+=ks0+2u;
  #pragma unroll
  for(int i=0;i<4;i++){x0+=x1;x1=rotl32(x1,ra[i]);x1^=x0;}
  x0+=ks0; x1+=ks1+3u;
  #pragma unroll
  for(int i=0;i<4;i++){x0+=x1;x1=rotl32(x1,rb[i]);x1^=x0;}
  x0+=ks1; x1+=ks2+4u;
  #pragma unroll
  for(int i=0;i<4;i++){x0+=x1;x1=rotl32(x1,ra[i]);x1^=x0;}
  x0+=ks2; x1+=ks0+5u;
  *o0=x0; *o1=x1;
}

__global__ __launch_bounds__(256) void gen_idx_k(uint32_t k1a,uint32_t k1b,
                                                 uint32_t k2a,uint32_t k2b,
                                                 int size,uint32_t span,uint32_t mult,
                                                 int* __restrict__ idx){
  int i = blockIdx.x*256 + threadIdx.x;
  if (i >= size) return;
  uint32_t h0,h1,l0,l1;
  tf2x32(k1a,k1b,0u,(uint32_t)i,&h0,&h1);
  tf2x32(k2a,k2b,0u,(uint32_t)i,&l0,&l1);
  uint32_t hb = h0^h1, lb = l0^l1;
  idx[i] = (int)((((hb%span)*mult) + (lb%span)) % span);
}

// ---------------- token embedding + PE (writes fp32 X and bf16 Xh) ----------------
__global__ __launch_bounds__(256) void embed_k(const float* __restrict__ xe,
                                               const float* __restrict__ tw,
                                               float* __restrict__ X,
                                               short* __restrict__ Xh){
  int i = blockIdx.x*256 + threadIdx.x;     // over 8*1021*512
  int c = i & 511;
  int bl = i >> 9;
  int l = bl % 1021;
  int b = bl / 1021;
  float acc = 0.f;
  #pragma unroll
  for (int t=0;t<3;t++){
    int ls = l - 1 + t;
    ls = (ls < 0) ? 1020 : (ls >= 1021 ? 0 : ls);
    const float* xp = xe + (size_t)(b*1021 + ls)*12;
    const float* wp = tw + (size_t)c*36 + t;
    #pragma unroll
    for (int ci=0; ci<12; ci++) acc += xp[ci] * wp[ci*3];
  }
  int ip = c >> 1;
  float div = expf((float)(2*ip) * (float)(-9.210340371976184/512.0));
  float ang = (float)l * div;
  acc += (c & 1) ? cosf(ang) : sinf(ang);
  X[i] = acc;
  Xh[i] = f2bf(acc);
}

// ---------------- weight converts ----------------
__global__ __launch_bounds__(256) void wcvt_k(const float* __restrict__ src,
                                              short* __restrict__ dst, int n){
  int i = blockIdx.x*256 + threadIdx.x;
  if (i < n) dst[i] = f2bf(src[i]);
}
__global__ __launch_bounds__(256) void convw_k(const float* __restrict__ cw,
                                               short* __restrict__ W){
  int i = blockIdx.x*256 + threadIdx.x;   // 512*1536
  int col = i % 1536; int co = i / 1536;
  int t = col / 512; int ci = col % 512;
  W[i] = f2bf(cw[(size_t)co*1536 + ci*3 + t]);
}

// ---------------- bf16 MFMA GEMM: C = A(MxK) @ W^T(NxK), batched, epilogues ----------
// mode 0: +bias  1: +bias,GELU  2: +bias,BN,ELU  3: raw  4: *rowscale
__global__ __launch_bounds__(256) void gemm_bf16_k(
    const short* __restrict__ A, long Ab,
    const short* __restrict__ W, long Wb,
    const float* __restrict__ bias,
    float* __restrict__ Cf, short* __restrict__ Ch, long Cb,
    int M, int Nreal, int Nstride, int K, int mode,
    const float* __restrict__ s2, const float* __restrict__ b2,
    const float* __restrict__ rs, long rsb)
{
  __shared__ short As[4096];   // 128 x 32
  __shared__ short Bs[4096];
  const int t = threadIdx.x;
  const int lane = t & 63;
  const int w = t >> 6;
  const int wr = w >> 1, wc = w & 1;
  const int z = blockIdx.z;
  const int m0 = blockIdx.x * 128, n0 = blockIdx.y * 128;
  const short* Az = A + (size_t)z * Ab;
  const short* Wz = W + (size_t)z * Wb;

  f32x4 acc[4][4];
  #pragma unroll
  for (int i=0;i<4;i++)
    #pragma unroll
    for (int j=0;j<4;j++) acc[i][j] = (f32x4){0.f,0.f,0.f,0.f};

  const int r0  = t >> 2;          // staging row for slot t
  const int k80 = (t & 3) << 3;    // staging k-offset (elements)
  char* AsB = (char*)As;
  char* BsB = (char*)Bs;

  for (int k0 = 0; k0 < K; k0 += 32){
    gload16(Az + (size_t)(m0 + r0)      * K + k0 + k80, AsB + (size_t)w*1024);
    gload16(Az + (size_t)(m0 + r0 + 64) * K + k0 + k80, AsB + 4096 + (size_t)w*1024);
    gload16(Wz + (size_t)(n0 + r0)      * K + k0 + k80, BsB + (size_t)w*1024);
    gload16(Wz + (size_t)(n0 + r0 + 64) * K + k0 + k80, BsB + 4096 + (size_t)w*1024);
    __syncthreads();
    bf16x8 a[4], b[4];
    #pragma unroll
    for (int mi=0; mi<4; mi++){
      int aoff = (wr*64 + mi*16 + (lane&15))*32 + ((lane>>4)<<3);
      a[mi] = *(const bf16x8*)(&As[aoff]);
    }
    #pragma unroll
    for (int ni=0; ni<4; ni++){
      int boff = (wc*64 + ni*16 + (lane&15))*32 + ((lane>>4)<<3);
      b[ni] = *(const bf16x8*)(&Bs[boff]);
    }
    #pragma unroll
    for (int mi=0; mi<4; mi++)
      #pragma unroll
      for (int ni=0; ni<4; ni++)
        acc[mi][ni] = __builtin_amdgcn_mfma_f32_16x16x32_bf16(a[mi], b[ni], acc[mi][ni], 0, 0, 0);
    __syncthreads();
  }

  #pragma unroll
  for (int mi=0; mi<4; mi++){
    #pragma unroll
    for (int r=0; r<4; r++){
      int gm = m0 + wr*64 + mi*16 + ((lane>>4)<<2) + r;
      if (gm >= M) continue;
      float rsc = (mode==4) ? rs[(size_t)z*rsb + gm] : 0.f;
      #pragma unroll
      for (int ni=0; ni<4; ni++){
        int gn = n0 + wc*64 + ni*16 + (lane&15);
        if (gn >= Nreal) continue;
        float v = acc[mi][ni][r];
        if (mode <= 2) v += bias[gn];
        if (mode == 1){
          v = 0.5f*v*(1.0f + erff(v*0.707106781186547524f));
        } else if (mode == 2){
          v = v * (s2[gn]*0.9999950000374997f) + b2[gn];
          v = (v > 0.f) ? v : expm1f(v);
        } else if (mode == 4){
          v *= rsc;
        }
        size_t off = (size_t)z*Cb + (size_t)gm*Nstride + gn;
        if (Cf) Cf[off] = v;
        if (Ch) Ch[off] = f2bf(v);
      }
    }
  }
}

// ---------------- sampled dots: one thread per (bh,l,s), fp32 float4 dot ----------------
__global__ __launch_bounds__(256) void qk_dot_k(const float* __restrict__ Q,
                                                const float* __restrict__ Kb,
                                                const int* __restrict__ idx,
                                                float* __restrict__ QK, int L, int n){
  long gi = (long)blockIdx.x*256 + threadIdx.x;   // over 64*L*n, layout (bh, l, s)
  long total = (long)64*L*n;
  if (gi >= total) return;
  int s = (int)(gi % n); long t2 = gi / n;
  int l = (int)(t2 % L); int bh = (int)(t2 / L);
  int h = bh & 7, b = bh >> 3;
  const float4* qp = (const float4*)(Q + (size_t)(b*L + l)*512 + h*64);
  int kr = idx[l*n + s];
  const float4* kp = (const float4*)(Kb + (size_t)(b*L + kr)*512 + h*64);
  float dot = 0.f;
  #pragma unroll
  for (int i=0;i<16;i++){
    float4 a = qp[i], c = kp[i];
    dot += a.x*c.x + a.y*c.y + a.z*c.z + a.w*c.w;
  }
  QK[gi] = dot;
}

// ---------------- m = max_s - sum_s/L over contiguous rows of n ----------------
__global__ __launch_bounds__(256) void reduce_m_k(const float* __restrict__ QK,
                                                  float* __restrict__ Mout, int L, int n){
  int gi = blockIdx.x*256 + threadIdx.x;   // over 64*L
  if (gi >= 64*L) return;
  int l = gi % L; int bh = gi / L;
  const float* row = QK + (size_t)gi*n;
  float mx = -INFINITY, sm = 0.f;
  for (int s=0;s<n;s++){ float v = row[s]; mx = fmaxf(mx, v); sm += v; }
  Mout[(size_t)bh*1024 + l] = mx - sm/(float)L;
}

// ---------------- top-k (single wave per bh, tie -> lower index) ----------------
__global__ __launch_bounds__(64) void topk_k(const float* __restrict__ Mv,
                                             int* __restrict__ topk, int L, int n){
  int bh = blockIdx.x; int lane = threadIdx.x;
  float v[16];
  #pragma unroll
  for (int i=0;i<16;i++){ int l = i*64 + lane; v[i] = (l<L) ? Mv[(size_t)bh*1024 + l] : -INFINITY; }
  for (int it=0; it<n; ++it){
    float bv = -INFINITY; int bi = 0x7fffffff;
    #pragma unroll
    for (int i=0;i<16;i++){ int l = i*64+lane; if (v[i] > bv){ bv = v[i]; bi = l; } }
    #pragma unroll
    for (int o=32;o>0;o>>=1){
      float ov = __shfl_xor(bv, o); int oi = __shfl_xor(bi, o);
      if (ov > bv || (ov == bv && oi < bi)){ bv = ov; bi = oi; }
    }
    if (lane == 0) topk[bh*n + it] = bi;
    int wl = bi & 63, wi = bi >> 6;
    if (lane == wl){
      #pragma unroll
      for (int i=0;i<16;i++) if (i == wi) v[i] = -INFINITY;
    }
  }
}

// ---------------- Qred gather (scaled by 1/8, bf16) ----------------
__global__ __launch_bounds__(64) void qred_k(const float* __restrict__ Q,
                                             const int* __restrict__ topk,
                                             short* __restrict__ Qrh, int L, int n){
  int u = blockIdx.x % n; int bh = blockIdx.x / n;
  int h = bh & 7, b = bh >> 3; int d = threadIdx.x;
  int lq = topk[bh*n + u];
  Qrh[(size_t)bh*8192 + u*64 + d] = f2bf(0.125f * Q[(size_t)(b*L + lq)*512 + h*64 + d]);
}

// ---------------- K head-gather to bf16 [bh][1024][64] ----------------
__global__ __launch_bounds__(256) void kh_k(const float* __restrict__ Kb,
                                            short* __restrict__ Kh, int L){
  int i = blockIdx.x*256 + threadIdx.x;  // 64*1024*64
  int d = i & 63; int l = (i>>6) & 1023; int bh = i >> 16;
  int h = bh & 7, b = bh >> 3;
  Kh[i] = (l < L) ? f2bf(Kb[(size_t)(b*L + l)*512 + h*64 + d]) : (short)0;
}

// ---------------- V transpose to bf16 [bh][128pad d][1024 l] ----------------
__global__ __launch_bounds__(256) void vt_k(const float* __restrict__ V,
                                            short* __restrict__ Vt, int L){
  __shared__ float ts[64][65];
  int z = blockIdx.x >> 4;
  int l0 = (blockIdx.x & 15) * 64;
  int h = z & 7, b = z >> 3;
  int t = threadIdx.x;
  for (int i = t; i < 4096; i += 256){
    int lloc = i >> 6, d = i & 63;
    int l = l0 + lloc;
    ts[d][lloc] = (l < L) ? V[(size_t)(b*L + l)*512 + h*64 + d] : 0.f;
  }
  __syncthreads();
  for (int i = t; i < 4096; i += 256){
    int d = i >> 6, lloc = i & 63;
    Vt[(size_t)z*131072 + (size_t)d*1024 + l0 + lloc] = f2bf(ts[d][lloc]);
  }
}

// ---------------- softmax on S rows -> bf16 P, 1/sum ----------------
__global__ __launch_bounds__(256) void softmax_k(const float* __restrict__ S,
                                                 short* __restrict__ Ph,
                                                 float* __restrict__ RS, int L, int n){
  int u = blockIdx.x % n; int z = blockIdx.x / n;
  const float* srow = S + (size_t)z*n*1024 + (size_t)u*1024;
  short* prow = Ph + (size_t)z*131072 + (size_t)u*1024;
  int t = threadIdx.x;
  __shared__ float red[256];
  float lm = -INFINITY;
  for (int l=t; l<L; l+=256) lm = fmaxf(lm, srow[l]);
  red[t]=lm; __syncthreads();
  for (int o=128;o>0;o>>=1){ if(t<o) red[t]=fmaxf(red[t],red[t+o]); __syncthreads(); }
  float mx = red[0]; __syncthreads();
  float ls = 0.f;
  for (int l=t; l<1024; l+=256){
    float p = (l < L) ? expf(srow[l]-mx) : 0.f;
    prow[l] = f2bf(p);
    ls += p;
  }
  red[t]=ls; __syncthreads();
  for (int o=128;o>0;o>>=1){ if(t<o) red[t]+=red[t+o]; __syncthreads(); }
  if (t==0) RS[(size_t)z*n + u] = 1.0f/red[0];
}

// ---------------- v mean ----------------
__global__ __launch_bounds__(512) void vmean_part_k(const float* __restrict__ V,
                                                    float* __restrict__ part, int L){
  int b = blockIdx.x; int j = blockIdx.y; int c = threadIdx.x;
  float s = 0.f;
  for (int l = j; l < L; l += 16) s += V[(size_t)(b*L + l)*512 + c];
  part[(size_t)(b*16 + j)*512 + c] = s;
}
__global__ __launch_bounds__(256) void vmean_comb_k(const float* __restrict__ part,
                                                    float* __restrict__ vmean, int L){
  int i = blockIdx.x*256 + threadIdx.x;
  int b = i >> 9; int c = i & 511;
  float s = 0.f;
  #pragma unroll
  for (int j=0;j<16;j++) s += part[(size_t)(b*16 + j)*512 + c];
  vmean[i] = s / (float)L;
}
__global__ __launch_bounds__(256) void ctx_fill_k(short* __restrict__ CTXh,
                                                  const float* __restrict__ vmean, int L){
  int i = blockIdx.x*256 + threadIdx.x;
  int c = i & 511; int bl = i >> 9; int b = bl / L;
  CTXh[i] = f2bf(vmean[b*512 + c]);
}
__global__ __launch_bounds__(256) void ctx_scatter_k(short* __restrict__ CTXh,
                                                     const float* __restrict__ UPD,
                                                     const int* __restrict__ topk, int L, int n){
  int i = blockIdx.x*256 + threadIdx.x;   // 64*n*64
  int d = i & 63; int u = (i >> 6) % n; int bh = i / (64*n);
  int h = bh & 7; int b = bh >> 3;
  int lq = topk[bh*n + u];
  CTXh[(size_t)(b*L + lq)*512 + h*64 + d] = f2bf(UPD[((size_t)bh*n + u)*64 + d]);
}

// ---------------- residual add + LayerNorm (X fp32 + Xh bf16) ----------------
__global__ __launch_bounds__(256) void add_ln_k(float* __restrict__ X,
                                                short* __restrict__ Xh,
                                                const float* __restrict__ Y,
                                                const float* __restrict__ w,
                                                const float* __restrict__ b){
  int r = blockIdx.x;
  size_t base = (size_t)r*512;
  int t = threadIdx.x;
  float v0 = X[base+t]     + Y[base+t];
  float v1 = X[base+t+256] + Y[base+t+256];
  __shared__ float red[256];
  red[t] = v0 + v1; __syncthreads();
  for (int o=128;o>0;o>>=1){ if(t<o) red[t]+=red[t+o]; __syncthreads(); }
  float mu = red[0]*(1.f/512.f); __syncthreads();
  float d0 = v0-mu, d1 = v1-mu;
  red[t] = d0*d0 + d1*d1; __syncthreads();
  for (int o=128;o>0;o>>=1){ if(t<o) red[t]+=red[t+o]; __syncthreads(); }
  float rs = 1.0f/sqrtf(red[0]*(1.f/512.f) + 1e-5f);
  float x0 = d0*rs*w[t]     + b[t];
  float x1 = d1*rs*w[t+256] + b[t+256];
  X[base+t]     = x0;  Xh[base+t]     = f2bf(x0);
  X[base+t+256] = x1;  Xh[base+t+256] = f2bf(x1);
}

// ---------------- final LayerNorm + GELU ----------------
__global__ __launch_bounds__(256) void ln_gelu_k(const float* __restrict__ X,
                                                 float* __restrict__ Yout,
                                                 const float* __restrict__ w,
                                                 const float* __restrict__ b){
  int r = blockIdx.x;
  size_t base = (size_t)r*512;
  int t = threadIdx.x;
  float v0 = X[base+t];
  float v1 = X[base+t+256];
  __shared__ float red[256];
  red[t] = v0 + v1; __syncthreads();
  for (int o=128;o>0;o>>=1){ if(t<o) red[t]+=red[t+o]; __syncthreads(); }
  float mu = red[0]*(1.f/512.f); __syncthreads();
  float d0 = v0-mu, d1 = v1-mu;
  red[t] = d0*d0 + d1*d1; __syncthreads();
  for (int o=128;o>0;o>>=1){ if(t<o) red[t]+=red[t+o]; __syncthreads(); }
  float rs = 1.0f/sqrtf(red[0]*(1.f/512.f) + 1e-5f);
  float g0 = d0*rs*w[t]     + b[t];
  float g1 = d1*rs*w[t+256] + b[t+256];
  Yout[base+t]     = 0.5f*g0*(1.0f + erff(g0*0.707106781186547524f));
  Yout[base+t+256] = 0.5f*g1*(1.0f + erff(g1*0.707106781186547524f));
}

// ---------------- conv helpers ----------------
__global__ __launch_bounds__(256) void im2col_k(const float* __restrict__ X,
                                                short* __restrict__ O, int L){
  int i = blockIdx.x*256 + threadIdx.x;   // 8*L*1536
  int col = i % 1536; int bl = i / 1536;
  int l = bl % L; int b = bl / L;
  int t = col / 512; int ci = col % 512;
  int ls = l - 1 + t;
  ls = (ls < 0) ? (L-1) : (ls >= L ? 0 : ls);
  O[(size_t)bl*1536 + col] = f2bf(X[(size_t)(b*L + ls)*512 + ci]);
}
__global__ __launch_bounds__(256) void pool_k(const short* __restrict__ Hc,
                                              float* __restrict__ X,
                                              short* __restrict__ Xh, int L, int Lo){
  int i = blockIdx.x*256 + threadIdx.x;   // 8*Lo*512
  int c = i & 511; int r = i >> 9; int lo = r % Lo; int b = r / Lo;
  float m = -INFINITY;
  #pragma unroll
  for (int dt=-1; dt<=1; dt++){
    int li = 2*lo + dt;
    if (li >= 0 && li < L) m = fmaxf(m, bf2f((unsigned short)Hc[(size_t)(b*L + li)*512 + c]));
  }
  size_t o = (size_t)(b*Lo + lo)*512 + c;
  X[o] = m; Xh[o] = f2bf(m);
}

// ---------------- split-K final projection ----------------
// grid (8 b x 32 chunks), 256 threads; each thread holds 16 x floats, loops 10 classes
__global__ __launch_bounds__(256) void proj_part_k(const float* __restrict__ Xg,
                                                   const float* __restrict__ pw,
                                                   float* __restrict__ part){
  int b = blockIdx.x >> 5;
  int c = blockIdx.x & 31;
  int t = threadIdx.x;
  const float4* xp = (const float4*)(Xg + (size_t)b*131072 + (size_t)c*4096);
  float4 x0 = xp[t], x1 = xp[t+256], x2 = xp[t+512], x3 = xp[t+768];
  float acc[10];
  #pragma unroll
  for (int j=0;j<10;j++){
    const float4* wp = (const float4*)(pw + (size_t)j*131072 + (size_t)c*4096);
    float4 w0 = wp[t], w1 = wp[t+256], w2 = wp[t+512], w3 = wp[t+768];
    acc[j] = x0.x*w0.x + x0.y*w0.y + x0.z*w0.z + x0.w*w0.w
           + x1.x*w1.x + x1.y*w1.y + x1.z*w1.z + x1.w*w1.w
           + x2.x*w2.x + x2.y*w2.y + x2.z*w2.z + x2.w*w2.w
           + x3.x*w3.x + x3.y*w3.y + x3.z*w3.z + x3.w*w3.w;
  }
  __shared__ float red[256];
  #pragma unroll
  for (int j=0;j<10;j++){
    red[t] = acc[j]; __syncthreads();
    for (int o=128;o>0;o>>=1){ if(t<o) red[t]+=red[t+o]; __syncthreads(); }
    if (t==0) part[(b*10 + j)*32 + c] = red[0];
    __syncthreads();
  }
}
__global__ __launch_bounds__(128) void proj_comb_k(const float* __restrict__ part,
                                                   const float* __restrict__ pb,
                                                   float* __restrict__ out){
  int t = threadIdx.x;
  if (t >= 80) return;
  int j = t % 10;
  const float* p = part + t*32;
  float s = 0.f;
  #pragma unroll
  for (int c=0;c<32;c++) s += p[c];
  out[t] = s + pb[j];
}

extern "C" void kernel_launch(void* const* d_in, const int* in_sizes, int n_in,
                              void* d_out, int out_size, void* d_ws, size_t ws_size,
                              hipStream_t stream){
  (void)in_sizes; (void)n_in; (void)out_size; (void)ws_size;
  const float* x_enc = (const float*)d_in[0];
  const float* tok_w = (const float*)d_in[1];
  const float* wq    = (const float*)d_in[2];
  const float* bq    = (const float*)d_in[3];
  const float* wk    = (const float*)d_in[4];
  const float* bk    = (const float*)d_in[5];
  const float* wvp   = (const float*)d_in[6];
  const float* bvp   = (const float*)d_in[7];
  const float* wo    = (const float*)d_in[8];
  const float* bo    = (const float*)d_in[9];
  const float* ln1w  = (const float*)d_in[10];
  const float* ln1b  = (const float*)d_in[11];
  const float* ln2w  = (const float*)d_in[12];
  const float* ln2b  = (const float*)d_in[13];
  const float* f1w   = (const float*)d_in[14];
  const float* f1b   = (const float*)d_in[15];
  const float* f2w   = (const float*)d_in[16];
  const float* f2b   = (const float*)d_in[17];
  const float* cvw   = (const float*)d_in[18];
  const float* cvb   = (const float*)d_in[19];
  const float* bnw   = (const float*)d_in[20];
  const float* bnb   = (const float*)d_in[21];
  const float* nw    = (const float*)d_in[22];
  const float* nb    = (const float*)d_in[23];
  const float* pw    = (const float*)d_in[24];
  const float* pb    = (const float*)d_in[25];

  char* wsb = (char*)d_ws;
  float* X    = (float*)(wsb + 0);            // 8192x512 f32
  float* Y    = (float*)(wsb + 16777216);     // 8192x512 f32
  float* Q    = (float*)(wsb + 33554432);
  float* Kbuf = (float*)(wsb + 50331648);
  float* V    = (float*)(wsb + 67108864);
  short* Xh   = (short*)(wsb + 83886080);     // 8192x512 bf16
  short* CTXh = (short*)(wsb + 92274688);     // 8192x512 bf16
  short* WQH  = (short*)(wsb + 100663296);
  short* WKH  = WQH + 262144;
  short* WVH  = WKH + 262144;
  short* WOH  = WVH + 262144;
  short* F1H  = WOH + 262144;                 // 2048x512
  short* F2H  = F1H + 1048576;                // 512x2048
  short* WCVH = F2H + 1048576;                // 512x1536
  char*  RB   = wsb + 108527616;              // shared region (58.7MB)
  short* FFh  = (short*)(RB);                 // 8192x2048 bf16 (FFN phase)
  short* IM2  = (short*)(RB + 33554432);      // 8192x1536 bf16 (conv phase)
  short* Kh   = (short*)(RB + 0);             // [64][1024][64] bf16 (attn phase)
  short* Vt   = (short*)(RB + 8388608);       // [64][128][1024] bf16
  short* Ph   = (short*)(RB + 25165824);      // [64][128][1024] bf16
  short* Qrh  = (short*)(RB + 41943040);      // [64][128][64] bf16
  float* S    = (float*)(RB + 42991616);      // [64][35][1024] f32 (also QK dots)
  float* RS   = (float*)(RB + 52166656);      // [64][35] f32
  float* UPD  = (float*)(RB + 52175616);      // [64][35][64] f32
  float* Mb   = (float*)(RB + 52749056);      // [64][1024] f32
  float* VME  = (float*)(RB + 53011200);
  float* VPA  = (float*)(RB + 53027584);
  int*   IDX  = (int*)  (RB + 53289728);
  int*   TOPK = (int*)  (RB + 53433088);
  float* PPART= (float*)(RB + 53450752);      // [8][10][32] f32

  // JAX partitionable key derivation (host)
  uint32_t rka[3], rkb[3];
  for (int l = 0; l < 3; ++l) tf2x32(0u, 42u, 0u, (uint32_t)l, &rka[l], &rkb[l]);

  auto gemm = [&](const short* A, long Ab, const short* W, long Wb, const float* bias,
                  float* Cf, short* Ch, long Cb, int M, int Nreal, int Nstride, int K,
                  int mode, const float* s2, const float* b2, const float* rs, long rsb,
                  int mt, int nt, int zt){
    hipLaunchKernelGGL(gemm_bf16_k, dim3(mt, nt, zt), dim3(256), 0, stream,
                       A, Ab, W, Wb, bias, Cf, Ch, Cb, M, Nreal, Nstride, K, mode,
                       s2, b2, rs, rsb);
  };

  hipLaunchKernelGGL(embed_k, dim3(16336), dim3(256), 0, stream, x_enc, tok_w, X, Xh);

  int L = 1021;
  for (int l = 0; l < 3; ++l){
    int n = 5 * (int)ceil(log((double)L)); if (n > L) n = L;
    int Mr = 8 * L;
    int mt = (Mr + 127)/128;

    // weight converts (bf16)
    hipLaunchKernelGGL(wcvt_k, dim3(1024), dim3(256), 0, stream, wq + (size_t)l*262144, WQH, 262144);
    hipLaunchKernelGGL(wcvt_k, dim3(1024), dim3(256), 0, stream, wk + (size_t)l*262144, WKH, 262144);
    hipLaunchKernelGGL(wcvt_k, dim3(1024), dim3(256), 0, stream, wvp+ (size_t)l*262144, WVH, 262144);
    hipLaunchKernelGGL(wcvt_k, dim3(1024), dim3(256), 0, stream, wo + (size_t)l*262144, WOH, 262144);
    hipLaunchKernelGGL(wcvt_k, dim3(4096), dim3(256), 0, stream, f1w+ (size_t)l*1048576, F1H, 1048576);
    hipLaunchKernelGGL(wcvt_k, dim3(4096), dim3(256), 0, stream, f2w+ (size_t)l*1048576, F2H, 1048576);

    // random sample indices
    uint32_t k1a,k1b,k2a,k2b;
    tf2x32(rka[l], rkb[l], 0u, 0u, &k1a, &k1b);
    tf2x32(rka[l], rkb[l], 0u, 1u, &k2a, &k2b);
    int size = L * n;
    uint32_t span = (uint32_t)L;
    uint32_t rr = 65536u % span;
    uint32_t mult = (rr * rr) % span;
    hipLaunchKernelGGL(gen_idx_k, dim3((unsigned)((size+255)/256)), dim3(256), 0, stream,
                       k1a, k1b, k2a, k2b, size, span, mult, IDX);

    // QKV (bf16 MFMA, fp32 out)
    gemm(Xh, 0, WQH, 0, bq + (size_t)l*512, Q,    nullptr, 0, Mr, 512, 512, 512, 0, 0, 0, 0, 0, mt, 4, 1);
    gemm(Xh, 0, WKH, 0, bk + (size_t)l*512, Kbuf, nullptr, 0, Mr, 512, 512, 512, 0, 0, 0, 0, 0, mt, 4, 1);
    gemm(Xh, 0, WVH, 0, bvp+ (size_t)l*512, V,    nullptr, 0, Mr, 512, 512, 512, 0, 0, 0, 0, 0, mt, 4, 1);

    // sampled dots (thread-per-(l,s)) then m-reduce, top-k
    long tot = (long)64*L*n;
    hipLaunchKernelGGL(qk_dot_k, dim3((unsigned)((tot+255)/256)), dim3(256), 0, stream,
                       Q, Kbuf, IDX, S, L, n);
    hipLaunchKernelGGL(reduce_m_k, dim3((unsigned)((64*L+255)/256)), dim3(256), 0, stream,
                       S, Mb, L, n);
    hipLaunchKernelGGL(topk_k, dim3(64), dim3(64), 0, stream, Mb, TOPK, L, n);

    // attention: gather -> scores GEMM -> softmax -> PV GEMM
    hipLaunchKernelGGL(qred_k, dim3((unsigned)(64*n)), dim3(64), 0, stream, Q, TOPK, Qrh, L, n);
    hipLaunchKernelGGL(kh_k, dim3(16384), dim3(256), 0, stream, Kbuf, Kh, L);
    hipLaunchKernelGGL(vt_k, dim3(1024), dim3(256), 0, stream, V, Vt, L);
    gemm(Qrh, 8192, Kh, 65536, nullptr, S, nullptr, (long)n*1024, n, L, 1024, 64, 3, 0, 0, 0, 0, 1, 8, 64);
    hipLaunchKernelGGL(softmax_k, dim3((unsigned)(64*n)), dim3(256), 0, stream, S, Ph, RS, L, n);
    gemm(Ph, 131072, Vt, 131072, nullptr, UPD, nullptr, (long)n*64, n, 64, 64, 1024, 4, 0, 0, RS, n, 1, 1, 64);

    // ctx = broadcast mean(v) with top-k rows replaced (bf16)
    hipLaunchKernelGGL(vmean_part_k, dim3(8,16), dim3(512), 0, stream, V, VPA, L);
    hipLaunchKernelGGL(vmean_comb_k, dim3(16), dim3(256), 0, stream, VPA, VME, L);
    hipLaunchKernelGGL(ctx_fill_k, dim3((unsigned)(Mr*2)), dim3(256), 0, stream, CTXh, VME, L);
    hipLaunchKernelGGL(ctx_scatter_k, dim3((unsigned)(16*n)), dim3(256), 0, stream, CTXh, UPD, TOPK, L, n);

    // out-proj + LN1
    gemm(CTXh, 0, WOH, 0, bo + (size_t)l*512, Y, nullptr, 0, Mr, 512, 512, 512, 0, 0, 0, 0, 0, mt, 4, 1);
    hipLaunchKernelGGL(add_ln_k, dim3((unsigned)Mr), dim3(256), 0, stream, X, Xh, Y, ln1w + (size_t)l*512, ln1b + (size_t)l*512);

    // FFN + LN2
    gemm(Xh, 0, F1H, 0, f1b + (size_t)l*2048, nullptr, FFh, 0, Mr, 2048, 2048, 512, 1, 0, 0, 0, 0, mt, 16, 1);
    gemm(FFh, 0, F2H, 0, f2b + (size_t)l*512, Y, nullptr, 0, Mr, 512, 512, 2048, 0, 0, 0, 0, 0, mt, 4, 1);
    hipLaunchKernelGGL(add_ln_k, dim3((unsigned)Mr), dim3(256), 0, stream, X, Xh, Y, ln2w + (size_t)l*512, ln2b + (size_t)l*512);

    // distilling conv (layers 0,1)
    if (l < 2){
      hipLaunchKernelGGL(convw_k, dim3(3072), dim3(256), 0, stream, cvw + (size_t)l*786432, WCVH);
      hipLaunchKernelGGL(im2col_k, dim3((unsigned)(Mr*6)), dim3(256), 0, stream, X, IM2, L);
      gemm(IM2, 0, WCVH, 0, cvb + (size_t)l*512, nullptr, CTXh, 0, Mr, 512, 512, 1536, 2,
           bnw + (size_t)l*512, bnb + (size_t)l*512, 0, 0, mt, 4, 1);
      int Lo = (L - 1)/2 + 1;
      hipLaunchKernelGGL(pool_k, dim3((unsigned)(8*Lo*2)), dim3(256), 0, stream, CTXh, X, Xh, L, Lo);
      L = Lo;
    }
  }

  hipLaunchKernelGGL(ln_gelu_k, dim3((unsigned)(8*L)), dim3(256), 0, stream, X, Y, nw, nb);
  hipLaunchKernelGGL(proj_part_k, dim3(256), dim3(256), 0, stream, Y, pw, PPART);
  hipLaunchKernelGGL(proj_comb_k, dim3(1), dim3(128), 0, stream, PPART, pb, (float*)d_out);
}

// Round 7
// 1685.449 us; speedup vs baseline: 2.6393x; 1.0170x over previous
//
#include <hip/hip_runtime.h>
#include <math.h>
#include <stdint.h>

typedef __attribute__((ext_vector_type(8))) short bf16x8;
typedef __attribute__((ext_vector_type(4))) float f32x4;

// ---------------- helpers ----------------
__device__ __forceinline__ unsigned short f2bf(float f){
  unsigned int u = __float_as_uint(f);
  unsigned int r = (u + 0x7fffu + ((u>>16)&1u)) >> 16;
  return (unsigned short)r;
}
__device__ __forceinline__ float bf2f(unsigned short h){
  return __uint_as_float(((unsigned int)h)<<16);
}
__device__ __forceinline__ void gload16(const void* g, void* l){
  __builtin_amdgcn_global_load_lds(
      (const __attribute__((address_space(1))) unsigned int*)g,
      (__attribute__((address_space(3))) unsigned int*)l, 16, 0, 0);
}

// ---------------- Threefry-2x32 (exact JAX PRNG, partitionable) ----------------
__host__ __device__ static inline uint32_t rotl32(uint32_t x, int d){ return (x<<d)|(x>>(32-d)); }
__host__ __device__ static inline void tf2x32(uint32_t k0, uint32_t k1, uint32_t c0, uint32_t c1,
                                              uint32_t* o0, uint32_t* o1){
  uint32_t ks0=k0, ks1=k1, ks2=k0^k1^0x1BD11BDAu;
  uint32_t x0=c0+ks0, x1=c1+ks1;
  const int ra[4]={13,15,26,6}, rb[4]={17,29,16,24};
  #pragma unroll
  for(int i=0;i<4;i++){x0+=x1;x1=rotl32(x1,ra[i]);x1^=x0;}
  x0+=ks1; x1+=ks2+1u;
  #pragma unroll
  for(int i=0;i<4;i++){x0+=x1;x1=rotl32(x1,rb[i]);x1^=x0;}
  x0+=ks2; x1+=ks0+2u;
  #pragma unroll
  for(int i=0;i<4;i++){x0+=x1;x1=rotl32(x1,ra[i]);x1^=x0;}
  x0+=ks0; x1+=ks1+3u;
  #pragma unroll
  for(int i=0;i<4;i++){x0+=x1;x1=rotl32(x1,rb[i]);x1^=x0;}
  x0+=ks1; x1+=ks2+4u;
  #pragma unroll
  for(int i=0;i<4;i++){x0+=x1;x1=rotl32(x1,ra[i]);x1^=x0;}
  x0+=ks2; x1+=ks0+5u;
  *o0=x0; *o1=x1;
}

__global__ __launch_bounds__(256) void gen_idx_k(uint32_t k1a,uint32_t k1b,
                                                 uint32_t k2a,uint32_t k2b,
                                                 int size,uint32_t span,uint32_t mult,
                                                 int* __restrict__ idx){
  int i = blockIdx.x*256 + threadIdx.x;
  if (i >= size) return;
  uint32_t h0,h1,l0,l1;
  tf2x32(k1a,k1b,0u,(uint32_t)i,&h0,&h1);
  tf2x32(k2a,k2b,0u,(uint32_t)i,&l0,&l1);
  uint32_t hb = h0^h1, lb = l0^l1;
  idx[i] = (int)((((hb%span)*mult) + (lb%span)) % span);
}

// ---------------- token embedding + PE (writes fp32 X and bf16 Xh) ----------------
__global__ __launch_bounds__(256) void embed_k(const float* __restrict__ xe,
                                               const float* __restrict__ tw,
                                               float* __restrict__ X,
                                               short* __restrict__ Xh){
  int i = blockIdx.x*256 + threadIdx.x;     // over 8*1021*512
  int c = i & 511;
  int bl = i >> 9;
  int l = bl % 1021;
  int b = bl / 1021;
  float acc = 0.f;
  #pragma unroll
  for (int t=0;t<3;t++){
    int ls = l - 1 + t;
    ls = (ls < 0) ? 1020 : (ls >= 1021 ? 0 : ls);
    const float* xp = xe + (size_t)(b*1021 + ls)*12;
    const float* wp = tw + (size_t)c*36 + t;
    #pragma unroll
    for (int ci=0; ci<12; ci++) acc += xp[ci] * wp[ci*3];
  }
  int ip = c >> 1;
  float div = expf((float)(2*ip) * (float)(-9.210340371976184/512.0));
  float ang = (float)l * div;
  acc += (c & 1) ? cosf(ang) : sinf(ang);
  X[i] = acc;
  Xh[i] = f2bf(acc);
}

// ---------------- weight converts ----------------
__global__ __launch_bounds__(256) void wcvt_k(const float* __restrict__ src,
                                              short* __restrict__ dst, int n){
  int i = blockIdx.x*256 + threadIdx.x;
  if (i < n) dst[i] = f2bf(src[i]);
}
__global__ __launch_bounds__(256) void convw_k(const float* __restrict__ cw,
                                               short* __restrict__ W){
  int i = blockIdx.x*256 + threadIdx.x;   // 512*1536
  int col = i % 1536; int co = i / 1536;
  int t = col / 512; int ci = col % 512;
  W[i] = f2bf(cw[(size_t)co*1536 + ci*3 + t]);
}

// ---------------- bf16 MFMA GEMM (double-buffered LDS): C = A @ W^T, batched ----------
// mode 0: +bias  1: +bias,GELU  2: +bias,BN,ELU  3: raw  4: *rowscale
// KhG != nullptr: also write bf16 head-gathered copy [b][h][1024 l][64 d] (needs Lq)
__global__ __launch_bounds__(256) void gemm_bf16_k(
    const short* __restrict__ A, long Ab,
    const short* __restrict__ W, long Wb,
    const float* __restrict__ bias,
    float* __restrict__ Cf, short* __restrict__ Ch, long Cb,
    int M, int Nreal, int Nstride, int K, int mode,
    const float* __restrict__ s2, const float* __restrict__ b2,
    const float* __restrict__ rs, long rsb,
    short* __restrict__ KhG, int Lq)
{
  __shared__ short As[8192];   // 2 buffers x 128 x 32
  __shared__ short Bs[8192];
  const int t = threadIdx.x;
  const int lane = t & 63;
  const int w = t >> 6;
  const int wr = w >> 1, wc = w & 1;
  const int z = blockIdx.z;
  const int m0 = blockIdx.x * 128, n0 = blockIdx.y * 128;
  const short* Az = A + (size_t)z * Ab;
  const short* Wz = W + (size_t)z * Wb;

  f32x4 acc[4][4];
  #pragma unroll
  for (int i=0;i<4;i++)
    #pragma unroll
    for (int j=0;j<4;j++) acc[i][j] = (f32x4){0.f,0.f,0.f,0.f};

  const int r0  = t >> 2;          // staging row for slot t
  const int k80 = (t & 3) << 3;    // staging k-offset (elements)
  char* AsB = (char*)As;
  char* BsB = (char*)Bs;

  #define STAGE(buf, k0) do { \
    gload16(Az + (size_t)(m0 + r0)      * K + (k0) + k80, AsB + (buf)*8192 + (size_t)w*1024); \
    gload16(Az + (size_t)(m0 + r0 + 64) * K + (k0) + k80, AsB + (buf)*8192 + 4096 + (size_t)w*1024); \
    gload16(Wz + (size_t)(n0 + r0)      * K + (k0) + k80, BsB + (buf)*8192 + (size_t)w*1024); \
    gload16(Wz + (size_t)(n0 + r0 + 64) * K + (k0) + k80, BsB + (buf)*8192 + 4096 + (size_t)w*1024); \
  } while(0)

  STAGE(0, 0);
  __syncthreads();
  int cur = 0;
  for (int k0 = 0; k0 < K; k0 += 32){
    if (k0 + 32 < K) STAGE(cur^1, k0+32);
    bf16x8 a[4], b[4];
    #pragma unroll
    for (int mi=0; mi<4; mi++){
      int aoff = cur*4096 + (wr*64 + mi*16 + (lane&15))*32 + ((lane>>4)<<3);
      a[mi] = *(const bf16x8*)(&As[aoff]);
    }
    #pragma unroll
    for (int ni=0; ni<4; ni++){
      int boff = cur*4096 + (wc*64 + ni*16 + (lane&15))*32 + ((lane>>4)<<3);
      b[ni] = *(const bf16x8*)(&Bs[boff]);
    }
    #pragma unroll
    for (int mi=0; mi<4; mi++)
      #pragma unroll
      for (int ni=0; ni<4; ni++)
        acc[mi][ni] = __builtin_amdgcn_mfma_f32_16x16x32_bf16(a[mi], b[ni], acc[mi][ni], 0, 0, 0);
    __syncthreads();   // drains STAGE (compiler vmcnt) + protects cur buffer
    cur ^= 1;
  }
  #undef STAGE

  #pragma unroll
  for (int mi=0; mi<4; mi++){
    #pragma unroll
    for (int r=0; r<4; r++){
      int gm = m0 + wr*64 + mi*16 + ((lane>>4)<<2) + r;
      if (gm >= M) continue;
      float rsc = (mode==4) ? rs[(size_t)z*rsb + gm] : 0.f;
      int bb = 0, ll = 0;
      if (KhG){ bb = gm / Lq; ll = gm - bb*Lq; }
      #pragma unroll
      for (int ni=0; ni<4; ni++){
        int gn = n0 + wc*64 + ni*16 + (lane&15);
        if (gn >= Nreal) continue;
        float v = acc[mi][ni][r];
        if (mode <= 2) v += bias[gn];
        if (mode == 1){
          v = 0.5f*v*(1.0f + erff(v*0.707106781186547524f));
        } else if (mode == 2){
          v = v * (s2[gn]*0.9999950000374997f) + b2[gn];
          v = (v > 0.f) ? v : expm1f(v);
        } else if (mode == 4){
          v *= rsc;
        }
        size_t off = (size_t)z*Cb + (size_t)gm*Nstride + gn;
        if (Cf) Cf[off] = v;
        if (Ch) Ch[off] = f2bf(v);
        if (KhG) KhG[(((size_t)bb*8 + (gn>>6))*1024 + ll)*64 + (gn&63)] = f2bf(v);
      }
    }
  }
}

// ---------------- sampled dots: block per (b,l), LDS-staged Q, thread per (h,s) -------
__global__ __launch_bounds__(320) void qk_dot_k(const float* __restrict__ Q,
                                                const float* __restrict__ Kb,
                                                const int* __restrict__ idx,
                                                float* __restrict__ QK, int L, int n){
  __shared__ float Qs[512];
  int blk = blockIdx.x;            // over 8*L
  int l = blk % L, b = blk / L;
  int t = threadIdx.x;
  if (t < 128){
    gload16(Q + (size_t)(b*L + l)*512 + t*4, (char*)Qs + (size_t)(t>>6)*1024);
  }
  __syncthreads();
  if (t < 8*n){
    int h = t / n, s = t - h*n;
    int kr = idx[l*n + s];
    const float4* kp = (const float4*)(Kb + (size_t)(b*L + kr)*512 + h*64);
    const float4* qp = (const float4*)(Qs + h*64);
    float dot = 0.f;
    #pragma unroll
    for (int i=0;i<16;i++){
      float4 a = qp[i], c = kp[i];
      dot += a.x*c.x + a.y*c.y + a.z*c.z + a.w*c.w;
    }
    QK[((size_t)(b*8 + h)*L + l)*n + s] = dot;
  }
}

// ---------------- m = max_s - sum_s/L over contiguous rows of n ----------------
__global__ __launch_bounds__(256) void reduce_m_k(const float* __restrict__ QK,
                                                  float* __restrict__ Mout, int L, int n){
  int gi = blockIdx.x*256 + threadIdx.x;   // over 64*L
  if (gi >= 64*L) return;
  int l = gi % L; int bh = gi / L;
  const float* row = QK + (size_t)gi*n;
  float mx = -INFINITY, sm = 0.f;
  for (int s=0;s<n;s++){ float v = row[s]; mx = fmaxf(mx, v); sm += v; }
  Mout[(size_t)bh*1024 + l] = mx - sm/(float)L;
}

// ---------------- top-k (single wave per bh, tie -> lower index) ----------------
__global__ __launch_bounds__(64) void topk_k(const float* __restrict__ Mv,
                                             int* __restrict__ topk, int L, int n){
  int bh = blockIdx.x; int lane = threadIdx.x;
  float v[16];
  #pragma unroll
  for (int i=0;i<16;i++){ int l = i*64 + lane; v[i] = (l<L) ? Mv[(size_t)bh*1024 + l] : -INFINITY; }
  for (int it=0; it<n; ++it){
    float bv = -INFINITY; int bi = 0x7fffffff;
    #pragma unroll
    for (int i=0;i<16;i++){ int l = i*64+lane; if (v[i] > bv){ bv = v[i]; bi = l; } }
    #pragma unroll
    for (int o=32;o>0;o>>=1){
      float ov = __shfl_xor(bv, o); int oi = __shfl_xor(bi, o);
      if (ov > bv || (ov == bv && oi < bi)){ bv = ov; bi = oi; }
    }
    if (lane == 0) topk[bh*n + it] = bi;
    int wl = bi & 63, wi = bi >> 6;
    if (lane == wl){
      #pragma unroll
      for (int i=0;i<16;i++) if (i == wi) v[i] = -INFINITY;
    }
  }
}

// ---------------- Qred gather (scaled by 1/8, bf16) ----------------
__global__ __launch_bounds__(64) void qred_k(const float* __restrict__ Q,
                                             const int* __restrict__ topk,
                                             short* __restrict__ Qrh, int L, int n){
  int u = blockIdx.x % n; int bh = blockIdx.x / n;
  int h = bh & 7, b = bh >> 3; int d = threadIdx.x;
  int lq = topk[bh*n + u];
  Qrh[(size_t)bh*8192 + u*64 + d] = f2bf(0.125f * Q[(size_t)(b*L + lq)*512 + h*64 + d]);
}

// ---------------- V transpose to bf16 [bh][128pad d][1024 l] ----------------
__global__ __launch_bounds__(256) void vt_k(const float* __restrict__ V,
                                            short* __restrict__ Vt, int L){
  __shared__ float ts[64][65];
  int z = blockIdx.x >> 4;
  int l0 = (blockIdx.x & 15) * 64;
  int h = z & 7, b = z >> 3;
  int t = threadIdx.x;
  for (int i = t; i < 4096; i += 256){
    int lloc = i >> 6, d = i & 63;
    int l = l0 + lloc;
    ts[d][lloc] = (l < L) ? V[(size_t)(b*L + l)*512 + h*64 + d] : 0.f;
  }
  __syncthreads();
  for (int i = t; i < 4096; i += 256){
    int d = i >> 6, lloc = i & 63;
    Vt[(size_t)z*131072 + (size_t)d*1024 + l0 + lloc] = f2bf(ts[d][lloc]);
  }
}

// ---------------- softmax on S rows -> bf16 P, 1/sum ----------------
__global__ __launch_bounds__(256) void softmax_k(const float* __restrict__ S,
                                                 short* __restrict__ Ph,
                                                 float* __restrict__ RS, int L, int n){
  int u = blockIdx.x % n; int z = blockIdx.x / n;
  const float* srow = S + (size_t)z*n*1024 + (size_t)u*1024;
  short* prow = Ph + (size_t)z*131072 + (size_t)u*1024;
  int t = threadIdx.x;
  __shared__ float red[256];
  float lm = -INFINITY;
  for (int l=t; l<L; l+=256) lm = fmaxf(lm, srow[l]);
  red[t]=lm; __syncthreads();
  for (int o=128;o>0;o>>=1){ if(t<o) red[t]=fmaxf(red[t],red[t+o]); __syncthreads(); }
  float mx = red[0]; __syncthreads();
  float ls = 0.f;
  for (int l=t; l<1024; l+=256){
    float p = (l < L) ? expf(srow[l]-mx) : 0.f;
    prow[l] = f2bf(p);
    ls += p;
  }
  red[t]=ls; __syncthreads();
  for (int o=128;o>0;o>>=1){ if(t<o) red[t]+=red[t+o]; __syncthreads(); }
  if (t==0) RS[(size_t)z*n + u] = 1.0f/red[0];
}

// ---------------- v mean ----------------
__global__ __launch_bounds__(512) void vmean_part_k(const float* __restrict__ V,
                                                    float* __restrict__ part, int L){
  int b = blockIdx.x; int j = blockIdx.y; int c = threadIdx.x;
  float s = 0.f;
  for (int l = j; l < L; l += 16) s += V[(size_t)(b*L + l)*512 + c];
  part[(size_t)(b*16 + j)*512 + c] = s;
}
__global__ __launch_bounds__(256) void vmean_comb_k(const float* __restrict__ part,
                                                    float* __restrict__ vmean, int L){
  int i = blockIdx.x*256 + threadIdx.x;
  int b = i >> 9; int c = i & 511;
  float s = 0.f;
  #pragma unroll
  for (int j=0;j<16;j++) s += part[(size_t)(b*16 + j)*512 + c];
  vmean[i] = s / (float)L;
}
__global__ __launch_bounds__(256) void ctx_fill_k(short* __restrict__ CTXh,
                                                  const float* __restrict__ vmean, int L){
  int i = blockIdx.x*256 + threadIdx.x;
  int c = i & 511; int bl = i >> 9; int b = bl / L;
  CTXh[i] = f2bf(vmean[b*512 + c]);
}
__global__ __launch_bounds__(256) void ctx_scatter_k(short* __restrict__ CTXh,
                                                     const float* __restrict__ UPD,
                                                     const int* __restrict__ topk, int L, int n){
  int i = blockIdx.x*256 + threadIdx.x;   // 64*n*64
  int d = i & 63; int u = (i >> 6) % n; int bh = i / (64*n);
  int h = bh & 7; int b = bh >> 3;
  int lq = topk[bh*n + u];
  CTXh[(size_t)(b*L + lq)*512 + h*64 + d] = f2bf(UPD[((size_t)bh*n + u)*64 + d]);
}

// ---------------- residual add + LayerNorm (X fp32 + Xh bf16) ----------------
__global__ __launch_bounds__(256) void add_ln_k(float* __restrict__ X,
                                                short* __restrict__ Xh,
                                                const float* __restrict__ Y,
                                                const float* __restrict__ w,
                                                const float* __restrict__ b){
  int r = blockIdx.x;
  size_t base = (size_t)r*512;
  int t = threadIdx.x;
  float v0 = X[base+t]     + Y[base+t];
  float v1 = X[base+t+256] + Y[base+t+256];
  __shared__ float red[256];
  red[t] = v0 + v1; __syncthreads();
  for (int o=128;o>0;o>>=1){ if(t<o) red[t]+=red[t+o]; __syncthreads(); }
  float mu = red[0]*(1.f/512.f); __syncthreads();
  float d0 = v0-mu, d1 = v1-mu;
  red[t] = d0*d0 + d1*d1; __syncthreads();
  for (int o=128;o>0;o>>=1){ if(t<o) red[t]+=red[t+o]; __syncthreads(); }
  float rs = 1.0f/sqrtf(red[0]*(1.f/512.f) + 1e-5f);
  float x0 = d0*rs*w[t]     + b[t];
  float x1 = d1*rs*w[t+256] + b[t+256];
  X[base+t]     = x0;  Xh[base+t]     = f2bf(x0);
  X[base+t+256] = x1;  Xh[base+t+256] = f2bf(x1);
}

// ---------------- final LayerNorm + GELU ----------------
__global__ __launch_bounds__(256) void ln_gelu_k(const float* __restrict__ X,
                                                 float* __restrict__ Yout,
                                                 const float* __restrict__ w,
                                                 const float* __restrict__ b){
  int r = blockIdx.x;
  size_t base = (size_t)r*512;
  int t = threadIdx.x;
  float v0 = X[base+t];
  float v1 = X[base+t+256];
  __shared__ float red[256];
  red[t] = v0 + v1; __syncthreads();
  for (int o=128;o>0;o>>=1){ if(t<o) red[t]+=red[t+o]; __syncthreads(); }
  float mu = red[0]*(1.f/512.f); __syncthreads();
  float d0 = v0-mu, d1 = v1-mu;
  red[t] = d0*d0 + d1*d1; __syncthreads();
  for (int o=128;o>0;o>>=1){ if(t<o) red[t]+=red[t+o]; __syncthreads(); }
  float rs = 1.0f/sqrtf(red[0]*(1.f/512.f) + 1e-5f);
  float g0 = d0*rs*w[t]     + b[t];
  float g1 = d1*rs*w[t+256] + b[t+256];
  Yout[base+t]     = 0.5f*g0*(1.0f + erff(g0*0.707106781186547524f));
  Yout[base+t+256] = 0.5f*g1*(1.0f + erff(g1*0.707106781186547524f));
}

// ---------------- conv helpers ----------------
__global__ __launch_bounds__(256) void im2col_k(const float* __restrict__ X,
                                                short* __restrict__ O, int L){
  int i = blockIdx.x*256 + threadIdx.x;   // 8*L*1536
  int col = i % 1536; int bl = i / 1536;
  int l = bl % L; int b = bl / L;
  int t = col / 512; int ci = col % 512;
  int ls = l - 1 + t;
  ls = (ls < 0) ? (L-1) : (ls >= L ? 0 : ls);
  O[(size_t)bl*1536 + col] = f2bf(X[(size_t)(b*L + ls)*512 + ci]);
}
__global__ __launch_bounds__(256) void pool_k(const short* __restrict__ Hc,
                                              float* __restrict__ X,
                                              short* __restrict__ Xh, int L, int Lo){
  int i = blockIdx.x*256 + threadIdx.x;   // 8*Lo*512
  int c = i & 511; int r = i >> 9; int lo = r % Lo; int b = r / Lo;
  float m = -INFINITY;
  #pragma unroll
  for (int dt=-1; dt<=1; dt++){
    int li = 2*lo + dt;
    if (li >= 0 && li < L) m = fmaxf(m, bf2f((unsigned short)Hc[(size_t)(b*L + li)*512 + c]));
  }
  size_t o = (size_t)(b*Lo + lo)*512 + c;
  X[o] = m; Xh[o] = f2bf(m);
}

// ---------------- split-K final projection ----------------
__global__ __launch_bounds__(256) void proj_part_k(const float* __restrict__ Xg,
                                                   const float* __restrict__ pw,
                                                   float* __restrict__ part){
  int b = blockIdx.x >> 5;
  int c = blockIdx.x & 31;
  int t = threadIdx.x;
  const float4* xp = (const float4*)(Xg + (size_t)b*131072 + (size_t)c*4096);
  float4 x0 = xp[t], x1 = xp[t+256], x2 = xp[t+512], x3 = xp[t+768];
  float acc[10];
  #pragma unroll
  for (int j=0;j<10;j++){
    const float4* wp = (const float4*)(pw + (size_t)j*131072 + (size_t)c*4096);
    float4 w0 = wp[t], w1 = wp[t+256], w2 = wp[t+512], w3 = wp[t+768];
    acc[j] = x0.x*w0.x + x0.y*w0.y + x0.z*w0.z + x0.w*w0.w
           + x1.x*w1.x + x1.y*w1.y + x1.z*w1.z + x1.w*w1.w
           + x2.x*w2.x + x2.y*w2.y + x2.z*w2.z + x2.w*w2.w
           + x3.x*w3.x + x3.y*w3.y + x3.z*w3.z + x3.w*w3.w;
  }
  __shared__ float red[256];
  #pragma unroll
  for (int j=0;j<10;j++){
    red[t] = acc[j]; __syncthreads();
    for (int o=128;o>0;o>>=1){ if(t<o) red[t]+=red[t+o]; __syncthreads(); }
    if (t==0) part[(b*10 + j)*32 + c] = red[0];
    __syncthreads();
  }
}
__global__ __launch_bounds__(128) void proj_comb_k(const float* __restrict__ part,
                                                   const float* __restrict__ pb,
                                                   float* __restrict__ out){
  int t = threadIdx.x;
  if (t >= 80) return;
  int j = t % 10;
  const float* p = part + t*32;
  float s = 0.f;
  #pragma unroll
  for (int c=0;c<32;c++) s += p[c];
  out[t] = s + pb[j];
}

extern "C" void kernel_launch(void* const* d_in, const int* in_sizes, int n_in,
                              void* d_out, int out_size, void* d_ws, size_t ws_size,
                              hipStream_t stream){
  (void)in_sizes; (void)n_in; (void)out_size; (void)ws_size;
  const float* x_enc = (const float*)d_in[0];
  const float* tok_w = (const float*)d_in[1];
  const float* wq    = (const float*)d_in[2];
  const float* bq    = (const float*)d_in[3];
  const float* wk    = (const float*)d_in[4];
  const float* bk    = (const float*)d_in[5];
  const float* wvp   = (const float*)d_in[6];
  const float* bvp   = (const float*)d_in[7];
  const float* wo    = (const float*)d_in[8];
  const float* bo    = (const float*)d_in[9];
  const float* ln1w  = (const float*)d_in[10];
  const float* ln1b  = (const float*)d_in[11];
  const float* ln2w  = (const float*)d_in[12];
  const float* ln2b  = (const float*)d_in[13];
  const float* f1w   = (const float*)d_in[14];
  const float* f1b   = (const float*)d_in[15];
  const float* f2w   = (const float*)d_in[16];
  const float* f2b   = (const float*)d_in[17];
  const float* cvw   = (const float*)d_in[18];
  const float* cvb   = (const float*)d_in[19];
  const float* bnw   = (const float*)d_in[20];
  const float* bnb   = (const float*)d_in[21];
  const float* nw    = (const float*)d_in[22];
  const float* nb    = (const float*)d_in[23];
  const float* pw    = (const float*)d_in[24];
  const float* pb    = (const float*)d_in[25];

  char* wsb = (char*)d_ws;
  float* X    = (float*)(wsb + 0);            // 8192x512 f32
  float* Y    = (float*)(wsb + 16777216);     // 8192x512 f32
  float* Q    = (float*)(wsb + 33554432);
  float* Kbuf = (float*)(wsb + 50331648);
  float* V    = (float*)(wsb + 67108864);
  short* Xh   = (short*)(wsb + 83886080);     // 8192x512 bf16
  short* CTXh = (short*)(wsb + 92274688);     // 8192x512 bf16
  short* WQH  = (short*)(wsb + 100663296);
  short* WKH  = WQH + 262144;
  short* WVH  = WKH + 262144;
  short* WOH  = WVH + 262144;
  short* F1H  = WOH + 262144;                 // 2048x512
  short* F2H  = F1H + 1048576;                // 512x2048
  short* WCVH = F2H + 1048576;                // 512x1536
  char*  RB   = wsb + 108527616;              // shared region (58.7MB)
  short* FFh  = (short*)(RB);                 // 8192x2048 bf16 (FFN phase)
  short* IM2  = (short*)(RB + 33554432);      // 8192x1536 bf16 (conv phase)
  short* Kh   = (short*)(RB + 0);             // [64][1024][64] bf16 (attn phase)
  short* Vt   = (short*)(RB + 8388608);       // [64][128][1024] bf16
  short* Ph   = (short*)(RB + 25165824);      // [64][128][1024] bf16
  short* Qrh  = (short*)(RB + 41943040);      // [64][128][64] bf16
  float* S    = (float*)(RB + 42991616);      // [64][35][1024] f32 (also QK dots)
  float* RS   = (float*)(RB + 52166656);      // [64][35] f32
  float* UPD  = (float*)(RB + 52175616);      // [64][35][64] f32
  float* Mb   = (float*)(RB + 52749056);      // [64][1024] f32
  float* VME  = (float*)(RB + 53011200);
  float* VPA  = (float*)(RB + 53027584);
  int*   IDX  = (int*)  (RB + 53289728);
  int*   TOPK = (int*)  (RB + 53433088);
  float* PPART= (float*)(RB + 53450752);      // [8][10][32] f32

  // JAX partitionable key derivation (host)
  uint32_t rka[3], rkb[3];
  for (int l = 0; l < 3; ++l) tf2x32(0u, 42u, 0u, (uint32_t)l, &rka[l], &rkb[l]);

  auto gemm = [&](const short* A, long Ab, const short* W, long Wb, const float* bias,
                  float* Cf, short* Ch, long Cb, int M, int Nreal, int Nstride, int K,
                  int mode, const float* s2, const float* b2, const float* rs, long rsb,
                  int mt, int nt, int zt, short* KhG, int Lq){
    hipLaunchKernelGGL(gemm_bf16_k, dim3(mt, nt, zt), dim3(256), 0, stream,
                       A, Ab, W, Wb, bias, Cf, Ch, Cb, M, Nreal, Nstride, K, mode,
                       s2, b2, rs, rsb, KhG, Lq);
  };

  hipLaunchKernelGGL(embed_k, dim3(16336), dim3(256), 0, stream, x_enc, tok_w, X, Xh);

  int L = 1021;
  for (int l = 0; l < 3; ++l){
    int n = 5 * (int)ceil(log((double)L)); if (n > L) n = L;
    int Mr = 8 * L;
    int mt = (Mr + 127)/128;

    // weight converts (bf16)
    hipLaunchKernelGGL(wcvt_k, dim3(1024), dim3(256), 0, stream, wq + (size_t)l*262144, WQH, 262144);
    hipLaunchKernelGGL(wcvt_k, dim3(1024), dim3(256), 0, stream, wk + (size_t)l*262144, WKH, 262144);
    hipLaunchKernelGGL(wcvt_k, dim3(1024), dim3(256), 0, stream, wvp+ (size_t)l*262144, WVH, 262144);
    hipLaunchKernelGGL(wcvt_k, dim3(1024), dim3(256), 0, stream, wo + (size_t)l*262144, WOH, 262144);
    hipLaunchKernelGGL(wcvt_k, dim3(4096), dim3(256), 0, stream, f1w+ (size_t)l*1048576, F1H, 1048576);
    hipLaunchKernelGGL(wcvt_k, dim3(4096), dim3(256), 0, stream, f2w+ (size_t)l*1048576, F2H, 1048576);

    // random sample indices
    uint32_t k1a,k1b,k2a,k2b;
    tf2x32(rka[l], rkb[l], 0u, 0u, &k1a, &k1b);
    tf2x32(rka[l], rkb[l], 0u, 1u, &k2a, &k2b);
    int size = L * n;
    uint32_t span = (uint32_t)L;
    uint32_t rr = 65536u % span;
    uint32_t mult = (rr * rr) % span;
    hipLaunchKernelGGL(gen_idx_k, dim3((unsigned)((size+255)/256)), dim3(256), 0, stream,
                       k1a, k1b, k2a, k2b, size, span, mult, IDX);

    // QKV (bf16 MFMA, fp32 out; K also writes head-gathered bf16 copy)
    gemm(Xh, 0, WQH, 0, bq + (size_t)l*512, Q,    nullptr, 0, Mr, 512, 512, 512, 0, 0, 0, 0, 0, mt, 4, 1, nullptr, 0);
    gemm(Xh, 0, WKH, 0, bk + (size_t)l*512, Kbuf, nullptr, 0, Mr, 512, 512, 512, 0, 0, 0, 0, 0, mt, 4, 1, Kh, L);
    gemm(Xh, 0, WVH, 0, bvp+ (size_t)l*512, V,    nullptr, 0, Mr, 512, 512, 512, 0, 0, 0, 0, 0, mt, 4, 1, nullptr, 0);

    // sampled dots (block per (b,l), LDS Q) then m-reduce, top-k
    hipLaunchKernelGGL(qk_dot_k, dim3((unsigned)(8*L)), dim3(320), 0, stream,
                       Q, Kbuf, IDX, S, L, n);
    hipLaunchKernelGGL(reduce_m_k, dim3((unsigned)((64*L+255)/256)), dim3(256), 0, stream,
                       S, Mb, L, n);
    hipLaunchKernelGGL(topk_k, dim3(64), dim3(64), 0, stream, Mb, TOPK, L, n);

    // attention: gather -> scores GEMM -> softmax -> PV GEMM
    hipLaunchKernelGGL(qred_k, dim3((unsigned)(64*n)), dim3(64), 0, stream, Q, TOPK, Qrh, L, n);
    hipLaunchKernelGGL(vt_k, dim3(1024), dim3(256), 0, stream, V, Vt, L);
    gemm(Qrh, 8192, Kh, 65536, nullptr, S, nullptr, (long)n*1024, n, L, 1024, 64, 3, 0, 0, 0, 0, 1, 8, 64, nullptr, 0);
    hipLaunchKernelGGL(softmax_k, dim3((unsigned)(64*n)), dim3(256), 0, stream, S, Ph, RS, L, n);
    gemm(Ph, 131072, Vt, 131072, nullptr, UPD, nullptr, (long)n*64, n, 64, 64, 1024, 4, 0, 0, RS, n, 1, 1, 64, nullptr, 0);

    // ctx = broadcast mean(v) with top-k rows replaced (bf16)
    hipLaunchKernelGGL(vmean_part_k, dim3(8,16), dim3(512), 0, stream, V, VPA, L);
    hipLaunchKernelGGL(vmean_comb_k, dim3(16), dim3(256), 0, stream, VPA, VME, L);
    hipLaunchKernelGGL(ctx_fill_k, dim3((unsigned)(Mr*2)), dim3(256), 0, stream, CTXh, VME, L);
    hipLaunchKernelGGL(ctx_scatter_k, dim3((unsigned)(16*n)), dim3(256), 0, stream, CTXh, UPD, TOPK, L, n);

    // out-proj + LN1
    gemm(CTXh, 0, WOH, 0, bo + (size_t)l*512, Y, nullptr, 0, Mr, 512, 512, 512, 0, 0, 0, 0, 0, mt, 4, 1, nullptr, 0);
    hipLaunchKernelGGL(add_ln_k, dim3((unsigned)Mr), dim3(256), 0, stream, X, Xh, Y, ln1w + (size_t)l*512, ln1b + (size_t)l*512);

    // FFN + LN2
    gemm(Xh, 0, F1H, 0, f1b + (size_t)l*2048, nullptr, FFh, 0, Mr, 2048, 2048, 512, 1, 0, 0, 0, 0, mt, 16, 1, nullptr, 0);
    gemm(FFh, 0, F2H, 0, f2b + (size_t)l*512, Y, nullptr, 0, Mr, 512, 512, 2048, 0, 0, 0, 0, 0, mt, 4, 1, nullptr, 0);
    hipLaunchKernelGGL(add_ln_k, dim3((unsigned)Mr), dim3(256), 0, stream, X, Xh, Y, ln2w + (size_t)l*512, ln2b + (size_t)l*512);

    // distilling conv (layers 0,1)
    if (l < 2){
      hipLaunchKernelGGL(convw_k, dim3(3072), dim3(256), 0, stream, cvw + (size_t)l*786432, WCVH);
      hipLaunchKernelGGL(im2col_k, dim3((unsigned)(Mr*6)), dim3(256), 0, stream, X, IM2, L);
      gemm(IM2, 0, WCVH, 0, cvb + (size_t)l*512, nullptr, CTXh, 0, Mr, 512, 512, 1536, 2,
           bnw + (size_t)l*512, bnb + (size_t)l*512, 0, 0, mt, 4, 1, nullptr, 0);
      int Lo = (L - 1)/2 + 1;
      hipLaunchKernelGGL(pool_k, dim3((unsigned)(8*Lo*2)), dim3(256), 0, stream, CTXh, X, Xh, L, Lo);
      L = Lo;
    }
  }

  hipLaunchKernelGGL(ln_gelu_k, dim3((unsigned)(8*L)), dim3(256), 0, stream, X, Y, nw, nb);
  hipLaunchKernelGGL(proj_part_k, dim3(256), dim3(256), 0, stream, Y, pw, PPART);
  hipLaunchKernelGGL(proj_comb_k, dim3(1), dim3(128), 0, stream, PPART, pb, (float*)d_out);
}

// Round 8
// 1567.417 us; speedup vs baseline: 2.8380x; 1.0753x over previous
//
#include <hip/hip_runtime.h>
#include <math.h>
#include <stdint.h>

typedef __attribute__((ext_vector_type(8))) short bf16x8;
typedef __attribute__((ext_vector_type(4))) float f32x4;

// ---------------- helpers ----------------
__device__ __forceinline__ unsigned short f2bf(float f){
  unsigned int u = __float_as_uint(f);
  unsigned int r = (u + 0x7fffu + ((u>>16)&1u)) >> 16;
  return (unsigned short)r;
}
__device__ __forceinline__ float bf2f(unsigned short h){
  return __uint_as_float(((unsigned int)h)<<16);
}
__device__ __forceinline__ void gload16(const void* g, void* l){
  __builtin_amdgcn_global_load_lds(
      (const __attribute__((address_space(1))) unsigned int*)g,
      (__attribute__((address_space(3))) unsigned int*)l, 16, 0, 0);
}

// ---------------- Threefry-2x32 (exact JAX PRNG, partitionable) ----------------
__host__ __device__ static inline uint32_t rotl32(uint32_t x, int d){ return (x<<d)|(x>>(32-d)); }
__host__ __device__ static inline void tf2x32(uint32_t k0, uint32_t k1, uint32_t c0, uint32_t c1,
                                              uint32_t* o0, uint32_t* o1){
  uint32_t ks0=k0, ks1=k1, ks2=k0^k1^0x1BD11BDAu;
  uint32_t x0=c0+ks0, x1=c1+ks1;
  const int ra[4]={13,15,26,6}, rb[4]={17,29,16,24};
  #pragma unroll
  for(int i=0;i<4;i++){x0+=x1;x1=rotl32(x1,ra[i]);x1^=x0;}
  x0+=ks1; x1+=ks2+1u;
  #pragma unroll
  for(int i=0;i<4;i++){x0+=x1;x1=rotl32(x1,rb[i]);x1^=x0;}
  x0+=ks2; x1+=ks0+2u;
  #pragma unroll
  for(int i=0;i<4;i++){x0+=x1;x1=rotl32(x1,ra[i]);x1^=x0;}
  x0+=ks0; x1+=ks1+3u;
  #pragma unroll
  for(int i=0;i<4;i++){x0+=x1;x1=rotl32(x1,rb[i]);x1^=x0;}
  x0+=ks1; x1+=ks2+4u;
  #pragma unroll
  for(int i=0;i<4;i++){x0+=x1;x1=rotl32(x1,ra[i]);x1^=x0;}
  x0+=ks2; x1+=ks0+5u;
  *o0=x0; *o1=x1;
}

__global__ __launch_bounds__(256) void gen_idx_k(uint32_t k1a,uint32_t k1b,
                                                 uint32_t k2a,uint32_t k2b,
                                                 int size,uint32_t span,uint32_t mult,
                                                 int* __restrict__ idx){
  int i = blockIdx.x*256 + threadIdx.x;
  if (i >= size) return;
  uint32_t h0,h1,l0,l1;
  tf2x32(k1a,k1b,0u,(uint32_t)i,&h0,&h1);
  tf2x32(k2a,k2b,0u,(uint32_t)i,&l0,&l1);
  uint32_t hb = h0^h1, lb = l0^l1;
  idx[i] = (int)((((hb%span)*mult) + (lb%span)) % span);
}

// ---------------- token embedding + PE (writes fp32 X and bf16 Xh) ----------------
__global__ __launch_bounds__(256) void embed_k(const float* __restrict__ xe,
                                               const float* __restrict__ tw,
                                               float* __restrict__ X,
                                               short* __restrict__ Xh){
  int i = blockIdx.x*256 + threadIdx.x;     // over 8*1021*512
  int c = i & 511;
  int bl = i >> 9;
  int l = bl % 1021;
  int b = bl / 1021;
  float acc = 0.f;
  #pragma unroll
  for (int t=0;t<3;t++){
    int ls = l - 1 + t;
    ls = (ls < 0) ? 1020 : (ls >= 1021 ? 0 : ls);
    const float* xp = xe + (size_t)(b*1021 + ls)*12;
    const float* wp = tw + (size_t)c*36 + t;
    #pragma unroll
    for (int ci=0; ci<12; ci++) acc += xp[ci] * wp[ci*3];
  }
  int ip = c >> 1;
  float div = expf((float)(2*ip) * (float)(-9.210340371976184/512.0));
  float ang = (float)l * div;
  acc += (c & 1) ? cosf(ang) : sinf(ang);
  X[i] = acc;
  Xh[i] = f2bf(acc);
}

// ---------------- weight converts ----------------
__global__ __launch_bounds__(256) void wcvt_k(const float* __restrict__ src,
                                              short* __restrict__ dst, int n){
  int i = blockIdx.x*256 + threadIdx.x;
  if (i < n) dst[i] = f2bf(src[i]);
}
__global__ __launch_bounds__(256) void convw_k(const float* __restrict__ cw,
                                               short* __restrict__ W){
  int i = blockIdx.x*256 + threadIdx.x;   // 512*1536
  int col = i % 1536; int co = i / 1536;
  int t = col / 512; int ci = col % 512;
  W[i] = f2bf(cw[(size_t)co*1536 + ci*3 + t]);
}

// ---------------- bf16 MFMA GEMM (double-buffered LDS): C = A @ W^T, batched ----------
// mode 0: +bias  1: +bias,GELU  2: +bias,BN,ELU  3: raw  4: *rowscale
// KhG != nullptr: also write bf16 head-gathered copy [b][h][1024 l][64 d] (needs Lq)
__global__ __launch_bounds__(256) void gemm_bf16_k(
    const short* __restrict__ A, long Ab,
    const short* __restrict__ W, long Wb,
    const float* __restrict__ bias,
    float* __restrict__ Cf, short* __restrict__ Ch, long Cb,
    int M, int Nreal, int Nstride, int K, int mode,
    const float* __restrict__ s2, const float* __restrict__ b2,
    const float* __restrict__ rs, long rsb,
    short* __restrict__ KhG, int Lq)
{
  __shared__ short As[8192];   // 2 buffers x 128 x 32
  __shared__ short Bs[8192];
  const int t = threadIdx.x;
  const int lane = t & 63;
  const int w = t >> 6;
  const int wr = w >> 1, wc = w & 1;
  const int z = blockIdx.z;
  const int m0 = blockIdx.x * 128, n0 = blockIdx.y * 128;
  const short* Az = A + (size_t)z * Ab;
  const short* Wz = W + (size_t)z * Wb;

  f32x4 acc[4][4];
  #pragma unroll
  for (int i=0;i<4;i++)
    #pragma unroll
    for (int j=0;j<4;j++) acc[i][j] = (f32x4){0.f,0.f,0.f,0.f};

  const int r0  = t >> 2;          // staging row for slot t
  const int k80 = (t & 3) << 3;    // staging k-offset (elements)
  char* AsB = (char*)As;
  char* BsB = (char*)Bs;

  #define STAGE(buf, k0) do { \
    gload16(Az + (size_t)(m0 + r0)      * K + (k0) + k80, AsB + (buf)*8192 + (size_t)w*1024); \
    gload16(Az + (size_t)(m0 + r0 + 64) * K + (k0) + k80, AsB + (buf)*8192 + 4096 + (size_t)w*1024); \
    gload16(Wz + (size_t)(n0 + r0)      * K + (k0) + k80, BsB + (buf)*8192 + (size_t)w*1024); \
    gload16(Wz + (size_t)(n0 + r0 + 64) * K + (k0) + k80, BsB + (buf)*8192 + 4096 + (size_t)w*1024); \
  } while(0)

  STAGE(0, 0);
  __syncthreads();
  int cur = 0;
  for (int k0 = 0; k0 < K; k0 += 32){
    if (k0 + 32 < K) STAGE(cur^1, k0+32);
    bf16x8 a[4], b[4];
    #pragma unroll
    for (int mi=0; mi<4; mi++){
      int aoff = cur*4096 + (wr*64 + mi*16 + (lane&15))*32 + ((lane>>4)<<3);
      a[mi] = *(const bf16x8*)(&As[aoff]);
    }
    #pragma unroll
    for (int ni=0; ni<4; ni++){
      int boff = cur*4096 + (wc*64 + ni*16 + (lane&15))*32 + ((lane>>4)<<3);
      b[ni] = *(const bf16x8*)(&Bs[boff]);
    }
    #pragma unroll
    for (int mi=0; mi<4; mi++)
      #pragma unroll
      for (int ni=0; ni<4; ni++)
        acc[mi][ni] = __builtin_amdgcn_mfma_f32_16x16x32_bf16(a[mi], b[ni], acc[mi][ni], 0, 0, 0);
    __syncthreads();   // drains STAGE (compiler vmcnt) + protects cur buffer
    cur ^= 1;
  }
  #undef STAGE

  #pragma unroll
  for (int mi=0; mi<4; mi++){
    #pragma unroll
    for (int r=0; r<4; r++){
      int gm = m0 + wr*64 + mi*16 + ((lane>>4)<<2) + r;
      if (gm >= M) continue;
      float rsc = (mode==4) ? rs[(size_t)z*rsb + gm] : 0.f;
      int bb = 0, ll = 0;
      if (KhG){ bb = gm / Lq; ll = gm - bb*Lq; }
      #pragma unroll
      for (int ni=0; ni<4; ni++){
        int gn = n0 + wc*64 + ni*16 + (lane&15);
        if (gn >= Nreal) continue;
        float v = acc[mi][ni][r];
        if (mode <= 2) v += bias[gn];
        if (mode == 1){
          v = 0.5f*v*(1.0f + erff(v*0.707106781186547524f));
        } else if (mode == 2){
          v = v * (s2[gn]*0.9999950000374997f) + b2[gn];
          v = (v > 0.f) ? v : expm1f(v);
        } else if (mode == 4){
          v *= rsc;
        }
        size_t off = (size_t)z*Cb + (size_t)gm*Nstride + gn;
        if (Cf) Cf[off] = v;
        if (Ch) Ch[off] = f2bf(v);
        if (KhG) KhG[(((size_t)bb*8 + (gn>>6))*1024 + ll)*64 + (gn&63)] = f2bf(v);
      }
    }
  }
}

// ---------------- sampled m: block per (b,l); wave per sample, coalesced K row reads;
// fused m = max_s - sum_s/L  ----------------
__global__ __launch_bounds__(256) void qk_dot_k(const float* __restrict__ Q,
                                                const float* __restrict__ Kb,
                                                const int* __restrict__ idx,
                                                float* __restrict__ Mout, int L, int n){
  __shared__ float Qs[512];
  __shared__ float dots[8][36];
  int blk = blockIdx.x;            // over 8*L
  int l = blk % L, b = blk / L;
  int t = threadIdx.x;
  int w = t >> 6, lane = t & 63;
  if (t < 128){
    gload16(Q + (size_t)(b*L + l)*512 + t*4, (char*)Qs + (size_t)(t>>6)*1024);
  }
  __syncthreads();
  const float4* qp = (const float4*)(Qs + lane*8);
  float4 q0 = qp[0], q1 = qp[1];
  for (int s = w; s < n; s += 4){
    int kr = idx[l*n + s];
    const float4* kp = (const float4*)(Kb + (size_t)(b*L + kr)*512 + lane*8);
    float4 a0 = kp[0], a1 = kp[1];
    float p = a0.x*q0.x + a0.y*q0.y + a0.z*q0.z + a0.w*q0.w
            + a1.x*q1.x + a1.y*q1.y + a1.z*q1.z + a1.w*q1.w;
    p += __shfl_xor(p, 1);
    p += __shfl_xor(p, 2);
    p += __shfl_xor(p, 4);
    if ((lane & 7) == 0) dots[lane >> 3][s] = p;
  }
  __syncthreads();
  if (t < 8){
    float mx = -INFINITY, sm = 0.f;
    for (int s = 0; s < n; ++s){ float v = dots[t][s]; mx = fmaxf(mx, v); sm += v; }
    Mout[(size_t)(b*8 + t)*1024 + l] = mx - sm/(float)L;
  }
}

// ---------------- top-k (single wave per bh, tie -> lower index) ----------------
__global__ __launch_bounds__(64) void topk_k(const float* __restrict__ Mv,
                                             int* __restrict__ topk, int L, int n){
  int bh = blockIdx.x; int lane = threadIdx.x;
  float v[16];
  #pragma unroll
  for (int i=0;i<16;i++){ int l = i*64 + lane; v[i] = (l<L) ? Mv[(size_t)bh*1024 + l] : -INFINITY; }
  for (int it=0; it<n; ++it){
    float bv = -INFINITY; int bi = 0x7fffffff;
    #pragma unroll
    for (int i=0;i<16;i++){ int l = i*64+lane; if (v[i] > bv){ bv = v[i]; bi = l; } }
    #pragma unroll
    for (int o=32;o>0;o>>=1){
      float ov = __shfl_xor(bv, o); int oi = __shfl_xor(bi, o);
      if (ov > bv || (ov == bv && oi < bi)){ bv = ov; bi = oi; }
    }
    if (lane == 0) topk[bh*n + it] = bi;
    int wl = bi & 63, wi = bi >> 6;
    if (lane == wl){
      #pragma unroll
      for (int i=0;i<16;i++) if (i == wi) v[i] = -INFINITY;
    }
  }
}

// ---------------- Qred gather (scaled by 1/8, bf16) ----------------
__global__ __launch_bounds__(64) void qred_k(const float* __restrict__ Q,
                                             const int* __restrict__ topk,
                                             short* __restrict__ Qrh, int L, int n){
  int u = blockIdx.x % n; int bh = blockIdx.x / n;
  int h = bh & 7, b = bh >> 3; int d = threadIdx.x;
  int lq = topk[bh*n + u];
  Qrh[(size_t)bh*8192 + u*64 + d] = f2bf(0.125f * Q[(size_t)(b*L + lq)*512 + h*64 + d]);
}

// ---------------- V transpose to bf16 [bh][128pad d][1024 l] ----------------
__global__ __launch_bounds__(256) void vt_k(const float* __restrict__ V,
                                            short* __restrict__ Vt, int L){
  __shared__ float ts[64][65];
  int z = blockIdx.x >> 4;
  int l0 = (blockIdx.x & 15) * 64;
  int h = z & 7, b = z >> 3;
  int t = threadIdx.x;
  for (int i = t; i < 4096; i += 256){
    int lloc = i >> 6, d = i & 63;
    int l = l0 + lloc;
    ts[d][lloc] = (l < L) ? V[(size_t)(b*L + l)*512 + h*64 + d] : 0.f;
  }
  __syncthreads();
  for (int i = t; i < 4096; i += 256){
    int d = i >> 6, lloc = i & 63;
    Vt[(size_t)z*131072 + (size_t)d*1024 + l0 + lloc] = f2bf(ts[d][lloc]);
  }
}

// ---------------- softmax on S rows -> bf16 P, 1/sum ----------------
__global__ __launch_bounds__(256) void softmax_k(const float* __restrict__ S,
                                                 short* __restrict__ Ph,
                                                 float* __restrict__ RS, int L, int n){
  int u = blockIdx.x % n; int z = blockIdx.x / n;
  const float* srow = S + (size_t)z*n*1024 + (size_t)u*1024;
  short* prow = Ph + (size_t)z*131072 + (size_t)u*1024;
  int t = threadIdx.x;
  __shared__ float red[256];
  float lm = -INFINITY;
  for (int l=t; l<L; l+=256) lm = fmaxf(lm, srow[l]);
  red[t]=lm; __syncthreads();
  for (int o=128;o>0;o>>=1){ if(t<o) red[t]=fmaxf(red[t],red[t+o]); __syncthreads(); }
  float mx = red[0]; __syncthreads();
  float ls = 0.f;
  for (int l=t; l<1024; l+=256){
    float p = (l < L) ? expf(srow[l]-mx) : 0.f;
    prow[l] = f2bf(p);
    ls += p;
  }
  red[t]=ls; __syncthreads();
  for (int o=128;o>0;o>>=1){ if(t<o) red[t]+=red[t+o]; __syncthreads(); }
  if (t==0) RS[(size_t)z*n + u] = 1.0f/red[0];
}

// ---------------- v mean ----------------
__global__ __launch_bounds__(512) void vmean_part_k(const float* __restrict__ V,
                                                    float* __restrict__ part, int L){
  int b = blockIdx.x; int j = blockIdx.y; int c = threadIdx.x;
  float s = 0.f;
  for (int l = j; l < L; l += 16) s += V[(size_t)(b*L + l)*512 + c];
  part[(size_t)(b*16 + j)*512 + c] = s;
}
__global__ __launch_bounds__(256) void vmean_comb_k(const float* __restrict__ part,
                                                    float* __restrict__ vmean, int L){
  int i = blockIdx.x*256 + threadIdx.x;
  int b = i >> 9; int c = i & 511;
  float s = 0.f;
  #pragma unroll
  for (int j=0;j<16;j++) s += part[(size_t)(b*16 + j)*512 + c];
  vmean[i] = s / (float)L;
}
__global__ __launch_bounds__(256) void ctx_fill_k(short* __restrict__ CTXh,
                                                  const float* __restrict__ vmean, int L){
  int i = blockIdx.x*256 + threadIdx.x;
  int c = i & 511; int bl = i >> 9; int b = bl / L;
  CTXh[i] = f2bf(vmean[b*512 + c]);
}
__global__ __launch_bounds__(256) void ctx_scatter_k(short* __restrict__ CTXh,
                                                     const float* __restrict__ UPD,
                                                     const int* __restrict__ topk, int L, int n){
  int i = blockIdx.x*256 + threadIdx.x;   // 64*n*64
  int d = i & 63; int u = (i >> 6) % n; int bh = i / (64*n);
  int h = bh & 7; int b = bh >> 3;
  int lq = topk[bh*n + u];
  CTXh[(size_t)(b*L + lq)*512 + h*64 + d] = f2bf(UPD[((size_t)bh*n + u)*64 + d]);
}

// ---------------- residual add + LayerNorm (X fp32 + Xh bf16) ----------------
__global__ __launch_bounds__(256) void add_ln_k(float* __restrict__ X,
                                                short* __restrict__ Xh,
                                                const float* __restrict__ Y,
                                                const float* __restrict__ w,
                                                const float* __restrict__ b){
  int r = blockIdx.x;
  size_t base = (size_t)r*512;
  int t = threadIdx.x;
  float v0 = X[base+t]     + Y[base+t];
  float v1 = X[base+t+256] + Y[base+t+256];
  __shared__ float red[256];
  red[t] = v0 + v1; __syncthreads();
  for (int o=128;o>0;o>>=1){ if(t<o) red[t]+=red[t+o]; __syncthreads(); }
  float mu = red[0]*(1.f/512.f); __syncthreads();
  float d0 = v0-mu, d1 = v1-mu;
  red[t] = d0*d0 + d1*d1; __syncthreads();
  for (int o=128;o>0;o>>=1){ if(t<o) red[t]+=red[t+o]; __syncthreads(); }
  float rs = 1.0f/sqrtf(red[0]*(1.f/512.f) + 1e-5f);
  float x0 = d0*rs*w[t]     + b[t];
  float x1 = d1*rs*w[t+256] + b[t+256];
  X[base+t]     = x0;  Xh[base+t]     = f2bf(x0);
  X[base+t+256] = x1;  Xh[base+t+256] = f2bf(x1);
}

// ---------------- final LayerNorm + GELU ----------------
__global__ __launch_bounds__(256) void ln_gelu_k(const float* __restrict__ X,
                                                 float* __restrict__ Yout,
                                                 const float* __restrict__ w,
                                                 const float* __restrict__ b){
  int r = blockIdx.x;
  size_t base = (size_t)r*512;
  int t = threadIdx.x;
  float v0 = X[base+t];
  float v1 = X[base+t+256];
  __shared__ float red[256];
  red[t] = v0 + v1; __syncthreads();
  for (int o=128;o>0;o>>=1){ if(t<o) red[t]+=red[t+o]; __syncthreads(); }
  float mu = red[0]*(1.f/512.f); __syncthreads();
  float d0 = v0-mu, d1 = v1-mu;
  red[t] = d0*d0 + d1*d1; __syncthreads();
  for (int o=128;o>0;o>>=1){ if(t<o) red[t]+=red[t+o]; __syncthreads(); }
  float rs = 1.0f/sqrtf(red[0]*(1.f/512.f) + 1e-5f);
  float g0 = d0*rs*w[t]     + b[t];
  float g1 = d1*rs*w[t+256] + b[t+256];
  Yout[base+t]     = 0.5f*g0*(1.0f + erff(g0*0.707106781186547524f));
  Yout[base+t+256] = 0.5f*g1*(1.0f + erff(g1*0.707106781186547524f));
}

// ---------------- conv helpers ----------------
__global__ __launch_bounds__(256) void im2col_k(const float* __restrict__ X,
                                                short* __restrict__ O, int L){
  int i = blockIdx.x*256 + threadIdx.x;   // 8*L*1536
  int col = i % 1536; int bl = i / 1536;
  int l = bl % L; int b = bl / L;
  int t = col / 512; int ci = col % 512;
  int ls = l - 1 + t;
  ls = (ls < 0) ? (L-1) : (ls >= L ? 0 : ls);
  O[(size_t)bl*1536 + col] = f2bf(X[(size_t)(b*L + ls)*512 + ci]);
}
__global__ __launch_bounds__(256) void pool_k(const short* __restrict__ Hc,
                                              float* __restrict__ X,
                                              short* __restrict__ Xh, int L, int Lo){
  int i = blockIdx.x*256 + threadIdx.x;   // 8*Lo*512
  int c = i & 511; int r = i >> 9; int lo = r % Lo; int b = r / Lo;
  float m = -INFINITY;
  #pragma unroll
  for (int dt=-1; dt<=1; dt++){
    int li = 2*lo + dt;
    if (li >= 0 && li < L) m = fmaxf(m, bf2f((unsigned short)Hc[(size_t)(b*L + li)*512 + c]));
  }
  size_t o = (size_t)(b*Lo + lo)*512 + c;
  X[o] = m; Xh[o] = f2bf(m);
}

// ---------------- split-K final projection ----------------
__global__ __launch_bounds__(256) void proj_part_k(const float* __restrict__ Xg,
                                                   const float* __restrict__ pw,
                                                   float* __restrict__ part){
  int b = blockIdx.x >> 5;
  int c = blockIdx.x & 31;
  int t = threadIdx.x;
  const float4* xp = (const float4*)(Xg + (size_t)b*131072 + (size_t)c*4096);
  float4 x0 = xp[t], x1 = xp[t+256], x2 = xp[t+512], x3 = xp[t+768];
  float acc[10];
  #pragma unroll
  for (int j=0;j<10;j++){
    const float4* wp = (const float4*)(pw + (size_t)j*131072 + (size_t)c*4096);
    float4 w0 = wp[t], w1 = wp[t+256], w2 = wp[t+512], w3 = wp[t+768];
    acc[j] = x0.x*w0.x + x0.y*w0.y + x0.z*w0.z + x0.w*w0.w
           + x1.x*w1.x + x1.y*w1.y + x1.z*w1.z + x1.w*w1.w
           + x2.x*w2.x + x2.y*w2.y + x2.z*w2.z + x2.w*w2.w
           + x3.x*w3.x + x3.y*w3.y + x3.z*w3.z + x3.w*w3.w;
  }
  __shared__ float red[256];
  #pragma unroll
  for (int j=0;j<10;j++){
    red[t] = acc[j]; __syncthreads();
    for (int o=128;o>0;o>>=1){ if(t<o) red[t]+=red[t+o]; __syncthreads(); }
    if (t==0) part[(b*10 + j)*32 + c] = red[0];
    __syncthreads();
  }
}
__global__ __launch_bounds__(128) void proj_comb_k(const float* __restrict__ part,
                                                   const float* __restrict__ pb,
                                                   float* __restrict__ out){
  int t = threadIdx.x;
  if (t >= 80) return;
  int j = t % 10;
  const float* p = part + t*32;
  float s = 0.f;
  #pragma unroll
  for (int c=0;c<32;c++) s += p[c];
  out[t] = s + pb[j];
}

extern "C" void kernel_launch(void* const* d_in, const int* in_sizes, int n_in,
                              void* d_out, int out_size, void* d_ws, size_t ws_size,
                              hipStream_t stream){
  (void)in_sizes; (void)n_in; (void)out_size; (void)ws_size;
  const float* x_enc = (const float*)d_in[0];
  const float* tok_w = (const float*)d_in[1];
  const float* wq    = (const float*)d_in[2];
  const float* bq    = (const float*)d_in[3];
  const float* wk    = (const float*)d_in[4];
  const float* bk    = (const float*)d_in[5];
  const float* wvp   = (const float*)d_in[6];
  const float* bvp   = (const float*)d_in[7];
  const float* wo    = (const float*)d_in[8];
  const float* bo    = (const float*)d_in[9];
  const float* ln1w  = (const float*)d_in[10];
  const float* ln1b  = (const float*)d_in[11];
  const float* ln2w  = (const float*)d_in[12];
  const float* ln2b  = (const float*)d_in[13];
  const float* f1w   = (const float*)d_in[14];
  const float* f1b   = (const float*)d_in[15];
  const float* f2w   = (const float*)d_in[16];
  const float* f2b   = (const float*)d_in[17];
  const float* cvw   = (const float*)d_in[18];
  const float* cvb   = (const float*)d_in[19];
  const float* bnw   = (const float*)d_in[20];
  const float* bnb   = (const float*)d_in[21];
  const float* nw    = (const float*)d_in[22];
  const float* nb    = (const float*)d_in[23];
  const float* pw    = (const float*)d_in[24];
  const float* pb    = (const float*)d_in[25];

  char* wsb = (char*)d_ws;
  float* X    = (float*)(wsb + 0);            // 8192x512 f32
  float* Y    = (float*)(wsb + 16777216);     // 8192x512 f32
  float* Q    = (float*)(wsb + 33554432);
  float* Kbuf = (float*)(wsb + 50331648);
  float* V    = (float*)(wsb + 67108864);
  short* Xh   = (short*)(wsb + 83886080);     // 8192x512 bf16
  short* CTXh = (short*)(wsb + 92274688);     // 8192x512 bf16
  short* WQH  = (short*)(wsb + 100663296);
  short* WKH  = WQH + 262144;
  short* WVH  = WKH + 262144;
  short* WOH  = WVH + 262144;
  short* F1H  = WOH + 262144;                 // 2048x512
  short* F2H  = F1H + 1048576;                // 512x2048
  short* WCVH = F2H + 1048576;                // 512x1536
  char*  RB   = wsb + 108527616;              // shared region (58.7MB)
  short* FFh  = (short*)(RB);                 // 8192x2048 bf16 (FFN phase)
  short* IM2  = (short*)(RB + 33554432);      // 8192x1536 bf16 (conv phase)
  short* Kh   = (short*)(RB + 0);             // [64][1024][64] bf16 (attn phase)
  short* Vt   = (short*)(RB + 8388608);       // [64][128][1024] bf16
  short* Ph   = (short*)(RB + 25165824);      // [64][128][1024] bf16
  short* Qrh  = (short*)(RB + 41943040);      // [64][128][64] bf16
  float* S    = (float*)(RB + 42991616);      // [64][35][1024] f32
  float* RS   = (float*)(RB + 52166656);      // [64][35] f32
  float* UPD  = (float*)(RB + 52175616);      // [64][35][64] f32
  float* Mb   = (float*)(RB + 52749056);      // [64][1024] f32
  float* VME  = (float*)(RB + 53011200);
  float* VPA  = (float*)(RB + 53027584);
  int*   IDX  = (int*)  (RB + 53289728);
  int*   TOPK = (int*)  (RB + 53433088);
  float* PPART= (float*)(RB + 53450752);      // [8][10][32] f32

  // JAX partitionable key derivation (host)
  uint32_t rka[3], rkb[3];
  for (int l = 0; l < 3; ++l) tf2x32(0u, 42u, 0u, (uint32_t)l, &rka[l], &rkb[l]);

  auto gemm = [&](const short* A, long Ab, const short* W, long Wb, const float* bias,
                  float* Cf, short* Ch, long Cb, int M, int Nreal, int Nstride, int K,
                  int mode, const float* s2, const float* b2, const float* rs, long rsb,
                  int mt, int nt, int zt, short* KhG, int Lq){
    hipLaunchKernelGGL(gemm_bf16_k, dim3(mt, nt, zt), dim3(256), 0, stream,
                       A, Ab, W, Wb, bias, Cf, Ch, Cb, M, Nreal, Nstride, K, mode,
                       s2, b2, rs, rsb, KhG, Lq);
  };

  hipLaunchKernelGGL(embed_k, dim3(16336), dim3(256), 0, stream, x_enc, tok_w, X, Xh);

  int L = 1021;
  for (int l = 0; l < 3; ++l){
    int n = 5 * (int)ceil(log((double)L)); if (n > L) n = L;
    int Mr = 8 * L;
    int mt = (Mr + 127)/128;

    // weight converts (bf16)
    hipLaunchKernelGGL(wcvt_k, dim3(1024), dim3(256), 0, stream, wq + (size_t)l*262144, WQH, 262144);
    hipLaunchKernelGGL(wcvt_k, dim3(1024), dim3(256), 0, stream, wk + (size_t)l*262144, WKH, 262144);
    hipLaunchKernelGGL(wcvt_k, dim3(1024), dim3(256), 0, stream, wvp+ (size_t)l*262144, WVH, 262144);
    hipLaunchKernelGGL(wcvt_k, dim3(1024), dim3(256), 0, stream, wo + (size_t)l*262144, WOH, 262144);
    hipLaunchKernelGGL(wcvt_k, dim3(4096), dim3(256), 0, stream, f1w+ (size_t)l*1048576, F1H, 1048576);
    hipLaunchKernelGGL(wcvt_k, dim3(4096), dim3(256), 0, stream, f2w+ (size_t)l*1048576, F2H, 1048576);

    // random sample indices
    uint32_t k1a,k1b,k2a,k2b;
    tf2x32(rka[l], rkb[l], 0u, 0u, &k1a, &k1b);
    tf2x32(rka[l], rkb[l], 0u, 1u, &k2a, &k2b);
    int size = L * n;
    uint32_t span = (uint32_t)L;
    uint32_t rr = 65536u % span;
    uint32_t mult = (rr * rr) % span;
    hipLaunchKernelGGL(gen_idx_k, dim3((unsigned)((size+255)/256)), dim3(256), 0, stream,
                       k1a, k1b, k2a, k2b, size, span, mult, IDX);

    // QKV (bf16 MFMA, fp32 out; K also writes head-gathered bf16 copy)
    gemm(Xh, 0, WQH, 0, bq + (size_t)l*512, Q,    nullptr, 0, Mr, 512, 512, 512, 0, 0, 0, 0, 0, mt, 4, 1, nullptr, 0);
    gemm(Xh, 0, WKH, 0, bk + (size_t)l*512, Kbuf, nullptr, 0, Mr, 512, 512, 512, 0, 0, 0, 0, 0, mt, 4, 1, Kh, L);
    gemm(Xh, 0, WVH, 0, bvp+ (size_t)l*512, V,    nullptr, 0, Mr, 512, 512, 512, 0, 0, 0, 0, 0, mt, 4, 1, nullptr, 0);

    // sampled m (coalesced wave-per-sample, fused reduce), top-k
    hipLaunchKernelGGL(qk_dot_k, dim3((unsigned)(8*L)), dim3(256), 0, stream,
                       Q, Kbuf, IDX, Mb, L, n);
    hipLaunchKernelGGL(topk_k, dim3(64), dim3(64), 0, stream, Mb, TOPK, L, n);

    // attention: gather -> scores GEMM -> softmax -> PV GEMM
    hipLaunchKernelGGL(qred_k, dim3((unsigned)(64*n)), dim3(64), 0, stream, Q, TOPK, Qrh, L, n);
    hipLaunchKernelGGL(vt_k, dim3(1024), dim3(256), 0, stream, V, Vt, L);
    gemm(Qrh, 8192, Kh, 65536, nullptr, S, nullptr, (long)n*1024, n, L, 1024, 64, 3, 0, 0, 0, 0, 1, 8, 64, nullptr, 0);
    hipLaunchKernelGGL(softmax_k, dim3((unsigned)(64*n)), dim3(256), 0, stream, S, Ph, RS, L, n);
    gemm(Ph, 131072, Vt, 131072, nullptr, UPD, nullptr, (long)n*64, n, 64, 64, 1024, 4, 0, 0, RS, n, 1, 1, 64, nullptr, 0);

    // ctx = broadcast mean(v) with top-k rows replaced (bf16)
    hipLaunchKernelGGL(vmean_part_k, dim3(8,16), dim3(512), 0, stream, V, VPA, L);
    hipLaunchKernelGGL(vmean_comb_k, dim3(16), dim3(256), 0, stream, VPA, VME, L);
    hipLaunchKernelGGL(ctx_fill_k, dim3((unsigned)(Mr*2)), dim3(256), 0, stream, CTXh, VME, L);
    hipLaunchKernelGGL(ctx_scatter_k, dim3((unsigned)(16*n)), dim3(256), 0, stream, CTXh, UPD, TOPK, L, n);

    // out-proj + LN1
    gemm(CTXh, 0, WOH, 0, bo + (size_t)l*512, Y, nullptr, 0, Mr, 512, 512, 512, 0, 0, 0, 0, 0, mt, 4, 1, nullptr, 0);
    hipLaunchKernelGGL(add_ln_k, dim3((unsigned)Mr), dim3(256), 0, stream, X, Xh, Y, ln1w + (size_t)l*512, ln1b + (size_t)l*512);

    // FFN + LN2
    gemm(Xh, 0, F1H, 0, f1b + (size_t)l*2048, nullptr, FFh, 0, Mr, 2048, 2048, 512, 1, 0, 0, 0, 0, mt, 16, 1, nullptr, 0);
    gemm(FFh, 0, F2H, 0, f2b + (size_t)l*512, Y, nullptr, 0, Mr, 512, 512, 2048, 0, 0, 0, 0, 0, mt, 4, 1, nullptr, 0);
    hipLaunchKernelGGL(add_ln_k, dim3((unsigned)Mr), dim3(256), 0, stream, X, Xh, Y, ln2w + (size_t)l*512, ln2b + (size_t)l*512);

    // distilling conv (layers 0,1)
    if (l < 2){
      hipLaunchKernelGGL(convw_k, dim3(3072), dim3(256), 0, stream, cvw + (size_t)l*786432, WCVH);
      hipLaunchKernelGGL(im2col_k, dim3((unsigned)(Mr*6)), dim3(256), 0, stream, X, IM2, L);
      gemm(IM2, 0, WCVH, 0, cvb + (size_t)l*512, nullptr, CTXh, 0, Mr, 512, 512, 1536, 2,
           bnw + (size_t)l*512, bnb + (size_t)l*512, 0, 0, mt, 4, 1, nullptr, 0);
      int Lo = (L - 1)/2 + 1;
      hipLaunchKernelGGL(pool_k, dim3((unsigned)(8*Lo*2)), dim3(256), 0, stream, CTXh, X, Xh, L, Lo);
      L = Lo;
    }
  }

  hipLaunchKernelGGL(ln_gelu_k, dim3((unsigned)(8*L)), dim3(256), 0, stream, X, Y, nw, nb);
  hipLaunchKernelGGL(proj_part_k, dim3(256), dim3(256), 0, stream, Y, pw, PPART);
  hipLaunchKernelGGL(proj_comb_k, dim3(1), dim3(128), 0, stream, PPART, pb, (float*)d_out);
}

// Round 9
// 1557.729 us; speedup vs baseline: 2.8557x; 1.0062x over previous
//
#include <hip/hip_runtime.h>
#include <math.h>
#include <stdint.h>

typedef __attribute__((ext_vector_type(8))) short bf16x8;
typedef __attribute__((ext_vector_type(4))) float f32x4;

// ---------------- helpers ----------------
__device__ __forceinline__ unsigned short f2bf(float f){
  unsigned int u = __float_as_uint(f);
  unsigned int r = (u + 0x7fffu + ((u>>16)&1u)) >> 16;
  return (unsigned short)r;
}
__device__ __forceinline__ float bf2f(unsigned short h){
  return __uint_as_float(((unsigned int)h)<<16);
}
__device__ __forceinline__ void gload16(const void* g, void* l){
  __builtin_amdgcn_global_load_lds(
      (const __attribute__((address_space(1))) unsigned int*)g,
      (__attribute__((address_space(3))) unsigned int*)l, 16, 0, 0);
}

// ---------------- Threefry-2x32 (exact JAX PRNG, partitionable) ----------------
__host__ __device__ static inline uint32_t rotl32(uint32_t x, int d){ return (x<<d)|(x>>(32-d)); }
__host__ __device__ static inline void tf2x32(uint32_t k0, uint32_t k1, uint32_t c0, uint32_t c1,
                                              uint32_t* o0, uint32_t* o1){
  uint32_t ks0=k0, ks1=k1, ks2=k0^k1^0x1BD11BDAu;
  uint32_t x0=c0+ks0, x1=c1+ks1;
  const int ra[4]={13,15,26,6}, rb[4]={17,29,16,24};
  #pragma unroll
  for(int i=0;i<4;i++){x0+=x1;x1=rotl32(x1,ra[i]);x1^=x0;}
  x0+=ks1; x1+=ks2+1u;
  #pragma unroll
  for(int i=0;i<4;i++){x0+=x1;x1=rotl32(x1,rb[i]);x1^=x0;}
  x0+=ks2; x1+=ks0+2u;
  #pragma unroll
  for(int i=0;i<4;i++){x0+=x1;x1=rotl32(x1,ra[i]);x1^=x0;}
  x0+=ks0; x1+=ks1+3u;
  #pragma unroll
  for(int i=0;i<4;i++){x0+=x1;x1=rotl32(x1,rb[i]);x1^=x0;}
  x0+=ks1; x1+=ks2+4u;
  #pragma unroll
  for(int i=0;i<4;i++){x0+=x1;x1=rotl32(x1,ra[i]);x1^=x0;}
  x0+=ks2; x1+=ks0+5u;
  *o0=x0; *o1=x1;
}

__global__ __launch_bounds__(256) void gen_idx_k(uint32_t k1a,uint32_t k1b,
                                                 uint32_t k2a,uint32_t k2b,
                                                 int size,uint32_t span,uint32_t mult,
                                                 int* __restrict__ idx){
  int i = blockIdx.x*256 + threadIdx.x;
  if (i >= size) return;
  uint32_t h0,h1,l0,l1;
  tf2x32(k1a,k1b,0u,(uint32_t)i,&h0,&h1);
  tf2x32(k2a,k2b,0u,(uint32_t)i,&l0,&l1);
  uint32_t hb = h0^h1, lb = l0^l1;
  idx[i] = (int)((((hb%span)*mult) + (lb%span)) % span);
}

// ---------------- token embedding + PE (writes fp32 X and bf16 Xh) ----------------
__global__ __launch_bounds__(256) void embed_k(const float* __restrict__ xe,
                                               const float* __restrict__ tw,
                                               float* __restrict__ X,
                                               short* __restrict__ Xh){
  int i = blockIdx.x*256 + threadIdx.x;     // over 8*1021*512
  int c = i & 511;
  int bl = i >> 9;
  int l = bl % 1021;
  int b = bl / 1021;
  float acc = 0.f;
  #pragma unroll
  for (int t=0;t<3;t++){
    int ls = l - 1 + t;
    ls = (ls < 0) ? 1020 : (ls >= 1021 ? 0 : ls);
    const float* xp = xe + (size_t)(b*1021 + ls)*12;
    const float* wp = tw + (size_t)c*36 + t;
    #pragma unroll
    for (int ci=0; ci<12; ci++) acc += xp[ci] * wp[ci*3];
  }
  int ip = c >> 1;
  float div = expf((float)(2*ip) * (float)(-9.210340371976184/512.0));
  float ang = (float)l * div;
  acc += (c & 1) ? cosf(ang) : sinf(ang);
  X[i] = acc;
  Xh[i] = f2bf(acc);
}

// ---------------- weight converts ----------------
__global__ __launch_bounds__(256) void wcvt_k(const float* __restrict__ src,
                                              short* __restrict__ dst, int n){
  int i = blockIdx.x*256 + threadIdx.x;
  if (i < n) dst[i] = f2bf(src[i]);
}
__global__ __launch_bounds__(256) void convw_k(const float* __restrict__ cw,
                                               short* __restrict__ W){
  int i = blockIdx.x*256 + threadIdx.x;   // 512*1536
  int col = i % 1536; int co = i / 1536;
  int t = col / 512; int ci = col % 512;
  W[i] = f2bf(cw[(size_t)co*1536 + ci*3 + t]);
}

// ---------------- bf16 MFMA GEMM (dbuf LDS + T2 XOR swizzle): C = A @ W^T, batched ----
// LDS tile [128 rows][4 chunks of 16B]; slot chunk' = chunk ^ ((row>>1)&3).
// Stager pre-swizzles the GLOBAL source chunk (LDS dest stays linear, per m104/m173);
// reader applies the same XOR. 8-way bank conflict -> 2-way (free, m136).
// mode 0: +bias  1: +bias,GELU  2: +bias,BN,ELU  3: raw  4: *rowscale
// KhG != nullptr: also write bf16 head-gathered copy [b][h][1024 l][64 d] (needs Lq)
__global__ __launch_bounds__(256) void gemm_bf16_k(
    const short* __restrict__ A, long Ab,
    const short* __restrict__ W, long Wb,
    const float* __restrict__ bias,
    float* __restrict__ Cf, short* __restrict__ Ch, long Cb,
    int M, int Nreal, int Nstride, int K, int mode,
    const float* __restrict__ s2, const float* __restrict__ b2,
    const float* __restrict__ rs, long rsb,
    short* __restrict__ KhG, int Lq)
{
  __shared__ short As[8192];   // 2 buffers x 128 x 32
  __shared__ short Bs[8192];
  const int t = threadIdx.x;
  const int lane = t & 63;
  const int w = t >> 6;
  const int wr = w >> 1, wc = w & 1;
  const int z = blockIdx.z;
  const int m0 = blockIdx.x * 128, n0 = blockIdx.y * 128;
  const short* Az = A + (size_t)z * Ab;
  const short* Wz = W + (size_t)z * Wb;

  f32x4 acc[4][4];
  #pragma unroll
  for (int i=0;i<4;i++)
    #pragma unroll
    for (int j=0;j<4;j++) acc[i][j] = (f32x4){0.f,0.f,0.f,0.f};

  const int r0  = t >> 2;                         // staging row for slot t
  const int k80 = (((t & 3) ^ ((t >> 3) & 3)) << 3);  // pre-swizzled global k-offset
  char* AsB = (char*)As;
  char* BsB = (char*)Bs;

  #define STAGE(buf, k0) do { \
    gload16(Az + (size_t)(m0 + r0)      * K + (k0) + k80, AsB + (buf)*8192 + (size_t)w*1024); \
    gload16(Az + (size_t)(m0 + r0 + 64) * K + (k0) + k80, AsB + (buf)*8192 + 4096 + (size_t)w*1024); \
    gload16(Wz + (size_t)(n0 + r0)      * K + (k0) + k80, BsB + (buf)*8192 + (size_t)w*1024); \
    gload16(Wz + (size_t)(n0 + r0 + 64) * K + (k0) + k80, BsB + (buf)*8192 + 4096 + (size_t)w*1024); \
  } while(0)

  STAGE(0, 0);
  __syncthreads();
  int cur = 0;
  const int rr  = lane & 15;
  const int swz = ((rr >> 1) & 3);
  const int kc  = ((lane >> 4) ^ swz) << 3;       // swizzled chunk offset (shorts)
  for (int k0 = 0; k0 < K; k0 += 32){
    if (k0 + 32 < K) STAGE(cur^1, k0+32);
    bf16x8 a[4], b[4];
    #pragma unroll
    for (int mi=0; mi<4; mi++){
      int aoff = cur*4096 + (wr*64 + mi*16 + rr)*32 + kc;
      a[mi] = *(const bf16x8*)(&As[aoff]);
    }
    #pragma unroll
    for (int ni=0; ni<4; ni++){
      int boff = cur*4096 + (wc*64 + ni*16 + rr)*32 + kc;
      b[ni] = *(const bf16x8*)(&Bs[boff]);
    }
    #pragma unroll
    for (int mi=0; mi<4; mi++)
      #pragma unroll
      for (int ni=0; ni<4; ni++)
        acc[mi][ni] = __builtin_amdgcn_mfma_f32_16x16x32_bf16(a[mi], b[ni], acc[mi][ni], 0, 0, 0);
    __syncthreads();   // drains STAGE (compiler vmcnt) + protects cur buffer
    cur ^= 1;
  }
  #undef STAGE

  #pragma unroll
  for (int mi=0; mi<4; mi++){
    #pragma unroll
    for (int r=0; r<4; r++){
      int gm = m0 + wr*64 + mi*16 + ((lane>>4)<<2) + r;
      if (gm >= M) continue;
      float rsc = (mode==4) ? rs[(size_t)z*rsb + gm] : 0.f;
      int bb = 0, ll = 0;
      if (KhG){ bb = gm / Lq; ll = gm - bb*Lq; }
      #pragma unroll
      for (int ni=0; ni<4; ni++){
        int gn = n0 + wc*64 + ni*16 + (lane&15);
        if (gn >= Nreal) continue;
        float v = acc[mi][ni][r];
        if (mode <= 2) v += bias[gn];
        if (mode == 1){
          v = 0.5f*v*(1.0f + erff(v*0.707106781186547524f));
        } else if (mode == 2){
          v = v * (s2[gn]*0.9999950000374997f) + b2[gn];
          v = (v > 0.f) ? v : expm1f(v);
        } else if (mode == 4){
          v *= rsc;
        }
        size_t off = (size_t)z*Cb + (size_t)gm*Nstride + gn;
        if (Cf) Cf[off] = v;
        if (Ch) Ch[off] = f2bf(v);
        if (KhG) KhG[(((size_t)bb*8 + (gn>>6))*1024 + ll)*64 + (gn&63)] = f2bf(v);
      }
    }
  }
}

// ---------------- sampled m: block per (b,l); wave per sample, coalesced K row reads;
// fused m = max_s - sum_s/L  ----------------
__global__ __launch_bounds__(256) void qk_dot_k(const float* __restrict__ Q,
                                                const float* __restrict__ Kb,
                                                const int* __restrict__ idx,
                                                float* __restrict__ Mout, int L, int n){
  __shared__ float Qs[512];
  __shared__ float dots[8][36];
  int blk = blockIdx.x;            // over 8*L
  int l = blk % L, b = blk / L;
  int t = threadIdx.x;
  int w = t >> 6, lane = t & 63;
  if (t < 128){
    gload16(Q + (size_t)(b*L + l)*512 + t*4, (char*)Qs + (size_t)(t>>6)*1024);
  }
  __syncthreads();
  const float4* qp = (const float4*)(Qs + lane*8);
  float4 q0 = qp[0], q1 = qp[1];
  for (int s = w; s < n; s += 4){
    int kr = idx[l*n + s];
    const float4* kp = (const float4*)(Kb + (size_t)(b*L + kr)*512 + lane*8);
    float4 a0 = kp[0], a1 = kp[1];
    float p = a0.x*q0.x + a0.y*q0.y + a0.z*q0.z + a0.w*q0.w
            + a1.x*q1.x + a1.y*q1.y + a1.z*q1.z + a1.w*q1.w;
    p += __shfl_xor(p, 1);
    p += __shfl_xor(p, 2);
    p += __shfl_xor(p, 4);
    if ((lane & 7) == 0) dots[lane >> 3][s] = p;
  }
  __syncthreads();
  if (t < 8){
    float mx = -INFINITY, sm = 0.f;
    for (int s = 0; s < n; ++s){ float v = dots[t][s]; mx = fmaxf(mx, v); sm += v; }
    Mout[(size_t)(b*8 + t)*1024 + l] = mx - sm/(float)L;
  }
}

// ---------------- top-k (single wave per bh, tie -> lower index) ----------------
__global__ __launch_bounds__(64) void topk_k(const float* __restrict__ Mv,
                                             int* __restrict__ topk, int L, int n){
  int bh = blockIdx.x; int lane = threadIdx.x;
  float v[16];
  #pragma unroll
  for (int i=0;i<16;i++){ int l = i*64 + lane; v[i] = (l<L) ? Mv[(size_t)bh*1024 + l] : -INFINITY; }
  for (int it=0; it<n; ++it){
    float bv = -INFINITY; int bi = 0x7fffffff;
    #pragma unroll
    for (int i=0;i<16;i++){ int l = i*64+lane; if (v[i] > bv){ bv = v[i]; bi = l; } }
    #pragma unroll
    for (int o=32;o>0;o>>=1){
      float ov = __shfl_xor(bv, o); int oi = __shfl_xor(bi, o);
      if (ov > bv || (ov == bv && oi < bi)){ bv = ov; bi = oi; }
    }
    if (lane == 0) topk[bh*n + it] = bi;
    int wl = bi & 63, wi = bi >> 6;
    if (lane == wl){
      #pragma unroll
      for (int i=0;i<16;i++) if (i == wi) v[i] = -INFINITY;
    }
  }
}

// ---------------- Qred gather (scaled by 1/8, bf16) ----------------
__global__ __launch_bounds__(64) void qred_k(const float* __restrict__ Q,
                                             const int* __restrict__ topk,
                                             short* __restrict__ Qrh, int L, int n){
  int u = blockIdx.x % n; int bh = blockIdx.x / n;
  int h = bh & 7, b = bh >> 3; int d = threadIdx.x;
  int lq = topk[bh*n + u];
  Qrh[(size_t)bh*8192 + u*64 + d] = f2bf(0.125f * Q[(size_t)(b*L + lq)*512 + h*64 + d]);
}

// ---------------- V transpose to bf16 [bh][128pad d][1024 l] ----------------
__global__ __launch_bounds__(256) void vt_k(const float* __restrict__ V,
                                            short* __restrict__ Vt, int L){
  __shared__ float ts[64][65];
  int z = blockIdx.x >> 4;
  int l0 = (blockIdx.x & 15) * 64;
  int h = z & 7, b = z >> 3;
  int t = threadIdx.x;
  for (int i = t; i < 4096; i += 256){
    int lloc = i >> 6, d = i & 63;
    int l = l0 + lloc;
    ts[d][lloc] = (l < L) ? V[(size_t)(b*L + l)*512 + h*64 + d] : 0.f;
  }
  __syncthreads();
  for (int i = t; i < 4096; i += 256){
    int d = i >> 6, lloc = i & 63;
    Vt[(size_t)z*131072 + (size_t)d*1024 + l0 + lloc] = f2bf(ts[d][lloc]);
  }
}

// ---------------- softmax on S rows -> bf16 P, 1/sum ----------------
__global__ __launch_bounds__(256) void softmax_k(const float* __restrict__ S,
                                                 short* __restrict__ Ph,
                                                 float* __restrict__ RS, int L, int n){
  int u = blockIdx.x % n; int z = blockIdx.x / n;
  const float* srow = S + (size_t)z*n*1024 + (size_t)u*1024;
  short* prow = Ph + (size_t)z*131072 + (size_t)u*1024;
  int t = threadIdx.x;
  __shared__ float red[256];
  float lm = -INFINITY;
  for (int l=t; l<L; l+=256) lm = fmaxf(lm, srow[l]);
  red[t]=lm; __syncthreads();
  for (int o=128;o>0;o>>=1){ if(t<o) red[t]=fmaxf(red[t],red[t+o]); __syncthreads(); }
  float mx = red[0]; __syncthreads();
  float ls = 0.f;
  for (int l=t; l<1024; l+=256){
    float p = (l < L) ? expf(srow[l]-mx) : 0.f;
    prow[l] = f2bf(p);
    ls += p;
  }
  red[t]=ls; __syncthreads();
  for (int o=128;o>0;o>>=1){ if(t<o) red[t]+=red[t+o]; __syncthreads(); }
  if (t==0) RS[(size_t)z*n + u] = 1.0f/red[0];
}

// ---------------- v mean ----------------
__global__ __launch_bounds__(512) void vmean_part_k(const float* __restrict__ V,
                                                    float* __restrict__ part, int L){
  int b = blockIdx.x; int j = blockIdx.y; int c = threadIdx.x;
  float s = 0.f;
  for (int l = j; l < L; l += 16) s += V[(size_t)(b*L + l)*512 + c];
  part[(size_t)(b*16 + j)*512 + c] = s;
}
__global__ __launch_bounds__(256) void vmean_comb_k(const float* __restrict__ part,
                                                    float* __restrict__ vmean, int L){
  int i = blockIdx.x*256 + threadIdx.x;
  int b = i >> 9; int c = i & 511;
  float s = 0.f;
  #pragma unroll
  for (int j=0;j<16;j++) s += part[(size_t)(b*16 + j)*512 + c];
  vmean[i] = s / (float)L;
}
__global__ __launch_bounds__(256) void ctx_fill_k(short* __restrict__ CTXh,
                                                  const float* __restrict__ vmean, int L){
  int i = blockIdx.x*256 + threadIdx.x;
  int c = i & 511; int bl = i >> 9; int b = bl / L;
  CTXh[i] = f2bf(vmean[b*512 + c]);
}
__global__ __launch_bounds__(256) void ctx_scatter_k(short* __restrict__ CTXh,
                                                     const float* __restrict__ UPD,
                                                     const int* __restrict__ topk, int L, int n){
  int i = blockIdx.x*256 + threadIdx.x;   // 64*n*64
  int d = i & 63; int u = (i >> 6) % n; int bh = i / (64*n);
  int h = bh & 7; int b = bh >> 3;
  int lq = topk[bh*n + u];
  CTXh[(size_t)(b*L + lq)*512 + h*64 + d] = f2bf(UPD[((size_t)bh*n + u)*64 + d]);
}

// ---------------- residual add + LayerNorm (X fp32 + Xh bf16) ----------------
__global__ __launch_bounds__(256) void add_ln_k(float* __restrict__ X,
                                                short* __restrict__ Xh,
                                                const float* __restrict__ Y,
                                                const float* __restrict__ w,
                                                const float* __restrict__ b){
  int r = blockIdx.x;
  size_t base = (size_t)r*512;
  int t = threadIdx.x;
  float v0 = X[base+t]     + Y[base+t];
  float v1 = X[base+t+256] + Y[base+t+256];
  __shared__ float red[256];
  red[t] = v0 + v1; __syncthreads();
  for (int o=128;o>0;o>>=1){ if(t<o) red[t]+=red[t+o]; __syncthreads(); }
  float mu = red[0]*(1.f/512.f); __syncthreads();
  float d0 = v0-mu, d1 = v1-mu;
  red[t] = d0*d0 + d1*d1; __syncthreads();
  for (int o=128;o>0;o>>=1){ if(t<o) red[t]+=red[t+o]; __syncthreads(); }
  float rs = 1.0f/sqrtf(red[0]*(1.f/512.f) + 1e-5f);
  float x0 = d0*rs*w[t]     + b[t];
  float x1 = d1*rs*w[t+256] + b[t+256];
  X[base+t]     = x0;  Xh[base+t]     = f2bf(x0);
  X[base+t+256] = x1;  Xh[base+t+256] = f2bf(x1);
}

// ---------------- final LayerNorm + GELU ----------------
__global__ __launch_bounds__(256) void ln_gelu_k(const float* __restrict__ X,
                                                 float* __restrict__ Yout,
                                                 const float* __restrict__ w,
                                                 const float* __restrict__ b){
  int r = blockIdx.x;
  size_t base = (size_t)r*512;
  int t = threadIdx.x;
  float v0 = X[base+t];
  float v1 = X[base+t+256];
  __shared__ float red[256];
  red[t] = v0 + v1; __syncthreads();
  for (int o=128;o>0;o>>=1){ if(t<o) red[t]+=red[t+o]; __syncthreads(); }
  float mu = red[0]*(1.f/512.f); __syncthreads();
  float d0 = v0-mu, d1 = v1-mu;
  red[t] = d0*d0 + d1*d1; __syncthreads();
  for (int o=128;o>0;o>>=1){ if(t<o) red[t]+=red[t+o]; __syncthreads(); }
  float rs = 1.0f/sqrtf(red[0]*(1.f/512.f) + 1e-5f);
  float g0 = d0*rs*w[t]     + b[t];
  float g1 = d1*rs*w[t+256] + b[t+256];
  Yout[base+t]     = 0.5f*g0*(1.0f + erff(g0*0.707106781186547524f));
  Yout[base+t+256] = 0.5f*g1*(1.0f + erff(g1*0.707106781186547524f));
}

// ---------------- conv helpers ----------------
__global__ __launch_bounds__(256) void im2col_k(const float* __restrict__ X,
                                                short* __restrict__ O, int L){
  int i = blockIdx.x*256 + threadIdx.x;   // 8*L*1536
  int col = i % 1536; int bl = i / 1536;
  int l = bl % L; int b = bl / L;
  int t = col / 512; int ci = col % 512;
  int ls = l - 1 + t;
  ls = (ls < 0) ? (L-1) : (ls >= L ? 0 : ls);
  O[(size_t)bl*1536 + col] = f2bf(X[(size_t)(b*L + ls)*512 + ci]);
}
__global__ __launch_bounds__(256) void pool_k(const short* __restrict__ Hc,
                                              float* __restrict__ X,
                                              short* __restrict__ Xh, int L, int Lo){
  int i = blockIdx.x*256 + threadIdx.x;   // 8*Lo*512
  int c = i & 511; int r = i >> 9; int lo = r % Lo; int b = r / Lo;
  float m = -INFINITY;
  #pragma unroll
  for (int dt=-1; dt<=1; dt++){
    int li = 2*lo + dt;
    if (li >= 0 && li < L) m = fmaxf(m, bf2f((unsigned short)Hc[(size_t)(b*L + li)*512 + c]));
  }
  size_t o = (size_t)(b*Lo + lo)*512 + c;
  X[o] = m; Xh[o] = f2bf(m);
}

// ---------------- split-K final projection ----------------
__global__ __launch_bounds__(256) void proj_part_k(const float* __restrict__ Xg,
                                                   const float* __restrict__ pw,
                                                   float* __restrict__ part){
  int b = blockIdx.x >> 5;
  int c = blockIdx.x & 31;
  int t = threadIdx.x;
  const float4* xp = (const float4*)(Xg + (size_t)b*131072 + (size_t)c*4096);
  float4 x0 = xp[t], x1 = xp[t+256], x2 = xp[t+512], x3 = xp[t+768];
  float acc[10];
  #pragma unroll
  for (int j=0;j<10;j++){
    const float4* wp = (const float4*)(pw + (size_t)j*131072 + (size_t)c*4096);
    float4 w0 = wp[t], w1 = wp[t+256], w2 = wp[t+512], w3 = wp[t+768];
    acc[j] = x0.x*w0.x + x0.y*w0.y + x0.z*w0.z + x0.w*w0.w
           + x1.x*w1.x + x1.y*w1.y + x1.z*w1.z + x1.w*w1.w
           + x2.x*w2.x + x2.y*w2.y + x2.z*w2.z + x2.w*w2.w
           + x3.x*w3.x + x3.y*w3.y + x3.z*w3.z + x3.w*w3.w;
  }
  __shared__ float red[256];
  #pragma unroll
  for (int j=0;j<10;j++){
    red[t] = acc[j]; __syncthreads();
    for (int o=128;o>0;o>>=1){ if(t<o) red[t]+=red[t+o]; __syncthreads(); }
    if (t==0) part[(b*10 + j)*32 + c] = red[0];
    __syncthreads();
  }
}
__global__ __launch_bounds__(128) void proj_comb_k(const float* __restrict__ part,
                                                   const float* __restrict__ pb,
                                                   float* __restrict__ out){
  int t = threadIdx.x;
  if (t >= 80) return;
  int j = t % 10;
  const float* p = part + t*32;
  float s = 0.f;
  #pragma unroll
  for (int c=0;c<32;c++) s += p[c];
  out[t] = s + pb[j];
}

extern "C" void kernel_launch(void* const* d_in, const int* in_sizes, int n_in,
                              void* d_out, int out_size, void* d_ws, size_t ws_size,
                              hipStream_t stream){
  (void)in_sizes; (void)n_in; (void)out_size; (void)ws_size;
  const float* x_enc = (const float*)d_in[0];
  const float* tok_w = (const float*)d_in[1];
  const float* wq    = (const float*)d_in[2];
  const float* bq    = (const float*)d_in[3];
  const float* wk    = (const float*)d_in[4];
  const float* bk    = (const float*)d_in[5];
  const float* wvp   = (const float*)d_in[6];
  const float* bvp   = (const float*)d_in[7];
  const float* wo    = (const float*)d_in[8];
  const float* bo    = (const float*)d_in[9];
  const float* ln1w  = (const float*)d_in[10];
  const float* ln1b  = (const float*)d_in[11];
  const float* ln2w  = (const float*)d_in[12];
  const float* ln2b  = (const float*)d_in[13];
  const float* f1w   = (const float*)d_in[14];
  const float* f1b   = (const float*)d_in[15];
  const float* f2w   = (const float*)d_in[16];
  const float* f2b   = (const float*)d_in[17];
  const float* cvw   = (const float*)d_in[18];
  const float* cvb   = (const float*)d_in[19];
  const float* bnw   = (const float*)d_in[20];
  const float* bnb   = (const float*)d_in[21];
  const float* nw    = (const float*)d_in[22];
  const float* nb    = (const float*)d_in[23];
  const float* pw    = (const float*)d_in[24];
  const float* pb    = (const float*)d_in[25];

  char* wsb = (char*)d_ws;
  float* X    = (float*)(wsb + 0);            // 8192x512 f32
  float* Y    = (float*)(wsb + 16777216);     // 8192x512 f32
  float* Q    = (float*)(wsb + 33554432);
  float* Kbuf = (float*)(wsb + 50331648);
  float* V    = (float*)(wsb + 67108864);
  short* Xh   = (short*)(wsb + 83886080);     // 8192x512 bf16
  short* CTXh = (short*)(wsb + 92274688);     // 8192x512 bf16
  short* WQH  = (short*)(wsb + 100663296);
  short* WKH  = WQH + 262144;
  short* WVH  = WKH + 262144;
  short* WOH  = WVH + 262144;
  short* F1H  = WOH + 262144;                 // 2048x512
  short* F2H  = F1H + 1048576;                // 512x2048
  short* WCVH = F2H + 1048576;                // 512x1536
  char*  RB   = wsb + 108527616;              // shared region (58.7MB)
  short* FFh  = (short*)(RB);                 // 8192x2048 bf16 (FFN phase)
  short* IM2  = (short*)(RB + 33554432);      // 8192x1536 bf16 (conv phase)
  short* Kh   = (short*)(RB + 0);             // [64][1024][64] bf16 (attn phase)
  short* Vt   = (short*)(RB + 8388608);       // [64][128][1024] bf16
  short* Ph   = (short*)(RB + 25165824);      // [64][128][1024] bf16
  short* Qrh  = (short*)(RB + 41943040);      // [64][128][64] bf16
  float* S    = (float*)(RB + 42991616);      // [64][35][1024] f32
  float* RS   = (float*)(RB + 52166656);      // [64][35] f32
  float* UPD  = (float*)(RB + 52175616);      // [64][35][64] f32
  float* Mb   = (float*)(RB + 52749056);      // [64][1024] f32
  float* VME  = (float*)(RB + 53011200);
  float* VPA  = (float*)(RB + 53027584);
  int*   IDX  = (int*)  (RB + 53289728);
  int*   TOPK = (int*)  (RB + 53433088);
  float* PPART= (float*)(RB + 53450752);      // [8][10][32] f32

  // JAX partitionable key derivation (host)
  uint32_t rka[3], rkb[3];
  for (int l = 0; l < 3; ++l) tf2x32(0u, 42u, 0u, (uint32_t)l, &rka[l], &rkb[l]);

  auto gemm = [&](const short* A, long Ab, const short* W, long Wb, const float* bias,
                  float* Cf, short* Ch, long Cb, int M, int Nreal, int Nstride, int K,
                  int mode, const float* s2, const float* b2, const float* rs, long rsb,
                  int mt, int nt, int zt, short* KhG, int Lq){
    hipLaunchKernelGGL(gemm_bf16_k, dim3(mt, nt, zt), dim3(256), 0, stream,
                       A, Ab, W, Wb, bias, Cf, Ch, Cb, M, Nreal, Nstride, K, mode,
                       s2, b2, rs, rsb, KhG, Lq);
  };

  hipLaunchKernelGGL(embed_k, dim3(16336), dim3(256), 0, stream, x_enc, tok_w, X, Xh);

  int L = 1021;
  for (int l = 0; l < 3; ++l){
    int n = 5 * (int)ceil(log((double)L)); if (n > L) n = L;
    int Mr = 8 * L;
    int mt = (Mr + 127)/128;

    // weight converts (bf16)
    hipLaunchKernelGGL(wcvt_k, dim3(1024), dim3(256), 0, stream, wq + (size_t)l*262144, WQH, 262144);
    hipLaunchKernelGGL(wcvt_k, dim3(1024), dim3(256), 0, stream, wk + (size_t)l*262144, WKH, 262144);
    hipLaunchKernelGGL(wcvt_k, dim3(1024), dim3(256), 0, stream, wvp+ (size_t)l*262144, WVH, 262144);
    hipLaunchKernelGGL(wcvt_k, dim3(1024), dim3(256), 0, stream, wo + (size_t)l*262144, WOH, 262144);
    hipLaunchKernelGGL(wcvt_k, dim3(4096), dim3(256), 0, stream, f1w+ (size_t)l*1048576, F1H, 1048576);
    hipLaunchKernelGGL(wcvt_k, dim3(4096), dim3(256), 0, stream, f2w+ (size_t)l*1048576, F2H, 1048576);

    // random sample indices
    uint32_t k1a,k1b,k2a,k2b;
    tf2x32(rka[l], rkb[l], 0u, 0u, &k1a, &k1b);
    tf2x32(rka[l], rkb[l], 0u, 1u, &k2a, &k2b);
    int size = L * n;
    uint32_t span = (uint32_t)L;
    uint32_t rr = 65536u % span;
    uint32_t mult = (rr * rr) % span;
    hipLaunchKernelGGL(gen_idx_k, dim3((unsigned)((size+255)/256)), dim3(256), 0, stream,
                       k1a, k1b, k2a, k2b, size, span, mult, IDX);

    // QKV (bf16 MFMA, fp32 out; K also writes head-gathered bf16 copy)
    gemm(Xh, 0, WQH, 0, bq + (size_t)l*512, Q,    nullptr, 0, Mr, 512, 512, 512, 0, 0, 0, 0, 0, mt, 4, 1, nullptr, 0);
    gemm(Xh, 0, WKH, 0, bk + (size_t)l*512, Kbuf, nullptr, 0, Mr, 512, 512, 512, 0, 0, 0, 0, 0, mt, 4, 1, Kh, L);
    gemm(Xh, 0, WVH, 0, bvp+ (size_t)l*512, V,    nullptr, 0, Mr, 512, 512, 512, 0, 0, 0, 0, 0, mt, 4, 1, nullptr, 0);

    // sampled m (coalesced wave-per-sample, fused reduce), top-k
    hipLaunchKernelGGL(qk_dot_k, dim3((unsigned)(8*L)), dim3(256), 0, stream,
                       Q, Kbuf, IDX, Mb, L, n);
    hipLaunchKernelGGL(topk_k, dim3(64), dim3(64), 0, stream, Mb, TOPK, L, n);

    // attention: gather -> scores GEMM -> softmax -> PV GEMM
    hipLaunchKernelGGL(qred_k, dim3((unsigned)(64*n)), dim3(64), 0, stream, Q, TOPK, Qrh, L, n);
    hipLaunchKernelGGL(vt_k, dim3(1024), dim3(256), 0, stream, V, Vt, L);
    gemm(Qrh, 8192, Kh, 65536, nullptr, S, nullptr, (long)n*1024, n, L, 1024, 64, 3, 0, 0, 0, 0, 1, 8, 64, nullptr, 0);
    hipLaunchKernelGGL(softmax_k, dim3((unsigned)(64*n)), dim3(256), 0, stream, S, Ph, RS, L, n);
    gemm(Ph, 131072, Vt, 131072, nullptr, UPD, nullptr, (long)n*64, n, 64, 64, 1024, 4, 0, 0, RS, n, 1, 1, 64, nullptr, 0);

    // ctx = broadcast mean(v) with top-k rows replaced (bf16)
    hipLaunchKernelGGL(vmean_part_k, dim3(8,16), dim3(512), 0, stream, V, VPA, L);
    hipLaunchKernelGGL(vmean_comb_k, dim3(16), dim3(256), 0, stream, VPA, VME, L);
    hipLaunchKernelGGL(ctx_fill_k, dim3((unsigned)(Mr*2)), dim3(256), 0, stream, CTXh, VME, L);
    hipLaunchKernelGGL(ctx_scatter_k, dim3((unsigned)(16*n)), dim3(256), 0, stream, CTXh, UPD, TOPK, L, n);

    // out-proj + LN1
    gemm(CTXh, 0, WOH, 0, bo + (size_t)l*512, Y, nullptr, 0, Mr, 512, 512, 512, 0, 0, 0, 0, 0, mt, 4, 1, nullptr, 0);
    hipLaunchKernelGGL(add_ln_k, dim3((unsigned)Mr), dim3(256), 0, stream, X, Xh, Y, ln1w + (size_t)l*512, ln1b + (size_t)l*512);

    // FFN + LN2
    gemm(Xh, 0, F1H, 0, f1b + (size_t)l*2048, nullptr, FFh, 0, Mr, 2048, 2048, 512, 1, 0, 0, 0, 0, mt, 16, 1, nullptr, 0);
    gemm(FFh, 0, F2H, 0, f2b + (size_t)l*512, Y, nullptr, 0, Mr, 512, 512, 2048, 0, 0, 0, 0, 0, mt, 4, 1, nullptr, 0);
    hipLaunchKernelGGL(add_ln_k, dim3((unsigned)Mr), dim3(256), 0, stream, X, Xh, Y, ln2w + (size_t)l*512, ln2b + (size_t)l*512);

    // distilling conv (layers 0,1)
    if (l < 2){
      hipLaunchKernelGGL(convw_k, dim3(3072), dim3(256), 0, stream, cvw + (size_t)l*786432, WCVH);
      hipLaunchKernelGGL(im2col_k, dim3((unsigned)(Mr*6)), dim3(256), 0, stream, X, IM2, L);
      gemm(IM2, 0, WCVH, 0, cvb + (size_t)l*512, nullptr, CTXh, 0, Mr, 512, 512, 1536, 2,
           bnw + (size_t)l*512, bnb + (size_t)l*512, 0, 0, mt, 4, 1, nullptr, 0);
      int Lo = (L - 1)/2 + 1;
      hipLaunchKernelGGL(pool_k, dim3((unsigned)(8*Lo*2)), dim3(256), 0, stream, CTXh, X, Xh, L, Lo);
      L = Lo;
    }
  }

  hipLaunchKernelGGL(ln_gelu_k, dim3((unsigned)(8*L)), dim3(256), 0, stream, X, Y, nw, nb);
  hipLaunchKernelGGL(proj_part_k, dim3(256), dim3(256), 0, stream, Y, pw, PPART);
  hipLaunchKernelGGL(proj_comb_k, dim3(1), dim3(128), 0, stream, PPART, pb, (float*)d_out);
}